// Round 13
// baseline (335.514 us; speedup 1.0000x reference)
//
#include <hip/hip_runtime.h>
#include <stdint.h>

// ---------- types ----------
typedef float f32x4 __attribute__((ext_vector_type(4)));
typedef __bf16 bf16x8 __attribute__((ext_vector_type(8)));
typedef __bf16 bf16x8_a __attribute__((ext_vector_type(8), may_alias));
typedef __bf16 bf16x4_a __attribute__((ext_vector_type(4), may_alias));
typedef unsigned int u32x4_a __attribute__((ext_vector_type(4), may_alias));
typedef unsigned short u16x4_a __attribute__((ext_vector_type(4), may_alias));

#define DEV __device__ __forceinline__
#define MFMA_B16(a, b, c) __builtin_amdgcn_mfma_f32_16x16x32_bf16((a), (b), (c), 0, 0, 0)

#if __has_builtin(__builtin_amdgcn_exp2f)
#define EXP2(x) __builtin_amdgcn_exp2f(x)
#else
#define EXP2(x) exp2f(x)
#endif

DEV unsigned short f2b(float f) {  // f32 -> bf16 RNE
  unsigned int u = __float_as_uint(f);
  u = u + 0x7FFFu + ((u >> 16) & 1u);
  return (unsigned short)(u >> 16);
}
DEV float b2f(unsigned short u) { return __uint_as_float(((unsigned int)u) << 16); }

// async global->LDS, 16B per lane; LDS dest is wave-uniform base + lane*16
#define GLOAD_LDS16(gsrc, ldst)                                                  \
  __builtin_amdgcn_global_load_lds(                                              \
      (__attribute__((address_space(1))) void*)(uintptr_t)(const void*)(gsrc),   \
      (__attribute__((address_space(3))) void*)(ldst), 16, 0, 0)

// ---------- fused prepass: cvt x | transpose wq/wk/wv | transpose w_proj/w1/w2 | bias ----------
__global__ __launch_bounds__(256) void prepass_kernel(
    const float* __restrict__ x, const float* __restrict__ wq,
    const float* __restrict__ wk, const float* __restrict__ wv,
    const float* __restrict__ w_proj, const float* __restrict__ w1,
    const float* __restrict__ w2, const float* __restrict__ bq,
    const float* __restrict__ bk, const float* __restrict__ bv,
    unsigned short* __restrict__ xb, unsigned short* __restrict__ Wqkv_t,
    unsigned short* __restrict__ o_proj, unsigned short* __restrict__ o1,
    unsigned short* __restrict__ o2, float* __restrict__ biasq) {
  __shared__ float tile[32][33];
  int bid = blockIdx.x;
  if (bid < 4096) {  // cvt: x f32 -> bf16
    int i = bid * 256 + threadIdx.x;
    float4 v = ((const float4*)x)[i];
    u16x4_a t = {f2b(v.x), f2b(v.y), f2b(v.z), f2b(v.w)};
    ((u16x4_a*)xb)[i] = t;
    return;
  }
  bid -= 4096;
  if (bid < 3072) {  // tqkv
    const int bx = bid & 1, by = (bid >> 1) & 31, zz = bid >> 6;
    const int sel = zz >> 4, zh = zz & 15;
    const float scale = sel == 0 ? 0.18033688f : 1.f;  // q: 1/sqrt(HD)*log2(e)
    const float* ip = (sel == 0 ? wq : (sel == 1 ? wk : wv)) + (size_t)zh * 1024 * 64;
    unsigned short* op = Wqkv_t + (size_t)sel * 1024 * 1024 + (size_t)zh * 1024 * 64;
    const int tx = threadIdx.x & 31, ty = threadIdx.x >> 5;
    const int c0 = bx * 32, r0 = by * 32;
#pragma unroll
    for (int j = 0; j < 32; j += 8)
      tile[ty + j][tx] = ip[(size_t)(r0 + ty + j) * 64 + (c0 + tx)];
    __syncthreads();
#pragma unroll
    for (int j = 0; j < 32; j += 8)
      op[(size_t)(c0 + ty + j) * 1024 + (r0 + tx)] = f2b(tile[tx][ty + j] * scale);
    return;
  }
  bid -= 3072;
  if (bid < 9216) {  // tw
    const float* in;
    unsigned short* out;
    int rows, cols, bx, by;
    if (bid < 1024) {
      in = w_proj; out = o_proj; rows = 1024; cols = 1024; bx = bid & 31; by = bid >> 5;
    } else if (bid < 5120) {
      bid -= 1024; in = w1; out = o1; rows = 1024; cols = 4096; bx = bid & 127; by = bid >> 7;
    } else {
      bid -= 5120; in = w2; out = o2; rows = 4096; cols = 1024; bx = bid & 31; by = bid >> 5;
    }
    const int tx = threadIdx.x & 31, ty = threadIdx.x >> 5;
    const int c0 = bx * 32, r0 = by * 32;
#pragma unroll
    for (int j = 0; j < 32; j += 8)
      tile[ty + j][tx] = in[(size_t)(r0 + ty + j) * cols + (c0 + tx)];
    __syncthreads();
#pragma unroll
    for (int j = 0; j < 32; j += 8)
      out[(size_t)(c0 + ty + j) * rows + (r0 + tx)] = f2b(tile[tx][ty + j]);
    return;
  }
  bid -= 9216;  // bias
  int c = bid * 256 + threadIdx.x;
  int which = c >> 10, idx = c & 1023;
  float v = which == 0 ? bq[idx] : (which == 1 ? bk[idx] : bv[idx]);
  biasq[c] = which == 0 ? v * 0.18033688f : v;
}

// ---------- 256x256 8-phase GEMM (m201 template, plain HIP; R11 epilogues) ----------
// EP 0: QKV scatter + bias. EP 2: bf16 relu. EP 3: bf16 raw partial (split-K).
template <int EP>
__global__ __launch_bounds__(512, 2) void gemm256_kernel(
    const unsigned short* __restrict__ A, const unsigned short* __restrict__ Bt,
    int M, int N, int K, int nbx, int KS,
    const float* __restrict__ bias, unsigned short* __restrict__ outb,
    unsigned short* __restrict__ q_out, unsigned short* __restrict__ k_out,
    unsigned short* __restrict__ v_out,
    unsigned short* __restrict__ pp0, unsigned short* __restrict__ pp1,
    unsigned short* __restrict__ pp2, unsigned short* __restrict__ pp3) {
  __shared__ __align__(16) unsigned short sA[2][256 * 64];
  __shared__ __align__(16) unsigned short sB[2][256 * 64];

  const int tid = threadIdx.x;
  const int wid = tid >> 6, lane = tid & 63;
  const int g = lane >> 4, r15 = lane & 15;
  const int wm = wid >> 2, wn = wid & 3;

  const int nwg = gridDim.x, cpx = nwg >> 3, orig = blockIdx.x;
  const int wg = (orig & 7) * cpx + (orig >> 3);
  const int bx = wg % nbx;
  const int t1 = wg / nbx;
  const int kz = t1 % KS, by = t1 / KS;
  const int row0 = by * 256, col0 = bx * 256;

  const int tilesK = K >> 6;
  const int qT = tilesK / KS, rT = tilesK % KS;
  const int tile0 = kz * qT + (kz < rT ? kz : rT);
  const int NT = qT + (kz < rT ? 1 : 0);
  const int kbase = tile0 << 6;

  const unsigned short* gA0 = A + (size_t)row0 * K + kbase;
  const unsigned short* gB0 = Bt + (size_t)col0 * K + kbase;
  const int srow8 = lane >> 3;
  const int schunk = ((lane & 7) ^ srow8) * 8;

  f32x4 acc[8][4] = {};
  bf16x8 af[4][2], bfr[4][2];

  auto stA = [&](int buf, int k0, int i) {
    const int r = wid * 32 + i * 8;
    GLOAD_LDS16(gA0 + (size_t)(r + srow8) * K + k0 + schunk, &sA[buf][r * 64]);
  };
  auto stB = [&](int buf, int k0, int i) {
    const int r = wid * 32 + i * 8;
    GLOAD_LDS16(gB0 + (size_t)(r + srow8) * K + k0 + schunk, &sB[buf][r * 64]);
  };
  auto ldA = [&](const unsigned short* p, int m, int ks) -> bf16x8 {
    const int row = wm * 128 + m * 16 + r15;
    return *(const bf16x8_a*)&p[row * 64 + (((ks * 4 + g) ^ (r15 & 7)) * 8)];
  };
  auto ldB = [&](const unsigned short* p, int n, int ks) -> bf16x8 {
    const int row = wn * 64 + n * 16 + r15;
    return *(const bf16x8_a*)&p[row * 64 + (((ks * 4 + g) ^ (r15 & 7)) * 8)];
  };

#pragma unroll
  for (int i = 0; i < 4; ++i) { stA(0, 0, i); stB(0, 0, i); }
  asm volatile("s_waitcnt vmcnt(0)" ::: "memory");
  __builtin_amdgcn_s_barrier();

  for (int kt = 0; kt < NT; ++kt) {
    const int cb = kt & 1, nb = cb ^ 1;
    const bool pf = (kt + 1) < NT;
    const int k1 = (kt + 1) << 6;
    const unsigned short* pA = sA[cb];
    const unsigned short* pB = sB[cb];

#pragma unroll
    for (int m = 0; m < 4; ++m) { af[m][0] = ldA(pA, m, 0); af[m][1] = ldA(pA, m, 1); }
#pragma unroll
    for (int n = 0; n < 4; ++n) { bfr[n][0] = ldB(pB, n, 0); bfr[n][1] = ldB(pB, n, 1); }
    if (pf) { stA(nb, k1, 0); stA(nb, k1, 1); }
    __builtin_amdgcn_s_barrier();
    asm volatile("s_waitcnt lgkmcnt(0)" ::: "memory");
    __builtin_amdgcn_sched_barrier(0);
    __builtin_amdgcn_s_setprio(1);
#pragma unroll
    for (int m = 0; m < 4; ++m)
#pragma unroll
      for (int n = 0; n < 2; ++n) {
        acc[m][n] = MFMA_B16(af[m][0], bfr[n][0], acc[m][n]);
        acc[m][n] = MFMA_B16(af[m][1], bfr[n][1], acc[m][n]);
      }
    __builtin_amdgcn_s_setprio(0);
    __builtin_amdgcn_s_barrier();

    if (pf) { stA(nb, k1, 2); stA(nb, k1, 3); }
    __builtin_amdgcn_s_barrier();
    __builtin_amdgcn_s_setprio(1);
#pragma unroll
    for (int m = 0; m < 4; ++m)
#pragma unroll
      for (int n = 2; n < 4; ++n) {
        acc[m][n] = MFMA_B16(af[m][0], bfr[n][0], acc[m][n]);
        acc[m][n] = MFMA_B16(af[m][1], bfr[n][1], acc[m][n]);
      }
    __builtin_amdgcn_s_setprio(0);
    __builtin_amdgcn_s_barrier();

#pragma unroll
    for (int m = 0; m < 4; ++m) { af[m][0] = ldA(pA, m + 4, 0); af[m][1] = ldA(pA, m + 4, 1); }
    if (pf) { stB(nb, k1, 0); stB(nb, k1, 1); }
    __builtin_amdgcn_s_barrier();
    asm volatile("s_waitcnt lgkmcnt(0)" ::: "memory");
    __builtin_amdgcn_sched_barrier(0);
    __builtin_amdgcn_s_setprio(1);
#pragma unroll
    for (int m = 0; m < 4; ++m)
#pragma unroll
      for (int n = 0; n < 2; ++n) {
        acc[m + 4][n] = MFMA_B16(af[m][0], bfr[n][0], acc[m + 4][n]);
        acc[m + 4][n] = MFMA_B16(af[m][1], bfr[n][1], acc[m + 4][n]);
      }
    __builtin_amdgcn_s_setprio(0);
    __builtin_amdgcn_s_barrier();

    if (pf) { stB(nb, k1, 2); stB(nb, k1, 3); }
    __builtin_amdgcn_s_barrier();
    __builtin_amdgcn_s_setprio(1);
#pragma unroll
    for (int m = 0; m < 4; ++m)
#pragma unroll
      for (int n = 2; n < 4; ++n) {
        acc[m + 4][n] = MFMA_B16(af[m][0], bfr[n][0], acc[m + 4][n]);
        acc[m + 4][n] = MFMA_B16(af[m][1], bfr[n][1], acc[m + 4][n]);
      }
    __builtin_amdgcn_s_setprio(0);
    asm volatile("s_waitcnt vmcnt(0)" ::: "memory");
    __builtin_amdgcn_s_barrier();
  }

  unsigned short* pz = kz == 0 ? pp0 : (kz == 1 ? pp1 : (kz == 2 ? pp2 : pp3));
#pragma unroll
  for (int m = 0; m < 8; ++m) {
    const int rbase = row0 + wm * 128 + m * 16 + g * 4;
#pragma unroll
    for (int n = 0; n < 4; ++n) {
      const int col = col0 + wn * 64 + n * 16 + r15;
      const float bb = (EP == 3) ? 0.f : bias[col];
      if constexpr (EP == 0) {
        const int which = col >> 10, cc = col & 1023;
        const int hh = cc >> 6, e = cc & 63;
        const int b = rbase >> 11, s0v = rbase & 2047;
        if (which == 2) {
          bf16x4_a pk;
#pragma unroll
          for (int r = 0; r < 4; ++r) pk[r] = (__bf16)(acc[m][n][r] + bb);
          *(bf16x4_a*)(v_out + (((size_t)(b * 16 + hh) * 64) + e) * 2048 + s0v) = pk;
        } else {
          unsigned short* dst = which == 0 ? q_out : k_out;
#pragma unroll
          for (int r = 0; r < 4; ++r)
            dst[(((size_t)(b * 16 + hh) * 2048) + s0v + r) * 64 + e] =
                f2b(acc[m][n][r] + bb);
        }
      } else {
#pragma unroll
        for (int r = 0; r < 4; ++r) {
          const int row = rbase + r;
          float v = acc[m][n][r] + bb;
          if constexpr (EP == 3) {
            pz[(size_t)row * N + col] = f2b(v);
          } else {
            outb[(size_t)row * N + col] = f2b(v > 0.f ? v : 0.f);
          }
        }
      }
    }
  }
}

// ---------- 128x128 GEMM, split-K over blockIdx.z, bf16 partial out (R11) ----------
__global__ __launch_bounds__(256) void gemm_bt_kernel(
    const unsigned short* __restrict__ A, const unsigned short* __restrict__ Bt,
    int M, int N, int Kchunk, int Kstride,
    unsigned short* __restrict__ pp0, unsigned short* __restrict__ pp1) {
  __shared__ __align__(16) unsigned short sA[2][128 * 32];
  __shared__ __align__(16) unsigned short sB[2][128 * 32];
  const int tid = threadIdx.x;
  const int wid = tid >> 6, lane = tid & 63;
  const int g = lane >> 4, r15 = lane & 15;
  const int wr = wid >> 1, wc = wid & 1;
  const int row0 = blockIdx.y * 128, col0 = blockIdx.x * 128;
  const int kz = blockIdx.z;

  f32x4 acc[4][4] = {};

  const int c0 = wid * 128 + lane;
  const unsigned short* gA0 = A + (size_t)row0 * Kstride + (size_t)kz * Kchunk;
  const unsigned short* gB0 = Bt + (size_t)col0 * Kstride + (size_t)kz * Kchunk;

  auto stage = [&](int buf, int k0) {
#pragma unroll
    for (int j = 0; j < 2; ++j) {
      int c = c0 + j * 64;
      GLOAD_LDS16(gA0 + (size_t)(c >> 2) * Kstride + k0 + (c & 3) * 8,
                  &sA[buf][(wid * 128 + j * 64) * 8]);
      GLOAD_LDS16(gB0 + (size_t)(c >> 2) * Kstride + k0 + (c & 3) * 8,
                  &sB[buf][(wid * 128 + j * 64) * 8]);
    }
  };

  stage(0, 0);
  const int NT = Kchunk >> 5;
  for (int t = 0; t < NT; ++t) {
    const int cb = t & 1;
    __syncthreads();
    if (t + 1 < NT) stage(cb ^ 1, (t + 1) * 32);
    bf16x8 af[4], bfr[4];
#pragma unroll
    for (int m = 0; m < 4; ++m)
      af[m] = *(const bf16x8_a*)&sA[cb][(wr * 64 + m * 16 + r15) * 32 + g * 8];
#pragma unroll
    for (int n = 0; n < 4; ++n)
      bfr[n] = *(const bf16x8_a*)&sB[cb][(wc * 64 + n * 16 + r15) * 32 + g * 8];
#pragma unroll
    for (int m = 0; m < 4; ++m)
#pragma unroll
      for (int n = 0; n < 4; ++n)
        acc[m][n] = MFMA_B16(af[m], bfr[n], acc[m][n]);
  }

  unsigned short* pz = kz == 0 ? pp0 : pp1;
#pragma unroll
  for (int m = 0; m < 4; ++m) {
    const int rbase = row0 + wr * 64 + m * 16 + g * 4;
#pragma unroll
    for (int n = 0; n < 4; ++n) {
      const int col = col0 + wc * 64 + n * 16 + r15;
#pragma unroll
      for (int r = 0; r < 4; ++r)
        pz[(size_t)(rbase + r) * N + col] = f2b(acc[m][n][r]);
    }
  }
}

// ---------- flash attention: K LDS-staged (dbuf), V register-prefetched from L2 ----------
// LDS 24576B -> 5-6 blocks/CU. V issued at tile start, consumed after softmax (T14).
__global__ __launch_bounds__(256) void attn_kernel(const unsigned short* __restrict__ Q,
                                                   const unsigned short* __restrict__ K,
                                                   const unsigned short* __restrict__ Vt,
                                                   unsigned short* __restrict__ out) {
  const int flat = blockIdx.y * gridDim.x + blockIdx.x;  // 0..1023
  const int xcd = flat & 7, rest = flat >> 3;
  const int bh = xcd * 4 + (rest >> 5);
  const int q0 = (rest & 31) * 64;

  const int tid = threadIdx.x, wid = tid >> 6, lane = tid & 63;
  const int g = lane >> 4, r15 = lane & 15;
  const int h = r15 & 7;
  const int s0 = ((g ^ h) * 8);
  const int s1 = (((g + 4) ^ h) * 8);
  const int pswz = r15 & 14;

  __shared__ __align__(16) unsigned short sK[2][64 * 64];
  __shared__ __align__(16) unsigned short sP[4][16 * 64];

  const size_t base = (size_t)bh * (2048 * 64);
  const unsigned short* Kb = K + base;
  const unsigned short* Vb = Vt + base;

  const int qrow = q0 + wid * 16 + r15;
  bf16x8 qf[2];
  qf[0] = *(const bf16x8_a*)(Q + base + (size_t)qrow * 64 + g * 8);
  qf[1] = *(const bf16x8_a*)(Q + base + (size_t)qrow * 64 + 32 + g * 8);

  const int srow = lane >> 3;
  const int schunk = ((lane & 7) ^ srow) * 8;

  union {
    unsigned short u[8];
    bf16x8 v;
  } ou;
#pragma unroll
  for (int i = 0; i < 8; ++i) ou.u[i] = 0x3F80;
  const bf16x8 onesb = ou.v;

  f32x4 o[4] = {};
  float mrow = -1e30f, lrow = 0.f;

  const int krd0 = r15 * 64 + s0;
  const int krd1 = r15 * 64 + s1;
  unsigned short* const pw = &sP[wid][r15 * 64];
  const int pwr0 = ((2 * g) ^ pswz) << 2;
  const int pwr1 = ((8 + 2 * g) ^ pswz) << 2;
  // per-lane V base: row dt*16+r15, two 16B chunks at g*8 and 32+g*8
  const unsigned short* const Vl = Vb + (size_t)r15 * 2048;

  auto stage = [&](int bufi, int kt0s) {
#pragma unroll
    for (int i = 0; i < 2; ++i) {
      const int inst = wid * 2 + i;
      const int row = 8 * inst + srow;
      GLOAD_LDS16(Kb + (size_t)(kt0s + row) * 64 + schunk, &sK[bufi][inst * 512]);
    }
  };

  auto do_tile = [&](const unsigned short* kbuf, int kt0s) {
    // V prefetch from global (L2-resident): issued NOW, consumed after softmax
    bf16x8 vf[4][2];
#pragma unroll
    for (int dt = 0; dt < 4; ++dt) {
      const unsigned short* vr = Vl + (size_t)dt * 16 * 2048 + kt0s;
      vf[dt][0] = *(const bf16x8_a*)(vr + g * 8);
      vf[dt][1] = *(const bf16x8_a*)(vr + 32 + g * 8);
    }

    f32x4 sc[4] = {};
#pragma unroll
    for (int kt = 0; kt < 4; ++kt) {
      bf16x8 kf0 = *(const bf16x8_a*)&kbuf[kt * 1024 + krd0];
      bf16x8 kf1 = *(const bf16x8_a*)&kbuf[kt * 1024 + krd1];
      sc[kt] = MFMA_B16(kf0, qf[0], sc[kt]);
      sc[kt] = MFMA_B16(kf1, qf[1], sc[kt]);
    }

    float a0 = fmaxf(fmaxf(sc[0][0], sc[0][1]), sc[0][2]);
    float a1 = fmaxf(fmaxf(sc[0][3], sc[1][0]), sc[1][1]);
    float a2 = fmaxf(fmaxf(sc[1][2], sc[1][3]), sc[2][0]);
    float a3 = fmaxf(fmaxf(sc[2][1], sc[2][2]), sc[2][3]);
    float a4 = fmaxf(fmaxf(sc[3][0], sc[3][1]), sc[3][2]);
    float b0 = fmaxf(fmaxf(a0, a1), a2);
    float b1 = fmaxf(fmaxf(a3, a4), sc[3][3]);
    float pmax = fmaxf(b0, b1);
    pmax = fmaxf(pmax, __shfl_xor(pmax, 16));
    pmax = fmaxf(pmax, __shfl_xor(pmax, 32));

    const bool allkeep = __all(pmax - mrow <= 11.5441f);
    float fac;
    if (allkeep) {
      fac = 1.0f;
    } else {
      float nm = fmaxf(mrow, pmax);
      fac = EXP2(mrow - nm);
      mrow = nm;
#pragma unroll
      for (int dt = 0; dt < 4; ++dt)
#pragma unroll
        for (int r = 0; r < 4; ++r) o[dt][r] *= fac;
    }

#pragma unroll
    for (int kt = 0; kt < 4; ++kt) {
      bf16x4_a pb;
      pb[0] = (__bf16)EXP2(sc[kt][0] - mrow);
      pb[1] = (__bf16)EXP2(sc[kt][1] - mrow);
      pb[2] = (__bf16)EXP2(sc[kt][2] - mrow);
      pb[3] = (__bf16)EXP2(sc[kt][3] - mrow);
      *(bf16x4_a*)&pw[((4 * kt + g) ^ pswz) << 2] = pb;
    }

    bf16x8 pf0 = *(const bf16x8_a*)&pw[pwr0];
    bf16x8 pf1 = *(const bf16x8_a*)&pw[pwr1];

    f32x4 lacc = {};
    lacc = MFMA_B16(onesb, pf0, lacc);
    lacc = MFMA_B16(onesb, pf1, lacc);
    lrow = lrow * fac + lacc[0];

#pragma unroll
    for (int dt = 0; dt < 4; ++dt) {
      o[dt] = MFMA_B16(vf[dt][0], pf0, o[dt]);
      o[dt] = MFMA_B16(vf[dt][1], pf1, o[dt]);
    }
  };

  stage(0, 0);
#pragma unroll 1
  for (int t = 0; t < 32; t += 2) {
    __syncthreads();
    stage(1, (t + 1) * 64);
    do_tile(&sK[0][0], t * 64);
    __syncthreads();
    if (t + 2 < 32) stage(0, (t + 2) * 64);
    do_tile(&sK[1][0], (t + 1) * 64);
  }

  const int b = bh >> 4, hh = bh & 15;
  const int s = q0 + wid * 16 + r15;
  const float inv = 1.f / lrow;
  unsigned short* orow = out + ((size_t)(b * 2048 + s)) * 1024 + hh * 64;
#pragma unroll
  for (int dt = 0; dt < 4; ++dt) {
    bf16x4_a tq;
    tq[0] = (__bf16)(o[dt][0] * inv);
    tq[1] = (__bf16)(o[dt][1] * inv);
    tq[2] = (__bf16)(o[dt][2] * inv);
    tq[3] = (__bf16)(o[dt][3] * inv);
    *(bf16x4_a*)(orow + dt * 16 + g * 4) = tq;
  }
}

// ---------- fused 2x bf16-partial reduce + bias + residual + LN -> f32 + bf16 ----------
__global__ __launch_bounds__(256) void ln2p_kernel(
    const unsigned short* __restrict__ p0, const unsigned short* __restrict__ p1,
    const float* __restrict__ bias, const float* __restrict__ resid,
    const float* __restrict__ gamma, const float* __restrict__ beta,
    float* __restrict__ outf, unsigned short* __restrict__ outb) {
  const int row = blockIdx.x, tid = threadIdx.x;
  const size_t off = (size_t)row * 1024;
  u16x4_a a4 = *(const u16x4_a*)(p0 + off + tid * 4);
  u16x4_a b4 = *(const u16x4_a*)(p1 + off + tid * 4);
  float4 bb4 = ((const float4*)bias)[tid];
  float4 rr = ((const float4*)(resid + off))[tid];
  float4 v;
  v.x = b2f(a4[0]) + b2f(b4[0]) + bb4.x + rr.x;
  v.y = b2f(a4[1]) + b2f(b4[1]) + bb4.y + rr.y;
  v.z = b2f(a4[2]) + b2f(b4[2]) + bb4.z + rr.z;
  v.w = b2f(a4[3]) + b2f(b4[3]) + bb4.w + rr.w;

  float s = v.x + v.y + v.z + v.w;
  float ss = v.x * v.x + v.y * v.y + v.z * v.z + v.w * v.w;
#pragma unroll
  for (int o2 = 32; o2 > 0; o2 >>= 1) {
    s += __shfl_down(s, o2);
    ss += __shfl_down(ss, o2);
  }
  __shared__ float red[8];
  const int wid = tid >> 6;
  if ((tid & 63) == 0) { red[wid] = s; red[4 + wid] = ss; }
  __syncthreads();
  float S = red[0] + red[1] + red[2] + red[3];
  float SS = red[4] + red[5] + red[6] + red[7];
  const float mean = S * (1.f / 1024.f);
  const float var = SS * (1.f / 1024.f) - mean * mean;
  const float inv = 1.f / sqrtf(var + 1e-10f);
  float4 gg = ((const float4*)gamma)[tid];
  float4 be = ((const float4*)beta)[tid];
  float4 o;
  o.x = (v.x - mean) * inv * gg.x + be.x;
  o.y = (v.y - mean) * inv * gg.y + be.y;
  o.z = (v.z - mean) * inv * gg.z + be.z;
  o.w = (v.w - mean) * inv * gg.w + be.w;
  ((float4*)(outf + off))[tid] = o;
  u16x4_a t = {f2b(o.x), f2b(o.y), f2b(o.z), f2b(o.w)};
  *(u16x4_a*)(outb + off + tid * 4) = t;
}

// ---------- fused 4x bf16-partial reduce + bias + residual + LN -> f32 ----------
__global__ __launch_bounds__(256) void ln4p_kernel(
    const unsigned short* __restrict__ p0, const unsigned short* __restrict__ p1,
    const unsigned short* __restrict__ p2, const unsigned short* __restrict__ p3,
    const float* __restrict__ bias, const float* __restrict__ resid,
    const float* __restrict__ gamma, const float* __restrict__ beta,
    float* __restrict__ outf) {
  const int row = blockIdx.x, tid = threadIdx.x;
  const size_t off = (size_t)row * 1024;
  u16x4_a a4 = *(const u16x4_a*)(p0 + off + tid * 4);
  u16x4_a b4 = *(const u16x4_a*)(p1 + off + tid * 4);
  u16x4_a c4 = *(const u16x4_a*)(p2 + off + tid * 4);
  u16x4_a d4 = *(const u16x4_a*)(p3 + off + tid * 4);
  float4 bb4 = ((const float4*)bias)[tid];
  float4 rr = ((const float4*)(resid + off))[tid];
  float4 v;
  v.x = (b2f(a4[0]) + b2f(b4[0])) + (b2f(c4[0]) + b2f(d4[0])) + bb4.x + rr.x;
  v.y = (b2f(a4[1]) + b2f(b4[1])) + (b2f(c4[1]) + b2f(d4[1])) + bb4.y + rr.y;
  v.z = (b2f(a4[2]) + b2f(b4[2])) + (b2f(c4[2]) + b2f(d4[2])) + bb4.z + rr.z;
  v.w = (b2f(a4[3]) + b2f(b4[3])) + (b2f(c4[3]) + b2f(d4[3])) + bb4.w + rr.w;

  float s = v.x + v.y + v.z + v.w;
  float ss = v.x * v.x + v.y * v.y + v.z * v.z + v.w * v.w;
#pragma unroll
  for (int o2 = 32; o2 > 0; o2 >>= 1) {
    s += __shfl_down(s, o2);
    ss += __shfl_down(ss, o2);
  }
  __shared__ float red[8];
  const int wid = tid >> 6;
  if ((tid & 63) == 0) { red[wid] = s; red[4 + wid] = ss; }
  __syncthreads();
  float S = red[0] + red[1] + red[2] + red[3];
  float SS = red[4] + red[5] + red[6] + red[7];
  const float mean = S * (1.f / 1024.f);
  const float var = SS * (1.f / 1024.f) - mean * mean;
  const float inv = 1.f / sqrtf(var + 1e-10f);
  float4 gg = ((const float4*)gamma)[tid];
  float4 be = ((const float4*)beta)[tid];
  float4 o;
  o.x = (v.x - mean) * inv * gg.x + be.x;
  o.y = (v.y - mean) * inv * gg.y + be.y;
  o.z = (v.z - mean) * inv * gg.z + be.z;
  o.w = (v.w - mean) * inv * gg.w + be.w;
  ((float4*)(outf + off))[tid] = o;
}

// ---------- launch ----------
extern "C" void kernel_launch(void* const* d_in, const int* in_sizes, int n_in,
                              void* d_out, int out_size, void* d_ws, size_t ws_size,
                              hipStream_t stream) {
  const float* x      = (const float*)d_in[0];
  const float* wq     = (const float*)d_in[1];
  const float* bq     = (const float*)d_in[2];
  const float* wk     = (const float*)d_in[3];
  const float* bk     = (const float*)d_in[4];
  const float* wv     = (const float*)d_in[5];
  const float* bv     = (const float*)d_in[6];
  const float* w_proj = (const float*)d_in[7];
  const float* b_proj = (const float*)d_in[8];
  const float* gamma1 = (const float*)d_in[9];
  const float* beta1  = (const float*)d_in[10];
  const float* w1     = (const float*)d_in[11];
  const float* b1     = (const float*)d_in[12];
  const float* w2     = (const float*)d_in[13];
  const float* b2     = (const float*)d_in[14];
  const float* gamma2 = (const float*)d_in[15];
  const float* beta2  = (const float*)d_in[16];

  char* p = (char*)d_ws;
  auto alloc = [&](size_t bytes) {
    char* r = p;
    p += (bytes + 255) & ~(size_t)255;
    return r;
  };
  unsigned short* xb      = (unsigned short*)alloc(4096ull * 1024 * 2);  // 8MB; dead after proj
  unsigned short* Wqkv_t  = (unsigned short*)alloc(3072ull * 1024 * 2);  // 6MB; dead after QKV
  unsigned short* Wproj_t = (unsigned short*)alloc(1024ull * 1024 * 2);  // 2MB; dead after proj
  unsigned short* W2t     = (unsigned short*)alloc(1024ull * 4096 * 2);  // 8MB; live thru FFN2
  float*          biasq   = (float*)alloc(3072 * 4);
  unsigned short* Qb      = (unsigned short*)alloc(4096ull * 1024 * 2);  // 8MB; dead after attn
  unsigned short* Kb      = (unsigned short*)alloc(4096ull * 1024 * 2);  // 8MB; dead after attn
  unsigned short* Vtb     = (unsigned short*)alloc(4096ull * 1024 * 2);  // 8MB; dead after attn
  unsigned short* W1t     = (unsigned short*)alloc(4096ull * 1024 * 2);  // 8MB; dead after FFN1
  float*          out1f   = (float*)alloc(4096ull * 1024 * 4);           // live thru ln4p
  unsigned short* out1b   = (unsigned short*)alloc(4096ull * 1024 * 2);  // dead after FFN1
  unsigned short* ffn_h   = (unsigned short*)alloc(4096ull * 4096 * 2);  // live thru FFN2
  unsigned short* concat  = xb;

  unsigned short* prA = Qb;
  unsigned short* prB = Kb;
  unsigned short* pp0 = xb;
  unsigned short* pp1 = Qb;
  unsigned short* pp2 = Kb;
  unsigned short* pp3 = Vtb;

  prepass_kernel<<<16396, 256, 0, stream>>>(x, wq, wk, wv, w_proj, w1, w2, bq, bk, bv,
                                            xb, Wqkv_t, Wproj_t, W1t, W2t, biasq);

  gemm256_kernel<0><<<192, 512, 0, stream>>>(xb, Wqkv_t, 4096, 3072, 1024, 12, 1, biasq,
                                             nullptr, Qb, Kb, Vtb, nullptr, nullptr,
                                             nullptr, nullptr);
  attn_kernel<<<dim3(32, 32), 256, 0, stream>>>(Qb, Kb, Vtb, concat);
  gemm_bt_kernel<<<dim3(8, 32, 2), 256, 0, stream>>>(concat, Wproj_t, 4096, 1024, 512, 1024,
                                                     prA, prB);
  ln2p_kernel<<<4096, 256, 0, stream>>>(prA, prB, b_proj, x, gamma1, beta1, out1f, out1b);
  gemm256_kernel<2><<<256, 512, 0, stream>>>(out1b, W1t, 4096, 4096, 1024, 16, 1, b1,
                                             ffn_h, nullptr, nullptr, nullptr,
                                             nullptr, nullptr, nullptr, nullptr);
  gemm256_kernel<3><<<256, 512, 0, stream>>>(ffn_h, W2t, 4096, 1024, 4096, 4, 4, nullptr,
                                             nullptr, nullptr, nullptr, nullptr,
                                             pp0, pp1, pp2, pp3);
  ln4p_kernel<<<4096, 256, 0, stream>>>(pp0, pp1, pp2, pp3, b2, out1f, gamma2, beta2,
                                        (float*)d_out);
}

// Round 14
// 244.274 us; speedup vs baseline: 1.3735x; 1.3735x over previous
//
#include <hip/hip_runtime.h>
#include <stdint.h>

// ---------- types ----------
typedef float f32x4 __attribute__((ext_vector_type(4)));
typedef __bf16 bf16x8 __attribute__((ext_vector_type(8)));
typedef __bf16 bf16x8_a __attribute__((ext_vector_type(8), may_alias));
typedef __bf16 bf16x4_a __attribute__((ext_vector_type(4), may_alias));
typedef unsigned int u32x4_a __attribute__((ext_vector_type(4), may_alias));
typedef unsigned short u16x4_a __attribute__((ext_vector_type(4), may_alias));
typedef unsigned long long u64;

#define DEV __device__ __forceinline__
#define MFMA_B16(a, b, c) __builtin_amdgcn_mfma_f32_16x16x32_bf16((a), (b), (c), 0, 0, 0)

#if __has_builtin(__builtin_amdgcn_exp2f)
#define EXP2(x) __builtin_amdgcn_exp2f(x)
#else
#define EXP2(x) exp2f(x)
#endif

DEV unsigned short f2b(float f) {  // f32 -> bf16 RNE
  unsigned int u = __float_as_uint(f);
  u = u + 0x7FFFu + ((u >> 16) & 1u);
  return (unsigned short)(u >> 16);
}
DEV float b2f(unsigned short u) { return __uint_as_float(((unsigned int)u) << 16); }

// async global->LDS, 16B per lane; LDS dest is wave-uniform base + lane*16
#define GLOAD_LDS16(gsrc, ldst)                                                  \
  __builtin_amdgcn_global_load_lds(                                              \
      (__attribute__((address_space(1))) void*)(uintptr_t)(const void*)(gsrc),   \
      (__attribute__((address_space(3))) void*)(ldst), 16, 0, 0)

// ---------- fused prepass: cvt x | transpose wq/wk/wv | transpose w_proj/w1/w2 | bias ----------
__global__ __launch_bounds__(256) void prepass_kernel(
    const float* __restrict__ x, const float* __restrict__ wq,
    const float* __restrict__ wk, const float* __restrict__ wv,
    const float* __restrict__ w_proj, const float* __restrict__ w1,
    const float* __restrict__ w2, const float* __restrict__ bq,
    const float* __restrict__ bk, const float* __restrict__ bv,
    unsigned short* __restrict__ xb, unsigned short* __restrict__ Wqkv_t,
    unsigned short* __restrict__ o_proj, unsigned short* __restrict__ o1,
    unsigned short* __restrict__ o2, float* __restrict__ biasq) {
  __shared__ float tile[32][33];
  int bid = blockIdx.x;
  if (bid < 4096) {  // cvt: x f32 -> bf16
    int i = bid * 256 + threadIdx.x;
    float4 v = ((const float4*)x)[i];
    u16x4_a t = {f2b(v.x), f2b(v.y), f2b(v.z), f2b(v.w)};
    ((u16x4_a*)xb)[i] = t;
    return;
  }
  bid -= 4096;
  if (bid < 3072) {  // tqkv
    const int bx = bid & 1, by = (bid >> 1) & 31, zz = bid >> 6;
    const int sel = zz >> 4, zh = zz & 15;
    const float scale = sel == 0 ? 0.18033688f : 1.f;  // q: 1/sqrt(HD)*log2(e)
    const float* ip = (sel == 0 ? wq : (sel == 1 ? wk : wv)) + (size_t)zh * 1024 * 64;
    unsigned short* op = Wqkv_t + (size_t)sel * 1024 * 1024 + (size_t)zh * 1024 * 64;
    const int tx = threadIdx.x & 31, ty = threadIdx.x >> 5;
    const int c0 = bx * 32, r0 = by * 32;
#pragma unroll
    for (int j = 0; j < 32; j += 8)
      tile[ty + j][tx] = ip[(size_t)(r0 + ty + j) * 64 + (c0 + tx)];
    __syncthreads();
#pragma unroll
    for (int j = 0; j < 32; j += 8)
      op[(size_t)(c0 + ty + j) * 1024 + (r0 + tx)] = f2b(tile[tx][ty + j] * scale);
    return;
  }
  bid -= 3072;
  if (bid < 9216) {  // tw
    const float* in;
    unsigned short* out;
    int rows, cols, bx, by;
    if (bid < 1024) {
      in = w_proj; out = o_proj; rows = 1024; cols = 1024; bx = bid & 31; by = bid >> 5;
    } else if (bid < 5120) {
      bid -= 1024; in = w1; out = o1; rows = 1024; cols = 4096; bx = bid & 127; by = bid >> 7;
    } else {
      bid -= 5120; in = w2; out = o2; rows = 4096; cols = 1024; bx = bid & 31; by = bid >> 5;
    }
    const int tx = threadIdx.x & 31, ty = threadIdx.x >> 5;
    const int c0 = bx * 32, r0 = by * 32;
#pragma unroll
    for (int j = 0; j < 32; j += 8)
      tile[ty + j][tx] = in[(size_t)(r0 + ty + j) * cols + (c0 + tx)];
    __syncthreads();
#pragma unroll
    for (int j = 0; j < 32; j += 8)
      out[(size_t)(c0 + ty + j) * rows + (r0 + tx)] = f2b(tile[tx][ty + j]);
    return;
  }
  bid -= 9216;  // bias
  int c = bid * 256 + threadIdx.x;
  int which = c >> 10, idx = c & 1023;
  float v = which == 0 ? bq[idx] : (which == 1 ? bk[idx] : bv[idx]);
  biasq[c] = which == 0 ? v * 0.18033688f : v;
}

// ---------- 256x256 8-phase GEMM (m201 template, plain HIP; R11 epilogues) ----------
// EP 0: QKV scatter + bias. EP 2: bf16 relu. EP 3: bf16 raw partial (split-K).
template <int EP>
__global__ __launch_bounds__(512, 2) void gemm256_kernel(
    const unsigned short* __restrict__ A, const unsigned short* __restrict__ Bt,
    int M, int N, int K, int nbx, int KS,
    const float* __restrict__ bias, unsigned short* __restrict__ outb,
    unsigned short* __restrict__ q_out, unsigned short* __restrict__ k_out,
    unsigned short* __restrict__ v_out,
    unsigned short* __restrict__ pp0, unsigned short* __restrict__ pp1,
    unsigned short* __restrict__ pp2, unsigned short* __restrict__ pp3) {
  __shared__ __align__(16) unsigned short sA[2][256 * 64];
  __shared__ __align__(16) unsigned short sB[2][256 * 64];

  const int tid = threadIdx.x;
  const int wid = tid >> 6, lane = tid & 63;
  const int g = lane >> 4, r15 = lane & 15;
  const int wm = wid >> 2, wn = wid & 3;

  const int nwg = gridDim.x, cpx = nwg >> 3, orig = blockIdx.x;
  const int wg = (orig & 7) * cpx + (orig >> 3);
  const int bx = wg % nbx;
  const int t1 = wg / nbx;
  const int kz = t1 % KS, by = t1 / KS;
  const int row0 = by * 256, col0 = bx * 256;

  const int tilesK = K >> 6;
  const int qT = tilesK / KS, rT = tilesK % KS;
  const int tile0 = kz * qT + (kz < rT ? kz : rT);
  const int NT = qT + (kz < rT ? 1 : 0);
  const int kbase = tile0 << 6;

  const unsigned short* gA0 = A + (size_t)row0 * K + kbase;
  const unsigned short* gB0 = Bt + (size_t)col0 * K + kbase;
  const int srow8 = lane >> 3;
  const int schunk = ((lane & 7) ^ srow8) * 8;

  f32x4 acc[8][4] = {};
  bf16x8 af[4][2], bfr[4][2];

  auto stA = [&](int buf, int k0, int i) {
    const int r = wid * 32 + i * 8;
    GLOAD_LDS16(gA0 + (size_t)(r + srow8) * K + k0 + schunk, &sA[buf][r * 64]);
  };
  auto stB = [&](int buf, int k0, int i) {
    const int r = wid * 32 + i * 8;
    GLOAD_LDS16(gB0 + (size_t)(r + srow8) * K + k0 + schunk, &sB[buf][r * 64]);
  };
  auto ldA = [&](const unsigned short* p, int m, int ks) -> bf16x8 {
    const int row = wm * 128 + m * 16 + r15;
    return *(const bf16x8_a*)&p[row * 64 + (((ks * 4 + g) ^ (r15 & 7)) * 8)];
  };
  auto ldB = [&](const unsigned short* p, int n, int ks) -> bf16x8 {
    const int row = wn * 64 + n * 16 + r15;
    return *(const bf16x8_a*)&p[row * 64 + (((ks * 4 + g) ^ (r15 & 7)) * 8)];
  };

#pragma unroll
  for (int i = 0; i < 4; ++i) { stA(0, 0, i); stB(0, 0, i); }
  asm volatile("s_waitcnt vmcnt(0)" ::: "memory");
  __builtin_amdgcn_s_barrier();

  for (int kt = 0; kt < NT; ++kt) {
    const int cb = kt & 1, nb = cb ^ 1;
    const bool pf = (kt + 1) < NT;
    const int k1 = (kt + 1) << 6;
    const unsigned short* pA = sA[cb];
    const unsigned short* pB = sB[cb];

#pragma unroll
    for (int m = 0; m < 4; ++m) { af[m][0] = ldA(pA, m, 0); af[m][1] = ldA(pA, m, 1); }
#pragma unroll
    for (int n = 0; n < 4; ++n) { bfr[n][0] = ldB(pB, n, 0); bfr[n][1] = ldB(pB, n, 1); }
    if (pf) { stA(nb, k1, 0); stA(nb, k1, 1); }
    __builtin_amdgcn_s_barrier();
    asm volatile("s_waitcnt lgkmcnt(0)" ::: "memory");
    __builtin_amdgcn_sched_barrier(0);
    __builtin_amdgcn_s_setprio(1);
#pragma unroll
    for (int m = 0; m < 4; ++m)
#pragma unroll
      for (int n = 0; n < 2; ++n) {
        acc[m][n] = MFMA_B16(af[m][0], bfr[n][0], acc[m][n]);
        acc[m][n] = MFMA_B16(af[m][1], bfr[n][1], acc[m][n]);
      }
    __builtin_amdgcn_s_setprio(0);
    __builtin_amdgcn_s_barrier();

    if (pf) { stA(nb, k1, 2); stA(nb, k1, 3); }
    __builtin_amdgcn_s_barrier();
    __builtin_amdgcn_s_setprio(1);
#pragma unroll
    for (int m = 0; m < 4; ++m)
#pragma unroll
      for (int n = 2; n < 4; ++n) {
        acc[m][n] = MFMA_B16(af[m][0], bfr[n][0], acc[m][n]);
        acc[m][n] = MFMA_B16(af[m][1], bfr[n][1], acc[m][n]);
      }
    __builtin_amdgcn_s_setprio(0);
    __builtin_amdgcn_s_barrier();

#pragma unroll
    for (int m = 0; m < 4; ++m) { af[m][0] = ldA(pA, m + 4, 0); af[m][1] = ldA(pA, m + 4, 1); }
    if (pf) { stB(nb, k1, 0); stB(nb, k1, 1); }
    __builtin_amdgcn_s_barrier();
    asm volatile("s_waitcnt lgkmcnt(0)" ::: "memory");
    __builtin_amdgcn_sched_barrier(0);
    __builtin_amdgcn_s_setprio(1);
#pragma unroll
    for (int m = 0; m < 4; ++m)
#pragma unroll
      for (int n = 0; n < 2; ++n) {
        acc[m + 4][n] = MFMA_B16(af[m][0], bfr[n][0], acc[m + 4][n]);
        acc[m + 4][n] = MFMA_B16(af[m][1], bfr[n][1], acc[m + 4][n]);
      }
    __builtin_amdgcn_s_setprio(0);
    __builtin_amdgcn_s_barrier();

    if (pf) { stB(nb, k1, 2); stB(nb, k1, 3); }
    __builtin_amdgcn_s_barrier();
    __builtin_amdgcn_s_setprio(1);
#pragma unroll
    for (int m = 0; m < 4; ++m)
#pragma unroll
      for (int n = 2; n < 4; ++n) {
        acc[m + 4][n] = MFMA_B16(af[m][0], bfr[n][0], acc[m + 4][n]);
        acc[m + 4][n] = MFMA_B16(af[m][1], bfr[n][1], acc[m + 4][n]);
      }
    __builtin_amdgcn_s_setprio(0);
    asm volatile("s_waitcnt vmcnt(0)" ::: "memory");
    __builtin_amdgcn_s_barrier();
  }

  unsigned short* pz = kz == 0 ? pp0 : (kz == 1 ? pp1 : (kz == 2 ? pp2 : pp3));
#pragma unroll
  for (int m = 0; m < 8; ++m) {
    const int rbase = row0 + wm * 128 + m * 16 + g * 4;
#pragma unroll
    for (int n = 0; n < 4; ++n) {
      const int col = col0 + wn * 64 + n * 16 + r15;
      const float bb = (EP == 3) ? 0.f : bias[col];
      if constexpr (EP == 0) {
        const int which = col >> 10, cc = col & 1023;
        const int hh = cc >> 6, e = cc & 63;
        const int b = rbase >> 11, s0v = rbase & 2047;
        if (which == 2) {
          bf16x4_a pk;
#pragma unroll
          for (int r = 0; r < 4; ++r) pk[r] = (__bf16)(acc[m][n][r] + bb);
          *(bf16x4_a*)(v_out + (((size_t)(b * 16 + hh) * 64) + e) * 2048 + s0v) = pk;
        } else {
          unsigned short* dst = which == 0 ? q_out : k_out;
#pragma unroll
          for (int r = 0; r < 4; ++r)
            dst[(((size_t)(b * 16 + hh) * 2048) + s0v + r) * 64 + e] =
                f2b(acc[m][n][r] + bb);
        }
      } else {
#pragma unroll
        for (int r = 0; r < 4; ++r) {
          const int row = rbase + r;
          float v = acc[m][n][r] + bb;
          if constexpr (EP == 3) {
            pz[(size_t)row * N + col] = f2b(v);
          } else {
            outb[(size_t)row * N + col] = f2b(v > 0.f ? v : 0.f);
          }
        }
      }
    }
  }
}

// ---------- 128x128 GEMM, split-K over blockIdx.z, bf16 partial out (R11) ----------
__global__ __launch_bounds__(256) void gemm_bt_kernel(
    const unsigned short* __restrict__ A, const unsigned short* __restrict__ Bt,
    int M, int N, int Kchunk, int Kstride,
    unsigned short* __restrict__ pp0, unsigned short* __restrict__ pp1) {
  __shared__ __align__(16) unsigned short sA[2][128 * 32];
  __shared__ __align__(16) unsigned short sB[2][128 * 32];
  const int tid = threadIdx.x;
  const int wid = tid >> 6, lane = tid & 63;
  const int g = lane >> 4, r15 = lane & 15;
  const int wr = wid >> 1, wc = wid & 1;
  const int row0 = blockIdx.y * 128, col0 = blockIdx.x * 128;
  const int kz = blockIdx.z;

  f32x4 acc[4][4] = {};

  const int c0 = wid * 128 + lane;
  const unsigned short* gA0 = A + (size_t)row0 * Kstride + (size_t)kz * Kchunk;
  const unsigned short* gB0 = Bt + (size_t)col0 * Kstride + (size_t)kz * Kchunk;

  auto stage = [&](int buf, int k0) {
#pragma unroll
    for (int j = 0; j < 2; ++j) {
      int c = c0 + j * 64;
      GLOAD_LDS16(gA0 + (size_t)(c >> 2) * Kstride + k0 + (c & 3) * 8,
                  &sA[buf][(wid * 128 + j * 64) * 8]);
      GLOAD_LDS16(gB0 + (size_t)(c >> 2) * Kstride + k0 + (c & 3) * 8,
                  &sB[buf][(wid * 128 + j * 64) * 8]);
    }
  };

  stage(0, 0);
  const int NT = Kchunk >> 5;
  for (int t = 0; t < NT; ++t) {
    const int cb = t & 1;
    __syncthreads();
    if (t + 1 < NT) stage(cb ^ 1, (t + 1) * 32);
    bf16x8 af[4], bfr[4];
#pragma unroll
    for (int m = 0; m < 4; ++m)
      af[m] = *(const bf16x8_a*)&sA[cb][(wr * 64 + m * 16 + r15) * 32 + g * 8];
#pragma unroll
    for (int n = 0; n < 4; ++n)
      bfr[n] = *(const bf16x8_a*)&sB[cb][(wc * 64 + n * 16 + r15) * 32 + g * 8];
#pragma unroll
    for (int m = 0; m < 4; ++m)
#pragma unroll
      for (int n = 0; n < 4; ++n)
        acc[m][n] = MFMA_B16(af[m], bfr[n], acc[m][n]);
  }

  unsigned short* pz = kz == 0 ? pp0 : pp1;
#pragma unroll
  for (int m = 0; m < 4; ++m) {
    const int rbase = row0 + wr * 64 + m * 16 + g * 4;
#pragma unroll
    for (int n = 0; n < 4; ++n) {
      const int col = col0 + wc * 64 + n * 16 + r15;
#pragma unroll
      for (int r = 0; r < 4; ++r)
        pz[(size_t)(rbase + r) * N + col] = f2b(acc[m][n][r]);
    }
  }
}

// ---------- flash attention: R11 structure (K/V LDS dbuf) + sP removed ----------
// P exchange fully in-register: stage1 shfl_xor(16) within (g,g^1) pairs, stage2
// pull from lane L=((g&1)<<1)|(g>>1). LDS 32768B -> 5 blocks/CU.
// Derivation: lane holds w[kt]=P[keys kt*16+g*4..+3][q=r15] (packed bf16x4).
// pf0 needs keys g*8..g*8+7 = w_{2(g&1)}[g>>1] ++ w_{2(g&1)+1}[g>>1];
// pf1 = same sources at kt+2. Verified per-lane for g=0..3.
__global__ __launch_bounds__(256) void attn_kernel(const unsigned short* __restrict__ Q,
                                                   const unsigned short* __restrict__ K,
                                                   const unsigned short* __restrict__ Vt,
                                                   unsigned short* __restrict__ out) {
  const int flat = blockIdx.y * gridDim.x + blockIdx.x;  // 0..1023
  const int xcd = flat & 7, rest = flat >> 3;
  const int bh = xcd * 4 + (rest >> 5);
  const int q0 = (rest & 31) * 64;

  const int tid = threadIdx.x, wid = tid >> 6, lane = tid & 63;
  const int g = lane >> 4, r15 = lane & 15;
  const int h = r15 & 7;
  const int s0 = ((g ^ h) * 8);
  const int s1 = (((g + 4) ^ h) * 8);

  __shared__ __align__(16) unsigned short sK[2][64 * 64];
  __shared__ __align__(16) unsigned short sV[2][64 * 64];

  const size_t base = (size_t)bh * (2048 * 64);
  const unsigned short* Kb = K + base;
  const unsigned short* Vb = Vt + base;

  const int qrow = q0 + wid * 16 + r15;
  bf16x8 qf[2];
  qf[0] = *(const bf16x8_a*)(Q + base + (size_t)qrow * 64 + g * 8);
  qf[1] = *(const bf16x8_a*)(Q + base + (size_t)qrow * 64 + 32 + g * 8);

  const int srow = lane >> 3;
  const int schunk = ((lane & 7) ^ srow) * 8;

  union {
    unsigned short u[8];
    bf16x8 v;
  } ou;
#pragma unroll
  for (int i = 0; i < 8; ++i) ou.u[i] = 0x3F80;
  const bf16x8 onesb = ou.v;

  f32x4 o[4] = {};
  float mrow = -1e30f, lrow = 0.f;

  const int krd0 = r15 * 64 + s0;
  const int krd1 = r15 * 64 + s1;
  const bool godd = (g & 1) != 0;
  const int xsrc = ((((g & 1) << 1) | (g >> 1)) << 4) + r15;  // stage-2 source lane

  auto stage = [&](int bufi, int kt0s) {
#pragma unroll
    for (int i = 0; i < 2; ++i) {
      const int inst = wid * 2 + i;
      const int row = 8 * inst + srow;
      GLOAD_LDS16(Kb + (size_t)(kt0s + row) * 64 + schunk, &sK[bufi][inst * 512]);
      GLOAD_LDS16(Vb + (size_t)row * 2048 + kt0s + schunk, &sV[bufi][inst * 512]);
    }
  };

  auto do_tile = [&](const unsigned short* kbuf, const unsigned short* vbuf) {
    f32x4 sc[4] = {};
#pragma unroll
    for (int kt = 0; kt < 4; ++kt) {
      bf16x8 kf0 = *(const bf16x8_a*)&kbuf[kt * 1024 + krd0];
      bf16x8 kf1 = *(const bf16x8_a*)&kbuf[kt * 1024 + krd1];
      sc[kt] = MFMA_B16(kf0, qf[0], sc[kt]);
      sc[kt] = MFMA_B16(kf1, qf[1], sc[kt]);
    }

    float a0 = fmaxf(fmaxf(sc[0][0], sc[0][1]), sc[0][2]);
    float a1 = fmaxf(fmaxf(sc[0][3], sc[1][0]), sc[1][1]);
    float a2 = fmaxf(fmaxf(sc[1][2], sc[1][3]), sc[2][0]);
    float a3 = fmaxf(fmaxf(sc[2][1], sc[2][2]), sc[2][3]);
    float a4 = fmaxf(fmaxf(sc[3][0], sc[3][1]), sc[3][2]);
    float b0 = fmaxf(fmaxf(a0, a1), a2);
    float b1 = fmaxf(fmaxf(a3, a4), sc[3][3]);
    float pmax = fmaxf(b0, b1);
    pmax = fmaxf(pmax, __shfl_xor(pmax, 16));
    pmax = fmaxf(pmax, __shfl_xor(pmax, 32));

    const bool allkeep = __all(pmax - mrow <= 11.5441f);
    float fac;
    if (allkeep) {
      fac = 1.0f;
    } else {
      float nm = fmaxf(mrow, pmax);
      fac = EXP2(mrow - nm);
      mrow = nm;
#pragma unroll
      for (int dt = 0; dt < 4; ++dt)
#pragma unroll
        for (int r = 0; r < 4; ++r) o[dt][r] *= fac;
    }

    // P = exp2(S - m), packed bf16x4 per kt (keys kt*16+g*4..+3, q=r15)
    u64 w[4];
#pragma unroll
    for (int kt = 0; kt < 4; ++kt) {
      union {
        bf16x4_a b;
        u64 u;
      } pk;
      pk.b[0] = (__bf16)EXP2(sc[kt][0] - mrow);
      pk.b[1] = (__bf16)EXP2(sc[kt][1] - mrow);
      pk.b[2] = (__bf16)EXP2(sc[kt][2] - mrow);
      pk.b[3] = (__bf16)EXP2(sc[kt][3] - mrow);
      w[kt] = pk.u;
    }
    // stage 1: exchange kt-halves within (g, g^1) pair (lane xor 16)
    u64 ra = __shfl_xor(godd ? w[0] : w[1], 16);
    u64 rb = __shfl_xor(godd ? w[2] : w[3], 16);
    // holdings: lane (pair p, parity e) holds w_{p0}[e], w_{p0}[e+2], w_{p1}[e], w_{p1}[e+2]
    u64 h0 = godd ? ra : w[0];
    u64 h1 = godd ? rb : w[2];
    u64 h2 = godd ? w[1] : ra;
    u64 h3 = godd ? w[3] : rb;
    // stage 2: pull full holding from lane L -> pf0/pf1
    u64 F0 = __shfl(h0, xsrc);
    u64 F1 = __shfl(h2, xsrc);
    u64 F2 = __shfl(h1, xsrc);
    u64 F3 = __shfl(h3, xsrc);
    union {
      u64 u[2];
      bf16x8 v;
    } P0, P1;
    P0.u[0] = F0;
    P0.u[1] = F1;
    P1.u[0] = F2;
    P1.u[1] = F3;
    bf16x8 pf0 = P0.v;
    bf16x8 pf1 = P1.v;

    f32x4 lacc = {};
    lacc = MFMA_B16(onesb, pf0, lacc);
    lacc = MFMA_B16(onesb, pf1, lacc);
    lrow = lrow * fac + lacc[0];

#pragma unroll
    for (int dt = 0; dt < 4; ++dt) {
      bf16x8 vf0 = *(const bf16x8_a*)&vbuf[dt * 1024 + krd0];
      bf16x8 vf1 = *(const bf16x8_a*)&vbuf[dt * 1024 + krd1];
      o[dt] = MFMA_B16(vf0, pf0, o[dt]);
      o[dt] = MFMA_B16(vf1, pf1, o[dt]);
    }
  };

  stage(0, 0);
#pragma unroll 1
  for (int t = 0; t < 32; t += 2) {
    __syncthreads();
    stage(1, (t + 1) * 64);
    do_tile(&sK[0][0], &sV[0][0]);
    __syncthreads();
    if (t + 2 < 32) stage(0, (t + 2) * 64);
    do_tile(&sK[1][0], &sV[1][0]);
  }

  const int b = bh >> 4, hh = bh & 15;
  const int s = q0 + wid * 16 + r15;
  const float inv = 1.f / lrow;
  unsigned short* orow = out + ((size_t)(b * 2048 + s)) * 1024 + hh * 64;
#pragma unroll
  for (int dt = 0; dt < 4; ++dt) {
    bf16x4_a tq;
    tq[0] = (__bf16)(o[dt][0] * inv);
    tq[1] = (__bf16)(o[dt][1] * inv);
    tq[2] = (__bf16)(o[dt][2] * inv);
    tq[3] = (__bf16)(o[dt][3] * inv);
    *(bf16x4_a*)(orow + dt * 16 + g * 4) = tq;
  }
}

// ---------- fused 2x bf16-partial reduce + bias + residual + LN -> f32 + bf16 ----------
__global__ __launch_bounds__(256) void ln2p_kernel(
    const unsigned short* __restrict__ p0, const unsigned short* __restrict__ p1,
    const float* __restrict__ bias, const float* __restrict__ resid,
    const float* __restrict__ gamma, const float* __restrict__ beta,
    float* __restrict__ outf, unsigned short* __restrict__ outb) {
  const int row = blockIdx.x, tid = threadIdx.x;
  const size_t off = (size_t)row * 1024;
  u16x4_a a4 = *(const u16x4_a*)(p0 + off + tid * 4);
  u16x4_a b4 = *(const u16x4_a*)(p1 + off + tid * 4);
  float4 bb4 = ((const float4*)bias)[tid];
  float4 rr = ((const float4*)(resid + off))[tid];
  float4 v;
  v.x = b2f(a4[0]) + b2f(b4[0]) + bb4.x + rr.x;
  v.y = b2f(a4[1]) + b2f(b4[1]) + bb4.y + rr.y;
  v.z = b2f(a4[2]) + b2f(b4[2]) + bb4.z + rr.z;
  v.w = b2f(a4[3]) + b2f(b4[3]) + bb4.w + rr.w;

  float s = v.x + v.y + v.z + v.w;
  float ss = v.x * v.x + v.y * v.y + v.z * v.z + v.w * v.w;
#pragma unroll
  for (int o2 = 32; o2 > 0; o2 >>= 1) {
    s += __shfl_down(s, o2);
    ss += __shfl_down(ss, o2);
  }
  __shared__ float red[8];
  const int wid = tid >> 6;
  if ((tid & 63) == 0) { red[wid] = s; red[4 + wid] = ss; }
  __syncthreads();
  float S = red[0] + red[1] + red[2] + red[3];
  float SS = red[4] + red[5] + red[6] + red[7];
  const float mean = S * (1.f / 1024.f);
  const float var = SS * (1.f / 1024.f) - mean * mean;
  const float inv = 1.f / sqrtf(var + 1e-10f);
  float4 gg = ((const float4*)gamma)[tid];
  float4 be = ((const float4*)beta)[tid];
  float4 o;
  o.x = (v.x - mean) * inv * gg.x + be.x;
  o.y = (v.y - mean) * inv * gg.y + be.y;
  o.z = (v.z - mean) * inv * gg.z + be.z;
  o.w = (v.w - mean) * inv * gg.w + be.w;
  ((float4*)(outf + off))[tid] = o;
  u16x4_a t = {f2b(o.x), f2b(o.y), f2b(o.z), f2b(o.w)};
  *(u16x4_a*)(outb + off + tid * 4) = t;
}

// ---------- fused 4x bf16-partial reduce + bias + residual + LN -> f32 ----------
__global__ __launch_bounds__(256) void ln4p_kernel(
    const unsigned short* __restrict__ p0, const unsigned short* __restrict__ p1,
    const unsigned short* __restrict__ p2, const unsigned short* __restrict__ p3,
    const float* __restrict__ bias, const float* __restrict__ resid,
    const float* __restrict__ gamma, const float* __restrict__ beta,
    float* __restrict__ outf) {
  const int row = blockIdx.x, tid = threadIdx.x;
  const size_t off = (size_t)row * 1024;
  u16x4_a a4 = *(const u16x4_a*)(p0 + off + tid * 4);
  u16x4_a b4 = *(const u16x4_a*)(p1 + off + tid * 4);
  u16x4_a c4 = *(const u16x4_a*)(p2 + off + tid * 4);
  u16x4_a d4 = *(const u16x4_a*)(p3 + off + tid * 4);
  float4 bb4 = ((const float4*)bias)[tid];
  float4 rr = ((const float4*)(resid + off))[tid];
  float4 v;
  v.x = (b2f(a4[0]) + b2f(b4[0])) + (b2f(c4[0]) + b2f(d4[0])) + bb4.x + rr.x;
  v.y = (b2f(a4[1]) + b2f(b4[1])) + (b2f(c4[1]) + b2f(d4[1])) + bb4.y + rr.y;
  v.z = (b2f(a4[2]) + b2f(b4[2])) + (b2f(c4[2]) + b2f(d4[2])) + bb4.z + rr.z;
  v.w = (b2f(a4[3]) + b2f(b4[3])) + (b2f(c4[3]) + b2f(d4[3])) + bb4.w + rr.w;

  float s = v.x + v.y + v.z + v.w;
  float ss = v.x * v.x + v.y * v.y + v.z * v.z + v.w * v.w;
#pragma unroll
  for (int o2 = 32; o2 > 0; o2 >>= 1) {
    s += __shfl_down(s, o2);
    ss += __shfl_down(ss, o2);
  }
  __shared__ float red[8];
  const int wid = tid >> 6;
  if ((tid & 63) == 0) { red[wid] = s; red[4 + wid] = ss; }
  __syncthreads();
  float S = red[0] + red[1] + red[2] + red[3];
  float SS = red[4] + red[5] + red[6] + red[7];
  const float mean = S * (1.f / 1024.f);
  const float var = SS * (1.f / 1024.f) - mean * mean;
  const float inv = 1.f / sqrtf(var + 1e-10f);
  float4 gg = ((const float4*)gamma)[tid];
  float4 be = ((const float4*)beta)[tid];
  float4 o;
  o.x = (v.x - mean) * inv * gg.x + be.x;
  o.y = (v.y - mean) * inv * gg.y + be.y;
  o.z = (v.z - mean) * inv * gg.z + be.z;
  o.w = (v.w - mean) * inv * gg.w + be.w;
  ((float4*)(outf + off))[tid] = o;
}

// ---------- launch ----------
extern "C" void kernel_launch(void* const* d_in, const int* in_sizes, int n_in,
                              void* d_out, int out_size, void* d_ws, size_t ws_size,
                              hipStream_t stream) {
  const float* x      = (const float*)d_in[0];
  const float* wq     = (const float*)d_in[1];
  const float* bq     = (const float*)d_in[2];
  const float* wk     = (const float*)d_in[3];
  const float* bk     = (const float*)d_in[4];
  const float* wv     = (const float*)d_in[5];
  const float* bv     = (const float*)d_in[6];
  const float* w_proj = (const float*)d_in[7];
  const float* b_proj = (const float*)d_in[8];
  const float* gamma1 = (const float*)d_in[9];
  const float* beta1  = (const float*)d_in[10];
  const float* w1     = (const float*)d_in[11];
  const float* b1     = (const float*)d_in[12];
  const float* w2     = (const float*)d_in[13];
  const float* b2     = (const float*)d_in[14];
  const float* gamma2 = (const float*)d_in[15];
  const float* beta2  = (const float*)d_in[16];

  char* p = (char*)d_ws;
  auto alloc = [&](size_t bytes) {
    char* r = p;
    p += (bytes + 255) & ~(size_t)255;
    return r;
  };
  unsigned short* xb      = (unsigned short*)alloc(4096ull * 1024 * 2);  // 8MB; dead after proj
  unsigned short* Wqkv_t  = (unsigned short*)alloc(3072ull * 1024 * 2);  // 6MB; dead after QKV
  unsigned short* Wproj_t = (unsigned short*)alloc(1024ull * 1024 * 2);  // 2MB; dead after proj
  unsigned short* W2t     = (unsigned short*)alloc(1024ull * 4096 * 2);  // 8MB; live thru FFN2
  float*          biasq   = (float*)alloc(3072 * 4);
  unsigned short* Qb      = (unsigned short*)alloc(4096ull * 1024 * 2);  // 8MB; dead after attn
  unsigned short* Kb      = (unsigned short*)alloc(4096ull * 1024 * 2);  // 8MB; dead after attn
  unsigned short* Vtb     = (unsigned short*)alloc(4096ull * 1024 * 2);  // 8MB; dead after attn
  unsigned short* W1t     = (unsigned short*)alloc(4096ull * 1024 * 2);  // 8MB; dead after FFN1
  float*          out1f   = (float*)alloc(4096ull * 1024 * 4);           // live thru ln4p
  unsigned short* out1b   = (unsigned short*)alloc(4096ull * 1024 * 2);  // dead after FFN1
  unsigned short* ffn_h   = (unsigned short*)alloc(4096ull * 4096 * 2);  // live thru FFN2
  unsigned short* concat  = xb;

  unsigned short* prA = Qb;
  unsigned short* prB = Kb;
  unsigned short* pp0 = xb;
  unsigned short* pp1 = Qb;
  unsigned short* pp2 = Kb;
  unsigned short* pp3 = Vtb;

  prepass_kernel<<<16396, 256, 0, stream>>>(x, wq, wk, wv, w_proj, w1, w2, bq, bk, bv,
                                            xb, Wqkv_t, Wproj_t, W1t, W2t, biasq);

  gemm256_kernel<0><<<192, 512, 0, stream>>>(xb, Wqkv_t, 4096, 3072, 1024, 12, 1, biasq,
                                             nullptr, Qb, Kb, Vtb, nullptr, nullptr,
                                             nullptr, nullptr);
  attn_kernel<<<dim3(32, 32), 256, 0, stream>>>(Qb, Kb, Vtb, concat);
  gemm_bt_kernel<<<dim3(8, 32, 2), 256, 0, stream>>>(concat, Wproj_t, 4096, 1024, 512, 1024,
                                                     prA, prB);
  ln2p_kernel<<<4096, 256, 0, stream>>>(prA, prB, b_proj, x, gamma1, beta1, out1f, out1b);
  gemm256_kernel<2><<<256, 512, 0, stream>>>(out1b, W1t, 4096, 4096, 1024, 16, 1, b1,
                                             ffn_h, nullptr, nullptr, nullptr,
                                             nullptr, nullptr, nullptr, nullptr);
  gemm256_kernel<3><<<256, 512, 0, stream>>>(ffn_h, W2t, 4096, 1024, 4096, 4, 4, nullptr,
                                             nullptr, nullptr, nullptr, nullptr,
                                             pp0, pp1, pp2, pp3);
  ln4p_kernel<<<4096, 256, 0, stream>>>(pp0, pp1, pp2, pp3, b2, out1f, gamma2, beta2,
                                        (float*)d_out);
}

// Round 15
// 234.252 us; speedup vs baseline: 1.4323x; 1.0428x over previous
//
#include <hip/hip_runtime.h>
#include <stdint.h>

// ---------- types ----------
typedef float f32x4 __attribute__((ext_vector_type(4)));
typedef __bf16 bf16x8 __attribute__((ext_vector_type(8)));
typedef __bf16 bf16x8_a __attribute__((ext_vector_type(8), may_alias));
typedef __bf16 bf16x4_a __attribute__((ext_vector_type(4), may_alias));
typedef unsigned int u32x4_a __attribute__((ext_vector_type(4), may_alias));
typedef unsigned short u16x4_a __attribute__((ext_vector_type(4), may_alias));

#define DEV __device__ __forceinline__
#define MFMA_B16(a, b, c) __builtin_amdgcn_mfma_f32_16x16x32_bf16((a), (b), (c), 0, 0, 0)

#if __has_builtin(__builtin_amdgcn_exp2f)
#define EXP2(x) __builtin_amdgcn_exp2f(x)
#else
#define EXP2(x) exp2f(x)
#endif

DEV unsigned short f2b(float f) {  // f32 -> bf16 RNE
  unsigned int u = __float_as_uint(f);
  u = u + 0x7FFFu + ((u >> 16) & 1u);
  return (unsigned short)(u >> 16);
}
DEV float b2f(unsigned short u) { return __uint_as_float(((unsigned int)u) << 16); }

// async global->LDS, 16B per lane; LDS dest is wave-uniform base + lane*16
#define GLOAD_LDS16(gsrc, ldst)                                                  \
  __builtin_amdgcn_global_load_lds(                                              \
      (__attribute__((address_space(1))) void*)(uintptr_t)(const void*)(gsrc),   \
      (__attribute__((address_space(3))) void*)(ldst), 16, 0, 0)

// ---------- fused prepass: cvt x | transpose wq/wk/wv | transpose w_proj/w1/w2 | bias ----------
__global__ __launch_bounds__(256) void prepass_kernel(
    const float* __restrict__ x, const float* __restrict__ wq,
    const float* __restrict__ wk, const float* __restrict__ wv,
    const float* __restrict__ w_proj, const float* __restrict__ w1,
    const float* __restrict__ w2, const float* __restrict__ bq,
    const float* __restrict__ bk, const float* __restrict__ bv,
    unsigned short* __restrict__ xb, unsigned short* __restrict__ Wqkv_t,
    unsigned short* __restrict__ o_proj, unsigned short* __restrict__ o1,
    unsigned short* __restrict__ o2, float* __restrict__ biasq) {
  __shared__ float tile[32][33];
  int bid = blockIdx.x;
  if (bid < 4096) {  // cvt: x f32 -> bf16
    int i = bid * 256 + threadIdx.x;
    float4 v = ((const float4*)x)[i];
    u16x4_a t = {f2b(v.x), f2b(v.y), f2b(v.z), f2b(v.w)};
    ((u16x4_a*)xb)[i] = t;
    return;
  }
  bid -= 4096;
  if (bid < 3072) {  // tqkv
    const int bx = bid & 1, by = (bid >> 1) & 31, zz = bid >> 6;
    const int sel = zz >> 4, zh = zz & 15;
    const float scale = sel == 0 ? 0.18033688f : 1.f;  // q: 1/sqrt(HD)*log2(e)
    const float* ip = (sel == 0 ? wq : (sel == 1 ? wk : wv)) + (size_t)zh * 1024 * 64;
    unsigned short* op = Wqkv_t + (size_t)sel * 1024 * 1024 + (size_t)zh * 1024 * 64;
    const int tx = threadIdx.x & 31, ty = threadIdx.x >> 5;
    const int c0 = bx * 32, r0 = by * 32;
#pragma unroll
    for (int j = 0; j < 32; j += 8)
      tile[ty + j][tx] = ip[(size_t)(r0 + ty + j) * 64 + (c0 + tx)];
    __syncthreads();
#pragma unroll
    for (int j = 0; j < 32; j += 8)
      op[(size_t)(c0 + ty + j) * 1024 + (r0 + tx)] = f2b(tile[tx][ty + j] * scale);
    return;
  }
  bid -= 3072;
  if (bid < 9216) {  // tw
    const float* in;
    unsigned short* out;
    int rows, cols, bx, by;
    if (bid < 1024) {
      in = w_proj; out = o_proj; rows = 1024; cols = 1024; bx = bid & 31; by = bid >> 5;
    } else if (bid < 5120) {
      bid -= 1024; in = w1; out = o1; rows = 1024; cols = 4096; bx = bid & 127; by = bid >> 7;
    } else {
      bid -= 5120; in = w2; out = o2; rows = 4096; cols = 1024; bx = bid & 31; by = bid >> 5;
    }
    const int tx = threadIdx.x & 31, ty = threadIdx.x >> 5;
    const int c0 = bx * 32, r0 = by * 32;
#pragma unroll
    for (int j = 0; j < 32; j += 8)
      tile[ty + j][tx] = in[(size_t)(r0 + ty + j) * cols + (c0 + tx)];
    __syncthreads();
#pragma unroll
    for (int j = 0; j < 32; j += 8)
      out[(size_t)(c0 + ty + j) * rows + (r0 + tx)] = f2b(tile[tx][ty + j]);
    return;
  }
  bid -= 9216;  // bias
  int c = bid * 256 + threadIdx.x;
  int which = c >> 10, idx = c & 1023;
  float v = which == 0 ? bq[idx] : (which == 1 ? bk[idx] : bv[idx]);
  biasq[c] = which == 0 ? v * 0.18033688f : v;
}

// ---------- 256x256 8-phase GEMM (m201 template, plain HIP; R11 epilogues) ----------
// EP 0: QKV scatter + bias. EP 2: bf16 relu. EP 3: bf16 raw partial (split-K).
template <int EP>
__global__ __launch_bounds__(512, 2) void gemm256_kernel(
    const unsigned short* __restrict__ A, const unsigned short* __restrict__ Bt,
    int M, int N, int K, int nbx, int KS,
    const float* __restrict__ bias, unsigned short* __restrict__ outb,
    unsigned short* __restrict__ q_out, unsigned short* __restrict__ k_out,
    unsigned short* __restrict__ v_out,
    unsigned short* __restrict__ pp0, unsigned short* __restrict__ pp1,
    unsigned short* __restrict__ pp2, unsigned short* __restrict__ pp3) {
  __shared__ __align__(16) unsigned short sA[2][256 * 64];
  __shared__ __align__(16) unsigned short sB[2][256 * 64];

  const int tid = threadIdx.x;
  const int wid = tid >> 6, lane = tid & 63;
  const int g = lane >> 4, r15 = lane & 15;
  const int wm = wid >> 2, wn = wid & 3;

  const int nwg = gridDim.x, cpx = nwg >> 3, orig = blockIdx.x;
  const int wg = (orig & 7) * cpx + (orig >> 3);
  const int bx = wg % nbx;
  const int t1 = wg / nbx;
  const int kz = t1 % KS, by = t1 / KS;
  const int row0 = by * 256, col0 = bx * 256;

  const int tilesK = K >> 6;
  const int qT = tilesK / KS, rT = tilesK % KS;
  const int tile0 = kz * qT + (kz < rT ? kz : rT);
  const int NT = qT + (kz < rT ? 1 : 0);
  const int kbase = tile0 << 6;

  const unsigned short* gA0 = A + (size_t)row0 * K + kbase;
  const unsigned short* gB0 = Bt + (size_t)col0 * K + kbase;
  const int srow8 = lane >> 3;
  const int schunk = ((lane & 7) ^ srow8) * 8;

  f32x4 acc[8][4] = {};
  bf16x8 af[4][2], bfr[4][2];

  auto stA = [&](int buf, int k0, int i) {
    const int r = wid * 32 + i * 8;
    GLOAD_LDS16(gA0 + (size_t)(r + srow8) * K + k0 + schunk, &sA[buf][r * 64]);
  };
  auto stB = [&](int buf, int k0, int i) {
    const int r = wid * 32 + i * 8;
    GLOAD_LDS16(gB0 + (size_t)(r + srow8) * K + k0 + schunk, &sB[buf][r * 64]);
  };
  auto ldA = [&](const unsigned short* p, int m, int ks) -> bf16x8 {
    const int row = wm * 128 + m * 16 + r15;
    return *(const bf16x8_a*)&p[row * 64 + (((ks * 4 + g) ^ (r15 & 7)) * 8)];
  };
  auto ldB = [&](const unsigned short* p, int n, int ks) -> bf16x8 {
    const int row = wn * 64 + n * 16 + r15;
    return *(const bf16x8_a*)&p[row * 64 + (((ks * 4 + g) ^ (r15 & 7)) * 8)];
  };

#pragma unroll
  for (int i = 0; i < 4; ++i) { stA(0, 0, i); stB(0, 0, i); }
  asm volatile("s_waitcnt vmcnt(0)" ::: "memory");
  __builtin_amdgcn_s_barrier();

  for (int kt = 0; kt < NT; ++kt) {
    const int cb = kt & 1, nb = cb ^ 1;
    const bool pf = (kt + 1) < NT;
    const int k1 = (kt + 1) << 6;
    const unsigned short* pA = sA[cb];
    const unsigned short* pB = sB[cb];

#pragma unroll
    for (int m = 0; m < 4; ++m) { af[m][0] = ldA(pA, m, 0); af[m][1] = ldA(pA, m, 1); }
#pragma unroll
    for (int n = 0; n < 4; ++n) { bfr[n][0] = ldB(pB, n, 0); bfr[n][1] = ldB(pB, n, 1); }
    if (pf) { stA(nb, k1, 0); stA(nb, k1, 1); }
    __builtin_amdgcn_s_barrier();
    asm volatile("s_waitcnt lgkmcnt(0)" ::: "memory");
    __builtin_amdgcn_sched_barrier(0);
    __builtin_amdgcn_s_setprio(1);
#pragma unroll
    for (int m = 0; m < 4; ++m)
#pragma unroll
      for (int n = 0; n < 2; ++n) {
        acc[m][n] = MFMA_B16(af[m][0], bfr[n][0], acc[m][n]);
        acc[m][n] = MFMA_B16(af[m][1], bfr[n][1], acc[m][n]);
      }
    __builtin_amdgcn_s_setprio(0);
    __builtin_amdgcn_s_barrier();

    if (pf) { stA(nb, k1, 2); stA(nb, k1, 3); }
    __builtin_amdgcn_s_barrier();
    __builtin_amdgcn_s_setprio(1);
#pragma unroll
    for (int m = 0; m < 4; ++m)
#pragma unroll
      for (int n = 2; n < 4; ++n) {
        acc[m][n] = MFMA_B16(af[m][0], bfr[n][0], acc[m][n]);
        acc[m][n] = MFMA_B16(af[m][1], bfr[n][1], acc[m][n]);
      }
    __builtin_amdgcn_s_setprio(0);
    __builtin_amdgcn_s_barrier();

#pragma unroll
    for (int m = 0; m < 4; ++m) { af[m][0] = ldA(pA, m + 4, 0); af[m][1] = ldA(pA, m + 4, 1); }
    if (pf) { stB(nb, k1, 0); stB(nb, k1, 1); }
    __builtin_amdgcn_s_barrier();
    asm volatile("s_waitcnt lgkmcnt(0)" ::: "memory");
    __builtin_amdgcn_sched_barrier(0);
    __builtin_amdgcn_s_setprio(1);
#pragma unroll
    for (int m = 0; m < 4; ++m)
#pragma unroll
      for (int n = 0; n < 2; ++n) {
        acc[m + 4][n] = MFMA_B16(af[m][0], bfr[n][0], acc[m + 4][n]);
        acc[m + 4][n] = MFMA_B16(af[m][1], bfr[n][1], acc[m + 4][n]);
      }
    __builtin_amdgcn_s_setprio(0);
    __builtin_amdgcn_s_barrier();

    if (pf) { stB(nb, k1, 2); stB(nb, k1, 3); }
    __builtin_amdgcn_s_barrier();
    __builtin_amdgcn_s_setprio(1);
#pragma unroll
    for (int m = 0; m < 4; ++m)
#pragma unroll
      for (int n = 2; n < 4; ++n) {
        acc[m + 4][n] = MFMA_B16(af[m][0], bfr[n][0], acc[m + 4][n]);
        acc[m + 4][n] = MFMA_B16(af[m][1], bfr[n][1], acc[m + 4][n]);
      }
    __builtin_amdgcn_s_setprio(0);
    asm volatile("s_waitcnt vmcnt(0)" ::: "memory");
    __builtin_amdgcn_s_barrier();
  }

  unsigned short* pz = kz == 0 ? pp0 : (kz == 1 ? pp1 : (kz == 2 ? pp2 : pp3));
#pragma unroll
  for (int m = 0; m < 8; ++m) {
    const int rbase = row0 + wm * 128 + m * 16 + g * 4;
#pragma unroll
    for (int n = 0; n < 4; ++n) {
      const int col = col0 + wn * 64 + n * 16 + r15;
      const float bb = (EP == 3) ? 0.f : bias[col];
      if constexpr (EP == 0) {
        const int which = col >> 10, cc = col & 1023;
        const int hh = cc >> 6, e = cc & 63;
        const int b = rbase >> 11, s0v = rbase & 2047;
        if (which == 2) {
          bf16x4_a pk;
#pragma unroll
          for (int r = 0; r < 4; ++r) pk[r] = (__bf16)(acc[m][n][r] + bb);
          *(bf16x4_a*)(v_out + (((size_t)(b * 16 + hh) * 64) + e) * 2048 + s0v) = pk;
        } else {
          unsigned short* dst = which == 0 ? q_out : k_out;
#pragma unroll
          for (int r = 0; r < 4; ++r)
            dst[(((size_t)(b * 16 + hh) * 2048) + s0v + r) * 64 + e] =
                f2b(acc[m][n][r] + bb);
        }
      } else {
#pragma unroll
        for (int r = 0; r < 4; ++r) {
          const int row = rbase + r;
          float v = acc[m][n][r] + bb;
          if constexpr (EP == 3) {
            pz[(size_t)row * N + col] = f2b(v);
          } else {
            outb[(size_t)row * N + col] = f2b(v > 0.f ? v : 0.f);
          }
        }
      }
    }
  }
}

// ---------- 128x128 GEMM, split-K over blockIdx.z, bf16 partial out (R11) ----------
__global__ __launch_bounds__(256) void gemm_bt_kernel(
    const unsigned short* __restrict__ A, const unsigned short* __restrict__ Bt,
    int M, int N, int Kchunk, int Kstride,
    unsigned short* __restrict__ pp0, unsigned short* __restrict__ pp1) {
  __shared__ __align__(16) unsigned short sA[2][128 * 32];
  __shared__ __align__(16) unsigned short sB[2][128 * 32];
  const int tid = threadIdx.x;
  const int wid = tid >> 6, lane = tid & 63;
  const int g = lane >> 4, r15 = lane & 15;
  const int wr = wid >> 1, wc = wid & 1;
  const int row0 = blockIdx.y * 128, col0 = blockIdx.x * 128;
  const int kz = blockIdx.z;

  f32x4 acc[4][4] = {};

  const int c0 = wid * 128 + lane;
  const unsigned short* gA0 = A + (size_t)row0 * Kstride + (size_t)kz * Kchunk;
  const unsigned short* gB0 = Bt + (size_t)col0 * Kstride + (size_t)kz * Kchunk;

  auto stage = [&](int buf, int k0) {
#pragma unroll
    for (int j = 0; j < 2; ++j) {
      int c = c0 + j * 64;
      GLOAD_LDS16(gA0 + (size_t)(c >> 2) * Kstride + k0 + (c & 3) * 8,
                  &sA[buf][(wid * 128 + j * 64) * 8]);
      GLOAD_LDS16(gB0 + (size_t)(c >> 2) * Kstride + k0 + (c & 3) * 8,
                  &sB[buf][(wid * 128 + j * 64) * 8]);
    }
  };

  stage(0, 0);
  const int NT = Kchunk >> 5;
  for (int t = 0; t < NT; ++t) {
    const int cb = t & 1;
    __syncthreads();
    if (t + 1 < NT) stage(cb ^ 1, (t + 1) * 32);
    bf16x8 af[4], bfr[4];
#pragma unroll
    for (int m = 0; m < 4; ++m)
      af[m] = *(const bf16x8_a*)&sA[cb][(wr * 64 + m * 16 + r15) * 32 + g * 8];
#pragma unroll
    for (int n = 0; n < 4; ++n)
      bfr[n] = *(const bf16x8_a*)&sB[cb][(wc * 64 + n * 16 + r15) * 32 + g * 8];
#pragma unroll
    for (int m = 0; m < 4; ++m)
#pragma unroll
      for (int n = 0; n < 4; ++n)
        acc[m][n] = MFMA_B16(af[m], bfr[n], acc[m][n]);
  }

  unsigned short* pz = kz == 0 ? pp0 : pp1;
#pragma unroll
  for (int m = 0; m < 4; ++m) {
    const int rbase = row0 + wr * 64 + m * 16 + g * 4;
#pragma unroll
    for (int n = 0; n < 4; ++n) {
      const int col = col0 + wc * 64 + n * 16 + r15;
#pragma unroll
      for (int r = 0; r < 4; ++r)
        pz[(size_t)(rbase + r) * N + col] = f2b(acc[m][n][r]);
    }
  }
}

// ---------- flash attention: R11 form (frozen; best measured 65.4 us) ----------
__global__ __launch_bounds__(256) void attn_kernel(const unsigned short* __restrict__ Q,
                                                   const unsigned short* __restrict__ K,
                                                   const unsigned short* __restrict__ Vt,
                                                   unsigned short* __restrict__ out) {
  const int flat = blockIdx.y * gridDim.x + blockIdx.x;  // 0..1023
  const int xcd = flat & 7, rest = flat >> 3;
  const int bh = xcd * 4 + (rest >> 5);
  const int q0 = (rest & 31) * 64;

  const int tid = threadIdx.x, wid = tid >> 6, lane = tid & 63;
  const int g = lane >> 4, r15 = lane & 15;
  const int h = r15 & 7;
  const int s0 = ((g ^ h) * 8);
  const int s1 = (((g + 4) ^ h) * 8);
  const int pswz = r15 & 14;

  __shared__ __align__(16) unsigned short sK[2][64 * 64];
  __shared__ __align__(16) unsigned short sV[2][64 * 64];
  __shared__ __align__(16) unsigned short sP[4][16 * 64];

  const size_t base = (size_t)bh * (2048 * 64);
  const unsigned short* Kb = K + base;
  const unsigned short* Vb = Vt + base;

  const int qrow = q0 + wid * 16 + r15;
  bf16x8 qf[2];
  qf[0] = *(const bf16x8_a*)(Q + base + (size_t)qrow * 64 + g * 8);
  qf[1] = *(const bf16x8_a*)(Q + base + (size_t)qrow * 64 + 32 + g * 8);

  const int srow = lane >> 3;
  const int schunk = ((lane & 7) ^ srow) * 8;

  union {
    unsigned short u[8];
    bf16x8 v;
  } ou;
#pragma unroll
  for (int i = 0; i < 8; ++i) ou.u[i] = 0x3F80;
  const bf16x8 onesb = ou.v;

  f32x4 o[4] = {};
  float mrow = -1e30f, lrow = 0.f;

  const int krd0 = r15 * 64 + s0;
  const int krd1 = r15 * 64 + s1;
  unsigned short* const pw = &sP[wid][r15 * 64];
  const int pwr0 = ((2 * g) ^ pswz) << 2;
  const int pwr1 = ((8 + 2 * g) ^ pswz) << 2;

  auto stage = [&](int bufi, int kt0s) {
#pragma unroll
    for (int i = 0; i < 2; ++i) {
      const int inst = wid * 2 + i;
      const int row = 8 * inst + srow;
      GLOAD_LDS16(Kb + (size_t)(kt0s + row) * 64 + schunk, &sK[bufi][inst * 512]);
      GLOAD_LDS16(Vb + (size_t)row * 2048 + kt0s + schunk, &sV[bufi][inst * 512]);
    }
  };

  auto do_tile = [&](const unsigned short* kbuf, const unsigned short* vbuf) {
    f32x4 sc[4] = {};
#pragma unroll
    for (int kt = 0; kt < 4; ++kt) {
      bf16x8 kf0 = *(const bf16x8_a*)&kbuf[kt * 1024 + krd0];
      bf16x8 kf1 = *(const bf16x8_a*)&kbuf[kt * 1024 + krd1];
      sc[kt] = MFMA_B16(kf0, qf[0], sc[kt]);
      sc[kt] = MFMA_B16(kf1, qf[1], sc[kt]);
    }

    float a0 = fmaxf(fmaxf(sc[0][0], sc[0][1]), sc[0][2]);
    float a1 = fmaxf(fmaxf(sc[0][3], sc[1][0]), sc[1][1]);
    float a2 = fmaxf(fmaxf(sc[1][2], sc[1][3]), sc[2][0]);
    float a3 = fmaxf(fmaxf(sc[2][1], sc[2][2]), sc[2][3]);
    float a4 = fmaxf(fmaxf(sc[3][0], sc[3][1]), sc[3][2]);
    float b0 = fmaxf(fmaxf(a0, a1), a2);
    float b1 = fmaxf(fmaxf(a3, a4), sc[3][3]);
    float pmax = fmaxf(b0, b1);
    pmax = fmaxf(pmax, __shfl_xor(pmax, 16));
    pmax = fmaxf(pmax, __shfl_xor(pmax, 32));

    const bool allkeep = __all(pmax - mrow <= 11.5441f);
    float fac;
    if (allkeep) {
      fac = 1.0f;
    } else {
      float nm = fmaxf(mrow, pmax);
      fac = EXP2(mrow - nm);
      mrow = nm;
#pragma unroll
      for (int dt = 0; dt < 4; ++dt)
#pragma unroll
        for (int r = 0; r < 4; ++r) o[dt][r] *= fac;
    }

#pragma unroll
    for (int kt = 0; kt < 4; ++kt) {
      bf16x4_a pb;
      pb[0] = (__bf16)EXP2(sc[kt][0] - mrow);
      pb[1] = (__bf16)EXP2(sc[kt][1] - mrow);
      pb[2] = (__bf16)EXP2(sc[kt][2] - mrow);
      pb[3] = (__bf16)EXP2(sc[kt][3] - mrow);
      *(bf16x4_a*)&pw[((4 * kt + g) ^ pswz) << 2] = pb;
    }

    bf16x8 pf0 = *(const bf16x8_a*)&pw[pwr0];
    bf16x8 pf1 = *(const bf16x8_a*)&pw[pwr1];

    f32x4 lacc = {};
    lacc = MFMA_B16(onesb, pf0, lacc);
    lacc = MFMA_B16(onesb, pf1, lacc);
    lrow = lrow * fac + lacc[0];

#pragma unroll
    for (int dt = 0; dt < 4; ++dt) {
      bf16x8 vf0 = *(const bf16x8_a*)&vbuf[dt * 1024 + krd0];
      bf16x8 vf1 = *(const bf16x8_a*)&vbuf[dt * 1024 + krd1];
      o[dt] = MFMA_B16(vf0, pf0, o[dt]);
      o[dt] = MFMA_B16(vf1, pf1, o[dt]);
    }
  };

  stage(0, 0);
#pragma unroll 1
  for (int t = 0; t < 32; t += 2) {
    __syncthreads();
    stage(1, (t + 1) * 64);
    do_tile(&sK[0][0], &sV[0][0]);
    __syncthreads();
    if (t + 2 < 32) stage(0, (t + 2) * 64);
    do_tile(&sK[1][0], &sV[1][0]);
  }

  const int b = bh >> 4, hh = bh & 15;
  const int s = q0 + wid * 16 + r15;
  const float inv = 1.f / lrow;
  unsigned short* orow = out + ((size_t)(b * 2048 + s)) * 1024 + hh * 64;
#pragma unroll
  for (int dt = 0; dt < 4; ++dt) {
    bf16x4_a tq;
    tq[0] = (__bf16)(o[dt][0] * inv);
    tq[1] = (__bf16)(o[dt][1] * inv);
    tq[2] = (__bf16)(o[dt][2] * inv);
    tq[3] = (__bf16)(o[dt][3] * inv);
    *(bf16x4_a*)(orow + dt * 16 + g * 4) = tq;
  }
}

// ---------- fused 2x bf16-partial reduce + bias + residual + LN -> bf16 only ----------
__global__ __launch_bounds__(256) void ln2p_kernel(
    const unsigned short* __restrict__ p0, const unsigned short* __restrict__ p1,
    const float* __restrict__ bias, const float* __restrict__ resid,
    const float* __restrict__ gamma, const float* __restrict__ beta,
    unsigned short* __restrict__ outb) {
  const int row = blockIdx.x, tid = threadIdx.x;
  const size_t off = (size_t)row * 1024;
  u16x4_a a4 = *(const u16x4_a*)(p0 + off + tid * 4);
  u16x4_a b4 = *(const u16x4_a*)(p1 + off + tid * 4);
  float4 bb4 = ((const float4*)bias)[tid];
  float4 rr = ((const float4*)(resid + off))[tid];
  float4 v;
  v.x = b2f(a4[0]) + b2f(b4[0]) + bb4.x + rr.x;
  v.y = b2f(a4[1]) + b2f(b4[1]) + bb4.y + rr.y;
  v.z = b2f(a4[2]) + b2f(b4[2]) + bb4.z + rr.z;
  v.w = b2f(a4[3]) + b2f(b4[3]) + bb4.w + rr.w;

  float s = v.x + v.y + v.z + v.w;
  float ss = v.x * v.x + v.y * v.y + v.z * v.z + v.w * v.w;
#pragma unroll
  for (int o2 = 32; o2 > 0; o2 >>= 1) {
    s += __shfl_down(s, o2);
    ss += __shfl_down(ss, o2);
  }
  __shared__ float red[8];
  const int wid = tid >> 6;
  if ((tid & 63) == 0) { red[wid] = s; red[4 + wid] = ss; }
  __syncthreads();
  float S = red[0] + red[1] + red[2] + red[3];
  float SS = red[4] + red[5] + red[6] + red[7];
  const float mean = S * (1.f / 1024.f);
  const float var = SS * (1.f / 1024.f) - mean * mean;
  const float inv = 1.f / sqrtf(var + 1e-10f);
  float4 gg = ((const float4*)gamma)[tid];
  float4 be = ((const float4*)beta)[tid];
  float4 o;
  o.x = (v.x - mean) * inv * gg.x + be.x;
  o.y = (v.y - mean) * inv * gg.y + be.y;
  o.z = (v.z - mean) * inv * gg.z + be.z;
  o.w = (v.w - mean) * inv * gg.w + be.w;
  u16x4_a t = {f2b(o.x), f2b(o.y), f2b(o.z), f2b(o.w)};
  *(u16x4_a*)(outb + off + tid * 4) = t;
}

// ---------- fused 4x bf16-partial reduce + bias + bf16-residual + LN -> f32 ----------
__global__ __launch_bounds__(256) void ln4p_kernel(
    const unsigned short* __restrict__ p0, const unsigned short* __restrict__ p1,
    const unsigned short* __restrict__ p2, const unsigned short* __restrict__ p3,
    const float* __restrict__ bias, const unsigned short* __restrict__ residb,
    const float* __restrict__ gamma, const float* __restrict__ beta,
    float* __restrict__ outf) {
  const int row = blockIdx.x, tid = threadIdx.x;
  const size_t off = (size_t)row * 1024;
  u16x4_a a4 = *(const u16x4_a*)(p0 + off + tid * 4);
  u16x4_a b4 = *(const u16x4_a*)(p1 + off + tid * 4);
  u16x4_a c4 = *(const u16x4_a*)(p2 + off + tid * 4);
  u16x4_a d4 = *(const u16x4_a*)(p3 + off + tid * 4);
  u16x4_a r4 = *(const u16x4_a*)(residb + off + tid * 4);
  float4 bb4 = ((const float4*)bias)[tid];
  float4 v;
  v.x = (b2f(a4[0]) + b2f(b4[0])) + (b2f(c4[0]) + b2f(d4[0])) + bb4.x + b2f(r4[0]);
  v.y = (b2f(a4[1]) + b2f(b4[1])) + (b2f(c4[1]) + b2f(d4[1])) + bb4.y + b2f(r4[1]);
  v.z = (b2f(a4[2]) + b2f(b4[2])) + (b2f(c4[2]) + b2f(d4[2])) + bb4.z + b2f(r4[2]);
  v.w = (b2f(a4[3]) + b2f(b4[3])) + (b2f(c4[3]) + b2f(d4[3])) + bb4.w + b2f(r4[3]);

  float s = v.x + v.y + v.z + v.w;
  float ss = v.x * v.x + v.y * v.y + v.z * v.z + v.w * v.w;
#pragma unroll
  for (int o2 = 32; o2 > 0; o2 >>= 1) {
    s += __shfl_down(s, o2);
    ss += __shfl_down(ss, o2);
  }
  __shared__ float red[8];
  const int wid = tid >> 6;
  if ((tid & 63) == 0) { red[wid] = s; red[4 + wid] = ss; }
  __syncthreads();
  float S = red[0] + red[1] + red[2] + red[3];
  float SS = red[4] + red[5] + red[6] + red[7];
  const float mean = S * (1.f / 1024.f);
  const float var = SS * (1.f / 1024.f) - mean * mean;
  const float inv = 1.f / sqrtf(var + 1e-10f);
  float4 gg = ((const float4*)gamma)[tid];
  float4 be = ((const float4*)beta)[tid];
  float4 o;
  o.x = (v.x - mean) * inv * gg.x + be.x;
  o.y = (v.y - mean) * inv * gg.y + be.y;
  o.z = (v.z - mean) * inv * gg.z + be.z;
  o.w = (v.w - mean) * inv * gg.w + be.w;
  ((float4*)(outf + off))[tid] = o;
}

// ---------- launch ----------
extern "C" void kernel_launch(void* const* d_in, const int* in_sizes, int n_in,
                              void* d_out, int out_size, void* d_ws, size_t ws_size,
                              hipStream_t stream) {
  const float* x      = (const float*)d_in[0];
  const float* wq     = (const float*)d_in[1];
  const float* bq     = (const float*)d_in[2];
  const float* wk     = (const float*)d_in[3];
  const float* bk     = (const float*)d_in[4];
  const float* wv     = (const float*)d_in[5];
  const float* bv     = (const float*)d_in[6];
  const float* w_proj = (const float*)d_in[7];
  const float* b_proj = (const float*)d_in[8];
  const float* gamma1 = (const float*)d_in[9];
  const float* beta1  = (const float*)d_in[10];
  const float* w1     = (const float*)d_in[11];
  const float* b1     = (const float*)d_in[12];
  const float* w2     = (const float*)d_in[13];
  const float* b2     = (const float*)d_in[14];
  const float* gamma2 = (const float*)d_in[15];
  const float* beta2  = (const float*)d_in[16];

  char* p = (char*)d_ws;
  auto alloc = [&](size_t bytes) {
    char* r = p;
    p += (bytes + 255) & ~(size_t)255;
    return r;
  };
  unsigned short* xb      = (unsigned short*)alloc(4096ull * 1024 * 2);  // 8MB; dead after proj
  unsigned short* Wqkv_t  = (unsigned short*)alloc(3072ull * 1024 * 2);  // 6MB; dead after QKV
  unsigned short* Wproj_t = (unsigned short*)alloc(1024ull * 1024 * 2);  // 2MB; dead after proj
  unsigned short* W2t     = (unsigned short*)alloc(1024ull * 4096 * 2);  // 8MB; live thru FFN2
  float*          biasq   = (float*)alloc(3072 * 4);
  unsigned short* Qb      = (unsigned short*)alloc(4096ull * 1024 * 2);  // 8MB; dead after attn
  unsigned short* Kb      = (unsigned short*)alloc(4096ull * 1024 * 2);  // 8MB; dead after attn
  unsigned short* Vtb     = (unsigned short*)alloc(4096ull * 1024 * 2);  // 8MB; dead after attn
  unsigned short* W1t     = (unsigned short*)alloc(4096ull * 1024 * 2);  // 8MB; dead after FFN1
  unsigned short* out1b   = (unsigned short*)alloc(4096ull * 1024 * 2);  // live thru ln4p
  unsigned short* ffn_h   = (unsigned short*)alloc(4096ull * 4096 * 2);  // live thru FFN2
  unsigned short* concat  = xb;

  unsigned short* prA = Qb;
  unsigned short* prB = Kb;
  unsigned short* pp0 = xb;
  unsigned short* pp1 = Qb;
  unsigned short* pp2 = Kb;
  unsigned short* pp3 = Vtb;

  prepass_kernel<<<16396, 256, 0, stream>>>(x, wq, wk, wv, w_proj, w1, w2, bq, bk, bv,
                                            xb, Wqkv_t, Wproj_t, W1t, W2t, biasq);

  gemm256_kernel<0><<<192, 512, 0, stream>>>(xb, Wqkv_t, 4096, 3072, 1024, 12, 1, biasq,
                                             nullptr, Qb, Kb, Vtb, nullptr, nullptr,
                                             nullptr, nullptr);
  attn_kernel<<<dim3(32, 32), 256, 0, stream>>>(Qb, Kb, Vtb, concat);
  gemm_bt_kernel<<<dim3(8, 32, 2), 256, 0, stream>>>(concat, Wproj_t, 4096, 1024, 512, 1024,
                                                     prA, prB);
  ln2p_kernel<<<4096, 256, 0, stream>>>(prA, prB, b_proj, x, gamma1, beta1, out1b);
  gemm256_kernel<2><<<256, 512, 0, stream>>>(out1b, W1t, 4096, 4096, 1024, 16, 1, b1,
                                             ffn_h, nullptr, nullptr, nullptr,
                                             nullptr, nullptr, nullptr, nullptr);
  gemm256_kernel<3><<<256, 512, 0, stream>>>(ffn_h, W2t, 4096, 1024, 4096, 4, 4, nullptr,
                                             nullptr, nullptr, nullptr, nullptr,
                                             pp0, pp1, pp2, pp3);
  ln4p_kernel<<<4096, 256, 0, stream>>>(pp0, pp1, pp2, pp3, b2, out1b, gamma2, beta2,
                                        (float*)d_out);
}

// Round 16
// 233.382 us; speedup vs baseline: 1.4376x; 1.0037x over previous
//
#include <hip/hip_runtime.h>
#include <stdint.h>

// ---------- types ----------
typedef float f32x4 __attribute__((ext_vector_type(4)));
typedef __bf16 bf16x8 __attribute__((ext_vector_type(8)));
typedef __bf16 bf16x8_a __attribute__((ext_vector_type(8), may_alias));
typedef __bf16 bf16x4_a __attribute__((ext_vector_type(4), may_alias));
typedef unsigned int u32x4_a __attribute__((ext_vector_type(4), may_alias));
typedef unsigned short u16x4_a __attribute__((ext_vector_type(4), may_alias));

#define DEV __device__ __forceinline__
#define MFMA_B16(a, b, c) __builtin_amdgcn_mfma_f32_16x16x32_bf16((a), (b), (c), 0, 0, 0)

#if __has_builtin(__builtin_amdgcn_exp2f)
#define EXP2(x) __builtin_amdgcn_exp2f(x)
#else
#define EXP2(x) exp2f(x)
#endif

DEV unsigned short f2b(float f) {  // f32 -> bf16 RNE
  unsigned int u = __float_as_uint(f);
  u = u + 0x7FFFu + ((u >> 16) & 1u);
  return (unsigned short)(u >> 16);
}
DEV float b2f(unsigned short u) { return __uint_as_float(((unsigned int)u) << 16); }

// async global->LDS, 16B per lane; LDS dest is wave-uniform base + lane*16
#define GLOAD_LDS16(gsrc, ldst)                                                  \
  __builtin_amdgcn_global_load_lds(                                              \
      (__attribute__((address_space(1))) void*)(uintptr_t)(const void*)(gsrc),   \
      (__attribute__((address_space(3))) void*)(ldst), 16, 0, 0)

// ---------- fused prepass: cvt x | transpose wq/wk/wv | transpose w_proj/w1/w2 | bias ----------
__global__ __launch_bounds__(256) void prepass_kernel(
    const float* __restrict__ x, const float* __restrict__ wq,
    const float* __restrict__ wk, const float* __restrict__ wv,
    const float* __restrict__ w_proj, const float* __restrict__ w1,
    const float* __restrict__ w2, const float* __restrict__ bq,
    const float* __restrict__ bk, const float* __restrict__ bv,
    unsigned short* __restrict__ xb, unsigned short* __restrict__ Wqkv_t,
    unsigned short* __restrict__ o_proj, unsigned short* __restrict__ o1,
    unsigned short* __restrict__ o2, float* __restrict__ biasq) {
  __shared__ float tile[32][33];
  int bid = blockIdx.x;
  if (bid < 4096) {  // cvt: x f32 -> bf16
    int i = bid * 256 + threadIdx.x;
    float4 v = ((const float4*)x)[i];
    u16x4_a t = {f2b(v.x), f2b(v.y), f2b(v.z), f2b(v.w)};
    ((u16x4_a*)xb)[i] = t;
    return;
  }
  bid -= 4096;
  if (bid < 3072) {  // tqkv
    const int bx = bid & 1, by = (bid >> 1) & 31, zz = bid >> 6;
    const int sel = zz >> 4, zh = zz & 15;
    const float scale = sel == 0 ? 0.18033688f : 1.f;  // q: 1/sqrt(HD)*log2(e)
    const float* ip = (sel == 0 ? wq : (sel == 1 ? wk : wv)) + (size_t)zh * 1024 * 64;
    unsigned short* op = Wqkv_t + (size_t)sel * 1024 * 1024 + (size_t)zh * 1024 * 64;
    const int tx = threadIdx.x & 31, ty = threadIdx.x >> 5;
    const int c0 = bx * 32, r0 = by * 32;
#pragma unroll
    for (int j = 0; j < 32; j += 8)
      tile[ty + j][tx] = ip[(size_t)(r0 + ty + j) * 64 + (c0 + tx)];
    __syncthreads();
#pragma unroll
    for (int j = 0; j < 32; j += 8)
      op[(size_t)(c0 + ty + j) * 1024 + (r0 + tx)] = f2b(tile[tx][ty + j] * scale);
    return;
  }
  bid -= 3072;
  if (bid < 9216) {  // tw
    const float* in;
    unsigned short* out;
    int rows, cols, bx, by;
    if (bid < 1024) {
      in = w_proj; out = o_proj; rows = 1024; cols = 1024; bx = bid & 31; by = bid >> 5;
    } else if (bid < 5120) {
      bid -= 1024; in = w1; out = o1; rows = 1024; cols = 4096; bx = bid & 127; by = bid >> 7;
    } else {
      bid -= 5120; in = w2; out = o2; rows = 4096; cols = 1024; bx = bid & 31; by = bid >> 5;
    }
    const int tx = threadIdx.x & 31, ty = threadIdx.x >> 5;
    const int c0 = bx * 32, r0 = by * 32;
#pragma unroll
    for (int j = 0; j < 32; j += 8)
      tile[ty + j][tx] = in[(size_t)(r0 + ty + j) * cols + (c0 + tx)];
    __syncthreads();
#pragma unroll
    for (int j = 0; j < 32; j += 8)
      out[(size_t)(c0 + ty + j) * rows + (r0 + tx)] = f2b(tile[tx][ty + j]);
    return;
  }
  bid -= 9216;  // bias
  int c = bid * 256 + threadIdx.x;
  int which = c >> 10, idx = c & 1023;
  float v = which == 0 ? bq[idx] : (which == 1 ? bk[idx] : bv[idx]);
  biasq[c] = which == 0 ? v * 0.18033688f : v;
}

// ---------- 256x256 8-phase GEMM (m201 template, plain HIP; R11 epilogues) ----------
// EP 0: QKV scatter + bias. EP 2: bf16 relu. EP 3: bf16 raw partial (split-K).
template <int EP>
__global__ __launch_bounds__(512, 2) void gemm256_kernel(
    const unsigned short* __restrict__ A, const unsigned short* __restrict__ Bt,
    int M, int N, int K, int nbx, int KS,
    const float* __restrict__ bias, unsigned short* __restrict__ outb,
    unsigned short* __restrict__ q_out, unsigned short* __restrict__ k_out,
    unsigned short* __restrict__ v_out,
    unsigned short* __restrict__ pp0, unsigned short* __restrict__ pp1,
    unsigned short* __restrict__ pp2, unsigned short* __restrict__ pp3) {
  __shared__ __align__(16) unsigned short sA[2][256 * 64];
  __shared__ __align__(16) unsigned short sB[2][256 * 64];

  const int tid = threadIdx.x;
  const int wid = tid >> 6, lane = tid & 63;
  const int g = lane >> 4, r15 = lane & 15;
  const int wm = wid >> 2, wn = wid & 3;

  const int nwg = gridDim.x, cpx = nwg >> 3, orig = blockIdx.x;
  const int wg = (orig & 7) * cpx + (orig >> 3);
  const int bx = wg % nbx;
  const int t1 = wg / nbx;
  const int kz = t1 % KS, by = t1 / KS;
  const int row0 = by * 256, col0 = bx * 256;

  const int tilesK = K >> 6;
  const int qT = tilesK / KS, rT = tilesK % KS;
  const int tile0 = kz * qT + (kz < rT ? kz : rT);
  const int NT = qT + (kz < rT ? 1 : 0);
  const int kbase = tile0 << 6;

  const unsigned short* gA0 = A + (size_t)row0 * K + kbase;
  const unsigned short* gB0 = Bt + (size_t)col0 * K + kbase;
  const int srow8 = lane >> 3;
  const int schunk = ((lane & 7) ^ srow8) * 8;

  f32x4 acc[8][4] = {};
  bf16x8 af[4][2], bfr[4][2];

  auto stA = [&](int buf, int k0, int i) {
    const int r = wid * 32 + i * 8;
    GLOAD_LDS16(gA0 + (size_t)(r + srow8) * K + k0 + schunk, &sA[buf][r * 64]);
  };
  auto stB = [&](int buf, int k0, int i) {
    const int r = wid * 32 + i * 8;
    GLOAD_LDS16(gB0 + (size_t)(r + srow8) * K + k0 + schunk, &sB[buf][r * 64]);
  };
  auto ldA = [&](const unsigned short* p, int m, int ks) -> bf16x8 {
    const int row = wm * 128 + m * 16 + r15;
    return *(const bf16x8_a*)&p[row * 64 + (((ks * 4 + g) ^ (r15 & 7)) * 8)];
  };
  auto ldB = [&](const unsigned short* p, int n, int ks) -> bf16x8 {
    const int row = wn * 64 + n * 16 + r15;
    return *(const bf16x8_a*)&p[row * 64 + (((ks * 4 + g) ^ (r15 & 7)) * 8)];
  };

#pragma unroll
  for (int i = 0; i < 4; ++i) { stA(0, 0, i); stB(0, 0, i); }
  asm volatile("s_waitcnt vmcnt(0)" ::: "memory");
  __builtin_amdgcn_s_barrier();

  for (int kt = 0; kt < NT; ++kt) {
    const int cb = kt & 1, nb = cb ^ 1;
    const bool pf = (kt + 1) < NT;
    const int k1 = (kt + 1) << 6;
    const unsigned short* pA = sA[cb];
    const unsigned short* pB = sB[cb];

#pragma unroll
    for (int m = 0; m < 4; ++m) { af[m][0] = ldA(pA, m, 0); af[m][1] = ldA(pA, m, 1); }
#pragma unroll
    for (int n = 0; n < 4; ++n) { bfr[n][0] = ldB(pB, n, 0); bfr[n][1] = ldB(pB, n, 1); }
    if (pf) { stA(nb, k1, 0); stA(nb, k1, 1); }
    __builtin_amdgcn_s_barrier();
    asm volatile("s_waitcnt lgkmcnt(0)" ::: "memory");
    __builtin_amdgcn_sched_barrier(0);
    __builtin_amdgcn_s_setprio(1);
#pragma unroll
    for (int m = 0; m < 4; ++m)
#pragma unroll
      for (int n = 0; n < 2; ++n) {
        acc[m][n] = MFMA_B16(af[m][0], bfr[n][0], acc[m][n]);
        acc[m][n] = MFMA_B16(af[m][1], bfr[n][1], acc[m][n]);
      }
    __builtin_amdgcn_s_setprio(0);
    __builtin_amdgcn_s_barrier();

    if (pf) { stA(nb, k1, 2); stA(nb, k1, 3); }
    __builtin_amdgcn_s_barrier();
    __builtin_amdgcn_s_setprio(1);
#pragma unroll
    for (int m = 0; m < 4; ++m)
#pragma unroll
      for (int n = 2; n < 4; ++n) {
        acc[m][n] = MFMA_B16(af[m][0], bfr[n][0], acc[m][n]);
        acc[m][n] = MFMA_B16(af[m][1], bfr[n][1], acc[m][n]);
      }
    __builtin_amdgcn_s_setprio(0);
    __builtin_amdgcn_s_barrier();

#pragma unroll
    for (int m = 0; m < 4; ++m) { af[m][0] = ldA(pA, m + 4, 0); af[m][1] = ldA(pA, m + 4, 1); }
    if (pf) { stB(nb, k1, 0); stB(nb, k1, 1); }
    __builtin_amdgcn_s_barrier();
    asm volatile("s_waitcnt lgkmcnt(0)" ::: "memory");
    __builtin_amdgcn_sched_barrier(0);
    __builtin_amdgcn_s_setprio(1);
#pragma unroll
    for (int m = 0; m < 4; ++m)
#pragma unroll
      for (int n = 0; n < 2; ++n) {
        acc[m + 4][n] = MFMA_B16(af[m][0], bfr[n][0], acc[m + 4][n]);
        acc[m + 4][n] = MFMA_B16(af[m][1], bfr[n][1], acc[m + 4][n]);
      }
    __builtin_amdgcn_s_setprio(0);
    __builtin_amdgcn_s_barrier();

    if (pf) { stB(nb, k1, 2); stB(nb, k1, 3); }
    __builtin_amdgcn_s_barrier();
    __builtin_amdgcn_s_setprio(1);
#pragma unroll
    for (int m = 0; m < 4; ++m)
#pragma unroll
      for (int n = 2; n < 4; ++n) {
        acc[m + 4][n] = MFMA_B16(af[m][0], bfr[n][0], acc[m + 4][n]);
        acc[m + 4][n] = MFMA_B16(af[m][1], bfr[n][1], acc[m + 4][n]);
      }
    __builtin_amdgcn_s_setprio(0);
    asm volatile("s_waitcnt vmcnt(0)" ::: "memory");
    __builtin_amdgcn_s_barrier();
  }

  unsigned short* pz = kz == 0 ? pp0 : (kz == 1 ? pp1 : (kz == 2 ? pp2 : pp3));
#pragma unroll
  for (int m = 0; m < 8; ++m) {
    const int rbase = row0 + wm * 128 + m * 16 + g * 4;
#pragma unroll
    for (int n = 0; n < 4; ++n) {
      const int col = col0 + wn * 64 + n * 16 + r15;
      const float bb = (EP == 3) ? 0.f : bias[col];
      if constexpr (EP == 0) {
        const int which = col >> 10, cc = col & 1023;
        const int hh = cc >> 6, e = cc & 63;
        const int b = rbase >> 11, s0v = rbase & 2047;
        if (which == 2) {
          bf16x4_a pk;
#pragma unroll
          for (int r = 0; r < 4; ++r) pk[r] = (__bf16)(acc[m][n][r] + bb);
          *(bf16x4_a*)(v_out + (((size_t)(b * 16 + hh) * 64) + e) * 2048 + s0v) = pk;
        } else {
          unsigned short* dst = which == 0 ? q_out : k_out;
#pragma unroll
          for (int r = 0; r < 4; ++r)
            dst[(((size_t)(b * 16 + hh) * 2048) + s0v + r) * 64 + e] =
                f2b(acc[m][n][r] + bb);
        }
      } else {
#pragma unroll
        for (int r = 0; r < 4; ++r) {
          const int row = rbase + r;
          float v = acc[m][n][r] + bb;
          if constexpr (EP == 3) {
            pz[(size_t)row * N + col] = f2b(v);
          } else {
            outb[(size_t)row * N + col] = f2b(v > 0.f ? v : 0.f);
          }
        }
      }
    }
  }
}

// ---------- 128x128 GEMM, split-K over blockIdx.z, bf16 partial out (R11) ----------
__global__ __launch_bounds__(256) void gemm_bt_kernel(
    const unsigned short* __restrict__ A, const unsigned short* __restrict__ Bt,
    int M, int N, int Kchunk, int Kstride,
    unsigned short* __restrict__ pp0, unsigned short* __restrict__ pp1) {
  __shared__ __align__(16) unsigned short sA[2][128 * 32];
  __shared__ __align__(16) unsigned short sB[2][128 * 32];
  const int tid = threadIdx.x;
  const int wid = tid >> 6, lane = tid & 63;
  const int g = lane >> 4, r15 = lane & 15;
  const int wr = wid >> 1, wc = wid & 1;
  const int row0 = blockIdx.y * 128, col0 = blockIdx.x * 128;
  const int kz = blockIdx.z;

  f32x4 acc[4][4] = {};

  const int c0 = wid * 128 + lane;
  const unsigned short* gA0 = A + (size_t)row0 * Kstride + (size_t)kz * Kchunk;
  const unsigned short* gB0 = Bt + (size_t)col0 * Kstride + (size_t)kz * Kchunk;

  auto stage = [&](int buf, int k0) {
#pragma unroll
    for (int j = 0; j < 2; ++j) {
      int c = c0 + j * 64;
      GLOAD_LDS16(gA0 + (size_t)(c >> 2) * Kstride + k0 + (c & 3) * 8,
                  &sA[buf][(wid * 128 + j * 64) * 8]);
      GLOAD_LDS16(gB0 + (size_t)(c >> 2) * Kstride + k0 + (c & 3) * 8,
                  &sB[buf][(wid * 128 + j * 64) * 8]);
    }
  };

  stage(0, 0);
  const int NT = Kchunk >> 5;
  for (int t = 0; t < NT; ++t) {
    const int cb = t & 1;
    __syncthreads();
    if (t + 1 < NT) stage(cb ^ 1, (t + 1) * 32);
    bf16x8 af[4], bfr[4];
#pragma unroll
    for (int m = 0; m < 4; ++m)
      af[m] = *(const bf16x8_a*)&sA[cb][(wr * 64 + m * 16 + r15) * 32 + g * 8];
#pragma unroll
    for (int n = 0; n < 4; ++n)
      bfr[n] = *(const bf16x8_a*)&sB[cb][(wc * 64 + n * 16 + r15) * 32 + g * 8];
#pragma unroll
    for (int m = 0; m < 4; ++m)
#pragma unroll
      for (int n = 0; n < 4; ++n)
        acc[m][n] = MFMA_B16(af[m], bfr[n], acc[m][n]);
  }

  unsigned short* pz = kz == 0 ? pp0 : pp1;
#pragma unroll
  for (int m = 0; m < 4; ++m) {
    const int rbase = row0 + wr * 64 + m * 16 + g * 4;
#pragma unroll
    for (int n = 0; n < 4; ++n) {
      const int col = col0 + wc * 64 + n * 16 + r15;
#pragma unroll
      for (int r = 0; r < 4; ++r)
        pz[(size_t)(rbase + r) * N + col] = f2b(acc[m][n][r]);
    }
  }
}

// ---------- flash attention: R11 core, 2 q-groups per wave ----------
// Block covers 128 q-rows (grid 512 = 2/CU); each wave runs 2 independent
// softmax chains against the same staged K/V tile -> staging+barriers per
// FLOP halved, ILP doubled. sP reused sequentially by both groups.
__global__ __launch_bounds__(256) void attn_kernel(const unsigned short* __restrict__ Q,
                                                   const unsigned short* __restrict__ K,
                                                   const unsigned short* __restrict__ Vt,
                                                   unsigned short* __restrict__ out) {
  const int flat = blockIdx.y * gridDim.x + blockIdx.x;  // 0..511
  const int xcd = flat & 7, rest = flat >> 3;            // rest 0..63
  const int bh = xcd * 4 + (rest >> 4);
  const int q0 = (rest & 15) * 128;

  const int tid = threadIdx.x, wid = tid >> 6, lane = tid & 63;
  const int g = lane >> 4, r15 = lane & 15;
  const int h = r15 & 7;
  const int s0 = ((g ^ h) * 8);
  const int s1 = (((g + 4) ^ h) * 8);
  const int pswz = r15 & 14;

  __shared__ __align__(16) unsigned short sK[2][64 * 64];
  __shared__ __align__(16) unsigned short sV[2][64 * 64];
  __shared__ __align__(16) unsigned short sP[4][16 * 64];

  const size_t base = (size_t)bh * (2048 * 64);
  const unsigned short* Kb = K + base;
  const unsigned short* Vb = Vt + base;

  const int qrow0 = q0 + wid * 16 + r15;
  bf16x8 qf0[2], qf1[2];
  qf0[0] = *(const bf16x8_a*)(Q + base + (size_t)qrow0 * 64 + g * 8);
  qf0[1] = *(const bf16x8_a*)(Q + base + (size_t)qrow0 * 64 + 32 + g * 8);
  qf1[0] = *(const bf16x8_a*)(Q + base + (size_t)(qrow0 + 64) * 64 + g * 8);
  qf1[1] = *(const bf16x8_a*)(Q + base + (size_t)(qrow0 + 64) * 64 + 32 + g * 8);

  const int srow = lane >> 3;
  const int schunk = ((lane & 7) ^ srow) * 8;

  union {
    unsigned short u[8];
    bf16x8 v;
  } ou;
#pragma unroll
  for (int i = 0; i < 8; ++i) ou.u[i] = 0x3F80;
  const bf16x8 onesb = ou.v;

  f32x4 o0[4] = {}, o1[4] = {};
  float m0 = -1e30f, l0 = 0.f, m1 = -1e30f, l1 = 0.f;

  const int krd0 = r15 * 64 + s0;
  const int krd1 = r15 * 64 + s1;
  unsigned short* const pw = &sP[wid][r15 * 64];
  const int pwr0 = ((2 * g) ^ pswz) << 2;
  const int pwr1 = ((8 + 2 * g) ^ pswz) << 2;

  auto stage = [&](int bufi, int kt0s) {
#pragma unroll
    for (int i = 0; i < 2; ++i) {
      const int inst = wid * 2 + i;
      const int row = 8 * inst + srow;
      GLOAD_LDS16(Kb + (size_t)(kt0s + row) * 64 + schunk, &sK[bufi][inst * 512]);
      GLOAD_LDS16(Vb + (size_t)row * 2048 + kt0s + schunk, &sV[bufi][inst * 512]);
    }
  };

  // one softmax+PV chain for one q-group against the staged K/V tile
  auto proc = [&](const unsigned short* kbuf, const unsigned short* vbuf,
                  const bf16x8 (&qf)[2], float& mrow, float& lrow, f32x4 (&o)[4]) {
    f32x4 sc[4] = {};
#pragma unroll
    for (int kt = 0; kt < 4; ++kt) {
      bf16x8 kf0 = *(const bf16x8_a*)&kbuf[kt * 1024 + krd0];
      bf16x8 kf1 = *(const bf16x8_a*)&kbuf[kt * 1024 + krd1];
      sc[kt] = MFMA_B16(kf0, qf[0], sc[kt]);
      sc[kt] = MFMA_B16(kf1, qf[1], sc[kt]);
    }

    float a0 = fmaxf(fmaxf(sc[0][0], sc[0][1]), sc[0][2]);
    float a1 = fmaxf(fmaxf(sc[0][3], sc[1][0]), sc[1][1]);
    float a2 = fmaxf(fmaxf(sc[1][2], sc[1][3]), sc[2][0]);
    float a3 = fmaxf(fmaxf(sc[2][1], sc[2][2]), sc[2][3]);
    float a4 = fmaxf(fmaxf(sc[3][0], sc[3][1]), sc[3][2]);
    float b0 = fmaxf(fmaxf(a0, a1), a2);
    float b1 = fmaxf(fmaxf(a3, a4), sc[3][3]);
    float pmax = fmaxf(b0, b1);
    pmax = fmaxf(pmax, __shfl_xor(pmax, 16));
    pmax = fmaxf(pmax, __shfl_xor(pmax, 32));

    const bool allkeep = __all(pmax - mrow <= 11.5441f);
    float fac;
    if (allkeep) {
      fac = 1.0f;
    } else {
      float nm = fmaxf(mrow, pmax);
      fac = EXP2(mrow - nm);
      mrow = nm;
#pragma unroll
      for (int dt = 0; dt < 4; ++dt)
#pragma unroll
        for (int r = 0; r < 4; ++r) o[dt][r] *= fac;
    }

#pragma unroll
    for (int kt = 0; kt < 4; ++kt) {
      bf16x4_a pb;
      pb[0] = (__bf16)EXP2(sc[kt][0] - mrow);
      pb[1] = (__bf16)EXP2(sc[kt][1] - mrow);
      pb[2] = (__bf16)EXP2(sc[kt][2] - mrow);
      pb[3] = (__bf16)EXP2(sc[kt][3] - mrow);
      *(bf16x4_a*)&pw[((4 * kt + g) ^ pswz) << 2] = pb;
    }

    bf16x8 pf0 = *(const bf16x8_a*)&pw[pwr0];
    bf16x8 pf1 = *(const bf16x8_a*)&pw[pwr1];

    f32x4 lacc = {};
    lacc = MFMA_B16(onesb, pf0, lacc);
    lacc = MFMA_B16(onesb, pf1, lacc);
    lrow = lrow * fac + lacc[0];

#pragma unroll
    for (int dt = 0; dt < 4; ++dt) {
      bf16x8 vf0 = *(const bf16x8_a*)&vbuf[dt * 1024 + krd0];
      bf16x8 vf1 = *(const bf16x8_a*)&vbuf[dt * 1024 + krd1];
      o[dt] = MFMA_B16(vf0, pf0, o[dt]);
      o[dt] = MFMA_B16(vf1, pf1, o[dt]);
    }
  };

  auto do_tile = [&](const unsigned short* kbuf, const unsigned short* vbuf) {
    proc(kbuf, vbuf, qf0, m0, l0, o0);
    proc(kbuf, vbuf, qf1, m1, l1, o1);
  };

  stage(0, 0);
#pragma unroll 1
  for (int t = 0; t < 32; t += 2) {
    __syncthreads();
    stage(1, (t + 1) * 64);
    do_tile(&sK[0][0], &sV[0][0]);
    __syncthreads();
    if (t + 2 < 32) stage(0, (t + 2) * 64);
    do_tile(&sK[1][0], &sV[1][0]);
  }

  const int b = bh >> 4, hh = bh & 15;
  const int s = q0 + wid * 16 + r15;
  const float inv0 = 1.f / l0, inv1 = 1.f / l1;
  unsigned short* orow0 = out + ((size_t)(b * 2048 + s)) * 1024 + hh * 64;
  unsigned short* orow1 = out + ((size_t)(b * 2048 + s + 64)) * 1024 + hh * 64;
#pragma unroll
  for (int dt = 0; dt < 4; ++dt) {
    bf16x4_a t0, t1;
    t0[0] = (__bf16)(o0[dt][0] * inv0);
    t0[1] = (__bf16)(o0[dt][1] * inv0);
    t0[2] = (__bf16)(o0[dt][2] * inv0);
    t0[3] = (__bf16)(o0[dt][3] * inv0);
    *(bf16x4_a*)(orow0 + dt * 16 + g * 4) = t0;
    t1[0] = (__bf16)(o1[dt][0] * inv1);
    t1[1] = (__bf16)(o1[dt][1] * inv1);
    t1[2] = (__bf16)(o1[dt][2] * inv1);
    t1[3] = (__bf16)(o1[dt][3] * inv1);
    *(bf16x4_a*)(orow1 + dt * 16 + g * 4) = t1;
  }
}

// ---------- fused 2x bf16-partial reduce + bias + residual + LN -> bf16 only ----------
__global__ __launch_bounds__(256) void ln2p_kernel(
    const unsigned short* __restrict__ p0, const unsigned short* __restrict__ p1,
    const float* __restrict__ bias, const float* __restrict__ resid,
    const float* __restrict__ gamma, const float* __restrict__ beta,
    unsigned short* __restrict__ outb) {
  const int row = blockIdx.x, tid = threadIdx.x;
  const size_t off = (size_t)row * 1024;
  u16x4_a a4 = *(const u16x4_a*)(p0 + off + tid * 4);
  u16x4_a b4 = *(const u16x4_a*)(p1 + off + tid * 4);
  float4 bb4 = ((const float4*)bias)[tid];
  float4 rr = ((const float4*)(resid + off))[tid];
  float4 v;
  v.x = b2f(a4[0]) + b2f(b4[0]) + bb4.x + rr.x;
  v.y = b2f(a4[1]) + b2f(b4[1]) + bb4.y + rr.y;
  v.z = b2f(a4[2]) + b2f(b4[2]) + bb4.z + rr.z;
  v.w = b2f(a4[3]) + b2f(b4[3]) + bb4.w + rr.w;

  float s = v.x + v.y + v.z + v.w;
  float ss = v.x * v.x + v.y * v.y + v.z * v.z + v.w * v.w;
#pragma unroll
  for (int o2 = 32; o2 > 0; o2 >>= 1) {
    s += __shfl_down(s, o2);
    ss += __shfl_down(ss, o2);
  }
  __shared__ float red[8];
  const int wid = tid >> 6;
  if ((tid & 63) == 0) { red[wid] = s; red[4 + wid] = ss; }
  __syncthreads();
  float S = red[0] + red[1] + red[2] + red[3];
  float SS = red[4] + red[5] + red[6] + red[7];
  const float mean = S * (1.f / 1024.f);
  const float var = SS * (1.f / 1024.f) - mean * mean;
  const float inv = 1.f / sqrtf(var + 1e-10f);
  float4 gg = ((const float4*)gamma)[tid];
  float4 be = ((const float4*)beta)[tid];
  float4 o;
  o.x = (v.x - mean) * inv * gg.x + be.x;
  o.y = (v.y - mean) * inv * gg.y + be.y;
  o.z = (v.z - mean) * inv * gg.z + be.z;
  o.w = (v.w - mean) * inv * gg.w + be.w;
  u16x4_a t = {f2b(o.x), f2b(o.y), f2b(o.z), f2b(o.w)};
  *(u16x4_a*)(outb + off + tid * 4) = t;
}

// ---------- fused 4x bf16-partial reduce + bias + bf16-residual + LN -> f32 ----------
__global__ __launch_bounds__(256) void ln4p_kernel(
    const unsigned short* __restrict__ p0, const unsigned short* __restrict__ p1,
    const unsigned short* __restrict__ p2, const unsigned short* __restrict__ p3,
    const float* __restrict__ bias, const unsigned short* __restrict__ residb,
    const float* __restrict__ gamma, const float* __restrict__ beta,
    float* __restrict__ outf) {
  const int row = blockIdx.x, tid = threadIdx.x;
  const size_t off = (size_t)row * 1024;
  u16x4_a a4 = *(const u16x4_a*)(p0 + off + tid * 4);
  u16x4_a b4 = *(const u16x4_a*)(p1 + off + tid * 4);
  u16x4_a c4 = *(const u16x4_a*)(p2 + off + tid * 4);
  u16x4_a d4 = *(const u16x4_a*)(p3 + off + tid * 4);
  u16x4_a r4 = *(const u16x4_a*)(residb + off + tid * 4);
  float4 bb4 = ((const float4*)bias)[tid];
  float4 v;
  v.x = (b2f(a4[0]) + b2f(b4[0])) + (b2f(c4[0]) + b2f(d4[0])) + bb4.x + b2f(r4[0]);
  v.y = (b2f(a4[1]) + b2f(b4[1])) + (b2f(c4[1]) + b2f(d4[1])) + bb4.y + b2f(r4[1]);
  v.z = (b2f(a4[2]) + b2f(b4[2])) + (b2f(c4[2]) + b2f(d4[2])) + bb4.z + b2f(r4[2]);
  v.w = (b2f(a4[3]) + b2f(b4[3])) + (b2f(c4[3]) + b2f(d4[3])) + bb4.w + b2f(r4[3]);

  float s = v.x + v.y + v.z + v.w;
  float ss = v.x * v.x + v.y * v.y + v.z * v.z + v.w * v.w;
#pragma unroll
  for (int o2 = 32; o2 > 0; o2 >>= 1) {
    s += __shfl_down(s, o2);
    ss += __shfl_down(ss, o2);
  }
  __shared__ float red[8];
  const int wid = tid >> 6;
  if ((tid & 63) == 0) { red[wid] = s; red[4 + wid] = ss; }
  __syncthreads();
  float S = red[0] + red[1] + red[2] + red[3];
  float SS = red[4] + red[5] + red[6] + red[7];
  const float mean = S * (1.f / 1024.f);
  const float var = SS * (1.f / 1024.f) - mean * mean;
  const float inv = 1.f / sqrtf(var + 1e-10f);
  float4 gg = ((const float4*)gamma)[tid];
  float4 be = ((const float4*)beta)[tid];
  float4 o;
  o.x = (v.x - mean) * inv * gg.x + be.x;
  o.y = (v.y - mean) * inv * gg.y + be.y;
  o.z = (v.z - mean) * inv * gg.z + be.z;
  o.w = (v.w - mean) * inv * gg.w + be.w;
  ((float4*)(outf + off))[tid] = o;
}

// ---------- launch ----------
extern "C" void kernel_launch(void* const* d_in, const int* in_sizes, int n_in,
                              void* d_out, int out_size, void* d_ws, size_t ws_size,
                              hipStream_t stream) {
  const float* x      = (const float*)d_in[0];
  const float* wq     = (const float*)d_in[1];
  const float* bq     = (const float*)d_in[2];
  const float* wk     = (const float*)d_in[3];
  const float* bk     = (const float*)d_in[4];
  const float* wv     = (const float*)d_in[5];
  const float* bv     = (const float*)d_in[6];
  const float* w_proj = (const float*)d_in[7];
  const float* b_proj = (const float*)d_in[8];
  const float* gamma1 = (const float*)d_in[9];
  const float* beta1  = (const float*)d_in[10];
  const float* w1     = (const float*)d_in[11];
  const float* b1     = (const float*)d_in[12];
  const float* w2     = (const float*)d_in[13];
  const float* b2     = (const float*)d_in[14];
  const float* gamma2 = (const float*)d_in[15];
  const float* beta2  = (const float*)d_in[16];

  char* p = (char*)d_ws;
  auto alloc = [&](size_t bytes) {
    char* r = p;
    p += (bytes + 255) & ~(size_t)255;
    return r;
  };
  unsigned short* xb      = (unsigned short*)alloc(4096ull * 1024 * 2);  // 8MB; dead after proj
  unsigned short* Wqkv_t  = (unsigned short*)alloc(3072ull * 1024 * 2);  // 6MB; dead after QKV
  unsigned short* Wproj_t = (unsigned short*)alloc(1024ull * 1024 * 2);  // 2MB; dead after proj
  unsigned short* W2t     = (unsigned short*)alloc(1024ull * 4096 * 2);  // 8MB; live thru FFN2
  float*          biasq   = (float*)alloc(3072 * 4);
  unsigned short* Qb      = (unsigned short*)alloc(4096ull * 1024 * 2);  // 8MB; dead after attn
  unsigned short* Kb      = (unsigned short*)alloc(4096ull * 1024 * 2);  // 8MB; dead after attn
  unsigned short* Vtb     = (unsigned short*)alloc(4096ull * 1024 * 2);  // 8MB; dead after attn
  unsigned short* W1t     = (unsigned short*)alloc(4096ull * 1024 * 2);  // 8MB; dead after FFN1
  unsigned short* out1b   = (unsigned short*)alloc(4096ull * 1024 * 2);  // live thru ln4p
  unsigned short* ffn_h   = (unsigned short*)alloc(4096ull * 4096 * 2);  // live thru FFN2
  unsigned short* concat  = xb;

  unsigned short* prA = Qb;
  unsigned short* prB = Kb;
  unsigned short* pp0 = xb;
  unsigned short* pp1 = Qb;
  unsigned short* pp2 = Kb;
  unsigned short* pp3 = Vtb;

  prepass_kernel<<<16396, 256, 0, stream>>>(x, wq, wk, wv, w_proj, w1, w2, bq, bk, bv,
                                            xb, Wqkv_t, Wproj_t, W1t, W2t, biasq);

  gemm256_kernel<0><<<192, 512, 0, stream>>>(xb, Wqkv_t, 4096, 3072, 1024, 12, 1, biasq,
                                             nullptr, Qb, Kb, Vtb, nullptr, nullptr,
                                             nullptr, nullptr);
  // attn: 2 q-groups/wave -> 512 blocks
  attn_kernel<<<dim3(16, 32), 256, 0, stream>>>(Qb, Kb, Vtb, concat);
  gemm_bt_kernel<<<dim3(8, 32, 2), 256, 0, stream>>>(concat, Wproj_t, 4096, 1024, 512, 1024,
                                                     prA, prB);
  ln2p_kernel<<<4096, 256, 0, stream>>>(prA, prB, b_proj, x, gamma1, beta1, out1b);
  gemm256_kernel<2><<<256, 512, 0, stream>>>(out1b, W1t, 4096, 4096, 1024, 16, 1, b1,
                                             ffn_h, nullptr, nullptr, nullptr,
                                             nullptr, nullptr, nullptr, nullptr);
  gemm256_kernel<3><<<256, 512, 0, stream>>>(ffn_h, W2t, 4096, 1024, 4096, 4, 4, nullptr,
                                             nullptr, nullptr, nullptr, nullptr,
                                             pp0, pp1, pp2, pp3);
  ln4p_kernel<<<4096, 256, 0, stream>>>(pp0, pp1, pp2, pp3, b2, out1b, gamma2, beta2,
                                        (float*)d_out);
}

// Round 17
// 232.016 us; speedup vs baseline: 1.4461x; 1.0059x over previous
//
#include <hip/hip_runtime.h>
#include <stdint.h>

// ---------- types ----------
typedef float f32x4 __attribute__((ext_vector_type(4)));
typedef __bf16 bf16x8 __attribute__((ext_vector_type(8)));
typedef __bf16 bf16x8_a __attribute__((ext_vector_type(8), may_alias));
typedef __bf16 bf16x4_a __attribute__((ext_vector_type(4), may_alias));
typedef unsigned int u32x4_a __attribute__((ext_vector_type(4), may_alias));
typedef unsigned short u16x4_a __attribute__((ext_vector_type(4), may_alias));

#define DEV __device__ __forceinline__
#define MFMA_B16(a, b, c) __builtin_amdgcn_mfma_f32_16x16x32_bf16((a), (b), (c), 0, 0, 0)

#if __has_builtin(__builtin_amdgcn_exp2f)
#define EXP2(x) __builtin_amdgcn_exp2f(x)
#else
#define EXP2(x) exp2f(x)
#endif

DEV unsigned short f2b(float f) {  // f32 -> bf16 RNE
  unsigned int u = __float_as_uint(f);
  u = u + 0x7FFFu + ((u >> 16) & 1u);
  return (unsigned short)(u >> 16);
}
DEV float b2f(unsigned short u) { return __uint_as_float(((unsigned int)u) << 16); }

// async global->LDS, 16B per lane; LDS dest is wave-uniform base + lane*16
#define GLOAD_LDS16(gsrc, ldst)                                                  \
  __builtin_amdgcn_global_load_lds(                                              \
      (__attribute__((address_space(1))) void*)(uintptr_t)(const void*)(gsrc),   \
      (__attribute__((address_space(3))) void*)(ldst), 16, 0, 0)

// ---------- fused prepass: cvt x | transpose wq/wk/wv | transpose w_proj/w1/w2 | bias ----------
__global__ __launch_bounds__(256) void prepass_kernel(
    const float* __restrict__ x, const float* __restrict__ wq,
    const float* __restrict__ wk, const float* __restrict__ wv,
    const float* __restrict__ w_proj, const float* __restrict__ w1,
    const float* __restrict__ w2, const float* __restrict__ bq,
    const float* __restrict__ bk, const float* __restrict__ bv,
    unsigned short* __restrict__ xb, unsigned short* __restrict__ Wqkv_t,
    unsigned short* __restrict__ o_proj, unsigned short* __restrict__ o1,
    unsigned short* __restrict__ o2, float* __restrict__ biasq) {
  __shared__ float tile[32][33];
  int bid = blockIdx.x;
  if (bid < 4096) {  // cvt: x f32 -> bf16
    int i = bid * 256 + threadIdx.x;
    float4 v = ((const float4*)x)[i];
    u16x4_a t = {f2b(v.x), f2b(v.y), f2b(v.z), f2b(v.w)};
    ((u16x4_a*)xb)[i] = t;
    return;
  }
  bid -= 4096;
  if (bid < 3072) {  // tqkv
    const int bx = bid & 1, by = (bid >> 1) & 31, zz = bid >> 6;
    const int sel = zz >> 4, zh = zz & 15;
    const float scale = sel == 0 ? 0.18033688f : 1.f;  // q: 1/sqrt(HD)*log2(e)
    const float* ip = (sel == 0 ? wq : (sel == 1 ? wk : wv)) + (size_t)zh * 1024 * 64;
    unsigned short* op = Wqkv_t + (size_t)sel * 1024 * 1024 + (size_t)zh * 1024 * 64;
    const int tx = threadIdx.x & 31, ty = threadIdx.x >> 5;
    const int c0 = bx * 32, r0 = by * 32;
#pragma unroll
    for (int j = 0; j < 32; j += 8)
      tile[ty + j][tx] = ip[(size_t)(r0 + ty + j) * 64 + (c0 + tx)];
    __syncthreads();
#pragma unroll
    for (int j = 0; j < 32; j += 8)
      op[(size_t)(c0 + ty + j) * 1024 + (r0 + tx)] = f2b(tile[tx][ty + j] * scale);
    return;
  }
  bid -= 3072;
  if (bid < 9216) {  // tw
    const float* in;
    unsigned short* out;
    int rows, cols, bx, by;
    if (bid < 1024) {
      in = w_proj; out = o_proj; rows = 1024; cols = 1024; bx = bid & 31; by = bid >> 5;
    } else if (bid < 5120) {
      bid -= 1024; in = w1; out = o1; rows = 1024; cols = 4096; bx = bid & 127; by = bid >> 7;
    } else {
      bid -= 5120; in = w2; out = o2; rows = 4096; cols = 1024; bx = bid & 31; by = bid >> 5;
    }
    const int tx = threadIdx.x & 31, ty = threadIdx.x >> 5;
    const int c0 = bx * 32, r0 = by * 32;
#pragma unroll
    for (int j = 0; j < 32; j += 8)
      tile[ty + j][tx] = in[(size_t)(r0 + ty + j) * cols + (c0 + tx)];
    __syncthreads();
#pragma unroll
    for (int j = 0; j < 32; j += 8)
      out[(size_t)(c0 + ty + j) * rows + (r0 + tx)] = f2b(tile[tx][ty + j]);
    return;
  }
  bid -= 9216;  // bias
  int c = bid * 256 + threadIdx.x;
  int which = c >> 10, idx = c & 1023;
  float v = which == 0 ? bq[idx] : (which == 1 ? bk[idx] : bv[idx]);
  biasq[c] = which == 0 ? v * 0.18033688f : v;
}

// ---------- 256x256 8-phase GEMM (m201 template, plain HIP; R11 epilogues) ----------
// EP 0: QKV scatter + bias. EP 2: bf16 relu. EP 3: bf16 raw partial (split-K).
template <int EP>
__global__ __launch_bounds__(512, 2) void gemm256_kernel(
    const unsigned short* __restrict__ A, const unsigned short* __restrict__ Bt,
    int M, int N, int K, int nbx, int KS,
    const float* __restrict__ bias, unsigned short* __restrict__ outb,
    unsigned short* __restrict__ q_out, unsigned short* __restrict__ k_out,
    unsigned short* __restrict__ v_out,
    unsigned short* __restrict__ pp0, unsigned short* __restrict__ pp1,
    unsigned short* __restrict__ pp2, unsigned short* __restrict__ pp3) {
  __shared__ __align__(16) unsigned short sA[2][256 * 64];
  __shared__ __align__(16) unsigned short sB[2][256 * 64];

  const int tid = threadIdx.x;
  const int wid = tid >> 6, lane = tid & 63;
  const int g = lane >> 4, r15 = lane & 15;
  const int wm = wid >> 2, wn = wid & 3;

  const int nwg = gridDim.x, cpx = nwg >> 3, orig = blockIdx.x;
  const int wg = (orig & 7) * cpx + (orig >> 3);
  const int bx = wg % nbx;
  const int t1 = wg / nbx;
  const int kz = t1 % KS, by = t1 / KS;
  const int row0 = by * 256, col0 = bx * 256;

  const int tilesK = K >> 6;
  const int qT = tilesK / KS, rT = tilesK % KS;
  const int tile0 = kz * qT + (kz < rT ? kz : rT);
  const int NT = qT + (kz < rT ? 1 : 0);
  const int kbase = tile0 << 6;

  const unsigned short* gA0 = A + (size_t)row0 * K + kbase;
  const unsigned short* gB0 = Bt + (size_t)col0 * K + kbase;
  const int srow8 = lane >> 3;
  const int schunk = ((lane & 7) ^ srow8) * 8;

  f32x4 acc[8][4] = {};
  bf16x8 af[4][2], bfr[4][2];

  auto stA = [&](int buf, int k0, int i) {
    const int r = wid * 32 + i * 8;
    GLOAD_LDS16(gA0 + (size_t)(r + srow8) * K + k0 + schunk, &sA[buf][r * 64]);
  };
  auto stB = [&](int buf, int k0, int i) {
    const int r = wid * 32 + i * 8;
    GLOAD_LDS16(gB0 + (size_t)(r + srow8) * K + k0 + schunk, &sB[buf][r * 64]);
  };
  auto ldA = [&](const unsigned short* p, int m, int ks) -> bf16x8 {
    const int row = wm * 128 + m * 16 + r15;
    return *(const bf16x8_a*)&p[row * 64 + (((ks * 4 + g) ^ (r15 & 7)) * 8)];
  };
  auto ldB = [&](const unsigned short* p, int n, int ks) -> bf16x8 {
    const int row = wn * 64 + n * 16 + r15;
    return *(const bf16x8_a*)&p[row * 64 + (((ks * 4 + g) ^ (r15 & 7)) * 8)];
  };

#pragma unroll
  for (int i = 0; i < 4; ++i) { stA(0, 0, i); stB(0, 0, i); }
  asm volatile("s_waitcnt vmcnt(0)" ::: "memory");
  __builtin_amdgcn_s_barrier();

  for (int kt = 0; kt < NT; ++kt) {
    const int cb = kt & 1, nb = cb ^ 1;
    const bool pf = (kt + 1) < NT;
    const int k1 = (kt + 1) << 6;
    const unsigned short* pA = sA[cb];
    const unsigned short* pB = sB[cb];

#pragma unroll
    for (int m = 0; m < 4; ++m) { af[m][0] = ldA(pA, m, 0); af[m][1] = ldA(pA, m, 1); }
#pragma unroll
    for (int n = 0; n < 4; ++n) { bfr[n][0] = ldB(pB, n, 0); bfr[n][1] = ldB(pB, n, 1); }
    if (pf) { stA(nb, k1, 0); stA(nb, k1, 1); }
    __builtin_amdgcn_s_barrier();
    asm volatile("s_waitcnt lgkmcnt(0)" ::: "memory");
    __builtin_amdgcn_sched_barrier(0);
    __builtin_amdgcn_s_setprio(1);
#pragma unroll
    for (int m = 0; m < 4; ++m)
#pragma unroll
      for (int n = 0; n < 2; ++n) {
        acc[m][n] = MFMA_B16(af[m][0], bfr[n][0], acc[m][n]);
        acc[m][n] = MFMA_B16(af[m][1], bfr[n][1], acc[m][n]);
      }
    __builtin_amdgcn_s_setprio(0);
    __builtin_amdgcn_s_barrier();

    if (pf) { stA(nb, k1, 2); stA(nb, k1, 3); }
    __builtin_amdgcn_s_barrier();
    __builtin_amdgcn_s_setprio(1);
#pragma unroll
    for (int m = 0; m < 4; ++m)
#pragma unroll
      for (int n = 2; n < 4; ++n) {
        acc[m][n] = MFMA_B16(af[m][0], bfr[n][0], acc[m][n]);
        acc[m][n] = MFMA_B16(af[m][1], bfr[n][1], acc[m][n]);
      }
    __builtin_amdgcn_s_setprio(0);
    __builtin_amdgcn_s_barrier();

#pragma unroll
    for (int m = 0; m < 4; ++m) { af[m][0] = ldA(pA, m + 4, 0); af[m][1] = ldA(pA, m + 4, 1); }
    if (pf) { stB(nb, k1, 0); stB(nb, k1, 1); }
    __builtin_amdgcn_s_barrier();
    asm volatile("s_waitcnt lgkmcnt(0)" ::: "memory");
    __builtin_amdgcn_sched_barrier(0);
    __builtin_amdgcn_s_setprio(1);
#pragma unroll
    for (int m = 0; m < 4; ++m)
#pragma unroll
      for (int n = 0; n < 2; ++n) {
        acc[m + 4][n] = MFMA_B16(af[m][0], bfr[n][0], acc[m + 4][n]);
        acc[m + 4][n] = MFMA_B16(af[m][1], bfr[n][1], acc[m + 4][n]);
      }
    __builtin_amdgcn_s_setprio(0);
    __builtin_amdgcn_s_barrier();

    if (pf) { stB(nb, k1, 2); stB(nb, k1, 3); }
    __builtin_amdgcn_s_barrier();
    __builtin_amdgcn_s_setprio(1);
#pragma unroll
    for (int m = 0; m < 4; ++m)
#pragma unroll
      for (int n = 2; n < 4; ++n) {
        acc[m + 4][n] = MFMA_B16(af[m][0], bfr[n][0], acc[m + 4][n]);
        acc[m + 4][n] = MFMA_B16(af[m][1], bfr[n][1], acc[m + 4][n]);
      }
    __builtin_amdgcn_s_setprio(0);
    asm volatile("s_waitcnt vmcnt(0)" ::: "memory");
    __builtin_amdgcn_s_barrier();
  }

  unsigned short* pz = kz == 0 ? pp0 : (kz == 1 ? pp1 : (kz == 2 ? pp2 : pp3));
#pragma unroll
  for (int m = 0; m < 8; ++m) {
    const int rbase = row0 + wm * 128 + m * 16 + g * 4;
#pragma unroll
    for (int n = 0; n < 4; ++n) {
      const int col = col0 + wn * 64 + n * 16 + r15;
      const float bb = (EP == 3) ? 0.f : bias[col];
      if constexpr (EP == 0) {
        const int which = col >> 10, cc = col & 1023;
        const int hh = cc >> 6, e = cc & 63;
        const int b = rbase >> 11, s0v = rbase & 2047;
        if (which == 2) {
          bf16x4_a pk;
#pragma unroll
          for (int r = 0; r < 4; ++r) pk[r] = (__bf16)(acc[m][n][r] + bb);
          *(bf16x4_a*)(v_out + (((size_t)(b * 16 + hh) * 64) + e) * 2048 + s0v) = pk;
        } else {
          unsigned short* dst = which == 0 ? q_out : k_out;
#pragma unroll
          for (int r = 0; r < 4; ++r)
            dst[(((size_t)(b * 16 + hh) * 2048) + s0v + r) * 64 + e] =
                f2b(acc[m][n][r] + bb);
        }
      } else {
#pragma unroll
        for (int r = 0; r < 4; ++r) {
          const int row = rbase + r;
          float v = acc[m][n][r] + bb;
          if constexpr (EP == 3) {
            pz[(size_t)row * N + col] = f2b(v);
          } else {
            outb[(size_t)row * N + col] = f2b(v > 0.f ? v : 0.f);
          }
        }
      }
    }
  }
}

// ---------- 128x128 GEMM, split-K over blockIdx.z, bf16 partial out (R11) ----------
__global__ __launch_bounds__(256) void gemm_bt_kernel(
    const unsigned short* __restrict__ A, const unsigned short* __restrict__ Bt,
    int M, int N, int Kchunk, int Kstride,
    unsigned short* __restrict__ pp0, unsigned short* __restrict__ pp1) {
  __shared__ __align__(16) unsigned short sA[2][128 * 32];
  __shared__ __align__(16) unsigned short sB[2][128 * 32];
  const int tid = threadIdx.x;
  const int wid = tid >> 6, lane = tid & 63;
  const int g = lane >> 4, r15 = lane & 15;
  const int wr = wid >> 1, wc = wid & 1;
  const int row0 = blockIdx.y * 128, col0 = blockIdx.x * 128;
  const int kz = blockIdx.z;

  f32x4 acc[4][4] = {};

  const int c0 = wid * 128 + lane;
  const unsigned short* gA0 = A + (size_t)row0 * Kstride + (size_t)kz * Kchunk;
  const unsigned short* gB0 = Bt + (size_t)col0 * Kstride + (size_t)kz * Kchunk;

  auto stage = [&](int buf, int k0) {
#pragma unroll
    for (int j = 0; j < 2; ++j) {
      int c = c0 + j * 64;
      GLOAD_LDS16(gA0 + (size_t)(c >> 2) * Kstride + k0 + (c & 3) * 8,
                  &sA[buf][(wid * 128 + j * 64) * 8]);
      GLOAD_LDS16(gB0 + (size_t)(c >> 2) * Kstride + k0 + (c & 3) * 8,
                  &sB[buf][(wid * 128 + j * 64) * 8]);
    }
  };

  stage(0, 0);
  const int NT = Kchunk >> 5;
  for (int t = 0; t < NT; ++t) {
    const int cb = t & 1;
    __syncthreads();
    if (t + 1 < NT) stage(cb ^ 1, (t + 1) * 32);
    bf16x8 af[4], bfr[4];
#pragma unroll
    for (int m = 0; m < 4; ++m)
      af[m] = *(const bf16x8_a*)&sA[cb][(wr * 64 + m * 16 + r15) * 32 + g * 8];
#pragma unroll
    for (int n = 0; n < 4; ++n)
      bfr[n] = *(const bf16x8_a*)&sB[cb][(wc * 64 + n * 16 + r15) * 32 + g * 8];
#pragma unroll
    for (int m = 0; m < 4; ++m)
#pragma unroll
      for (int n = 0; n < 4; ++n)
        acc[m][n] = MFMA_B16(af[m], bfr[n], acc[m][n]);
  }

  unsigned short* pz = kz == 0 ? pp0 : pp1;
#pragma unroll
  for (int m = 0; m < 4; ++m) {
    const int rbase = row0 + wr * 64 + m * 16 + g * 4;
#pragma unroll
    for (int n = 0; n < 4; ++n) {
      const int col = col0 + wc * 64 + n * 16 + r15;
#pragma unroll
      for (int r = 0; r < 4; ++r)
        pz[(size_t)(rbase + r) * N + col] = f2b(acc[m][n][r]);
    }
  }
}

// ---------- flash attention: 2 q-groups/wave, 4-deep K/V buffers ----------
// 2 barriers per 4 KV tiles (halved vs R16); each staged tile has a 2-tile
// compute window in flight. LDS 72KB -> 2 blocks/CU (= grid cap).
__global__ __launch_bounds__(256) void attn_kernel(const unsigned short* __restrict__ Q,
                                                   const unsigned short* __restrict__ K,
                                                   const unsigned short* __restrict__ Vt,
                                                   unsigned short* __restrict__ out) {
  const int flat = blockIdx.y * gridDim.x + blockIdx.x;  // 0..511
  const int xcd = flat & 7, rest = flat >> 3;            // rest 0..63
  const int bh = xcd * 4 + (rest >> 4);
  const int q0 = (rest & 15) * 128;

  const int tid = threadIdx.x, wid = tid >> 6, lane = tid & 63;
  const int g = lane >> 4, r15 = lane & 15;
  const int h = r15 & 7;
  const int s0 = ((g ^ h) * 8);
  const int s1 = (((g + 4) ^ h) * 8);
  const int pswz = r15 & 14;

  __shared__ __align__(16) unsigned short sK[4][64 * 64];
  __shared__ __align__(16) unsigned short sV[4][64 * 64];
  __shared__ __align__(16) unsigned short sP[4][16 * 64];

  const size_t base = (size_t)bh * (2048 * 64);
  const unsigned short* Kb = K + base;
  const unsigned short* Vb = Vt + base;

  const int qrow0 = q0 + wid * 16 + r15;
  bf16x8 qf0[2], qf1[2];
  qf0[0] = *(const bf16x8_a*)(Q + base + (size_t)qrow0 * 64 + g * 8);
  qf0[1] = *(const bf16x8_a*)(Q + base + (size_t)qrow0 * 64 + 32 + g * 8);
  qf1[0] = *(const bf16x8_a*)(Q + base + (size_t)(qrow0 + 64) * 64 + g * 8);
  qf1[1] = *(const bf16x8_a*)(Q + base + (size_t)(qrow0 + 64) * 64 + 32 + g * 8);

  const int srow = lane >> 3;
  const int schunk = ((lane & 7) ^ srow) * 8;

  union {
    unsigned short u[8];
    bf16x8 v;
  } ou;
#pragma unroll
  for (int i = 0; i < 8; ++i) ou.u[i] = 0x3F80;
  const bf16x8 onesb = ou.v;

  f32x4 o0[4] = {}, o1[4] = {};
  float m0 = -1e30f, l0 = 0.f, m1 = -1e30f, l1 = 0.f;

  const int krd0 = r15 * 64 + s0;
  const int krd1 = r15 * 64 + s1;
  unsigned short* const pw = &sP[wid][r15 * 64];
  const int pwr0 = ((2 * g) ^ pswz) << 2;
  const int pwr1 = ((8 + 2 * g) ^ pswz) << 2;

  auto stage = [&](int bufi, int tile) {
    const int kt0s = tile * 64;
#pragma unroll
    for (int i = 0; i < 2; ++i) {
      const int inst = wid * 2 + i;
      const int row = 8 * inst + srow;
      GLOAD_LDS16(Kb + (size_t)(kt0s + row) * 64 + schunk, &sK[bufi][inst * 512]);
      GLOAD_LDS16(Vb + (size_t)row * 2048 + kt0s + schunk, &sV[bufi][inst * 512]);
    }
  };

  auto proc = [&](const unsigned short* kbuf, const unsigned short* vbuf,
                  const bf16x8 (&qf)[2], float& mrow, float& lrow, f32x4 (&o)[4]) {
    f32x4 sc[4] = {};
#pragma unroll
    for (int kt = 0; kt < 4; ++kt) {
      bf16x8 kf0 = *(const bf16x8_a*)&kbuf[kt * 1024 + krd0];
      bf16x8 kf1 = *(const bf16x8_a*)&kbuf[kt * 1024 + krd1];
      sc[kt] = MFMA_B16(kf0, qf[0], sc[kt]);
      sc[kt] = MFMA_B16(kf1, qf[1], sc[kt]);
    }

    float a0 = fmaxf(fmaxf(sc[0][0], sc[0][1]), sc[0][2]);
    float a1 = fmaxf(fmaxf(sc[0][3], sc[1][0]), sc[1][1]);
    float a2 = fmaxf(fmaxf(sc[1][2], sc[1][3]), sc[2][0]);
    float a3 = fmaxf(fmaxf(sc[2][1], sc[2][2]), sc[2][3]);
    float a4 = fmaxf(fmaxf(sc[3][0], sc[3][1]), sc[3][2]);
    float b0 = fmaxf(fmaxf(a0, a1), a2);
    float b1 = fmaxf(fmaxf(a3, a4), sc[3][3]);
    float pmax = fmaxf(b0, b1);
    pmax = fmaxf(pmax, __shfl_xor(pmax, 16));
    pmax = fmaxf(pmax, __shfl_xor(pmax, 32));

    const bool allkeep = __all(pmax - mrow <= 11.5441f);
    float fac;
    if (allkeep) {
      fac = 1.0f;
    } else {
      float nm = fmaxf(mrow, pmax);
      fac = EXP2(mrow - nm);
      mrow = nm;
#pragma unroll
      for (int dt = 0; dt < 4; ++dt)
#pragma unroll
        for (int r = 0; r < 4; ++r) o[dt][r] *= fac;
    }

#pragma unroll
    for (int kt = 0; kt < 4; ++kt) {
      bf16x4_a pb;
      pb[0] = (__bf16)EXP2(sc[kt][0] - mrow);
      pb[1] = (__bf16)EXP2(sc[kt][1] - mrow);
      pb[2] = (__bf16)EXP2(sc[kt][2] - mrow);
      pb[3] = (__bf16)EXP2(sc[kt][3] - mrow);
      *(bf16x4_a*)&pw[((4 * kt + g) ^ pswz) << 2] = pb;
    }

    bf16x8 pf0 = *(const bf16x8_a*)&pw[pwr0];
    bf16x8 pf1 = *(const bf16x8_a*)&pw[pwr1];

    f32x4 lacc = {};
    lacc = MFMA_B16(onesb, pf0, lacc);
    lacc = MFMA_B16(onesb, pf1, lacc);
    lrow = lrow * fac + lacc[0];

#pragma unroll
    for (int dt = 0; dt < 4; ++dt) {
      bf16x8 vf0 = *(const bf16x8_a*)&vbuf[dt * 1024 + krd0];
      bf16x8 vf1 = *(const bf16x8_a*)&vbuf[dt * 1024 + krd1];
      o[dt] = MFMA_B16(vf0, pf0, o[dt]);
      o[dt] = MFMA_B16(vf1, pf1, o[dt]);
    }
  };

  auto do_tile = [&](const unsigned short* kbuf, const unsigned short* vbuf) {
    proc(kbuf, vbuf, qf0, m0, l0, o0);
    proc(kbuf, vbuf, qf1, m1, l1, o1);
  };

  // prologue: tiles 0,1 into bufs 0,1
  stage(0, 0);
  stage(1, 1);
  // steady state: 2 barriers per 4 tiles. WAR safety: each buffer's re-stage is
  // issued after a barrier that follows its last read (traced per-buffer).
#pragma unroll 1
  for (int t = 0; t < 32; t += 4) {
    __syncthreads();                       // bufs (t,t+1) ready
    stage(2, t + 2);
    stage(3, t + 3);
    do_tile(&sK[0][0], &sV[0][0]);         // tile t
    do_tile(&sK[1][0], &sV[1][0]);         // tile t+1
    __syncthreads();                       // bufs (t+2,t+3) ready
    if (t + 4 < 32) {
      stage(0, t + 4);
      stage(1, t + 5);
    }
    do_tile(&sK[2][0], &sV[2][0]);         // tile t+2
    do_tile(&sK[3][0], &sV[3][0]);         // tile t+3
  }

  const int b = bh >> 4, hh = bh & 15;
  const int s = q0 + wid * 16 + r15;
  const float inv0 = 1.f / l0, inv1 = 1.f / l1;
  unsigned short* orow0 = out + ((size_t)(b * 2048 + s)) * 1024 + hh * 64;
  unsigned short* orow1 = out + ((size_t)(b * 2048 + s + 64)) * 1024 + hh * 64;
#pragma unroll
  for (int dt = 0; dt < 4; ++dt) {
    bf16x4_a t0, t1;
    t0[0] = (__bf16)(o0[dt][0] * inv0);
    t0[1] = (__bf16)(o0[dt][1] * inv0);
    t0[2] = (__bf16)(o0[dt][2] * inv0);
    t0[3] = (__bf16)(o0[dt][3] * inv0);
    *(bf16x4_a*)(orow0 + dt * 16 + g * 4) = t0;
    t1[0] = (__bf16)(o1[dt][0] * inv1);
    t1[1] = (__bf16)(o1[dt][1] * inv1);
    t1[2] = (__bf16)(o1[dt][2] * inv1);
    t1[3] = (__bf16)(o1[dt][3] * inv1);
    *(bf16x4_a*)(orow1 + dt * 16 + g * 4) = t1;
  }
}

// ---------- fused 2x bf16-partial reduce + bias + residual + LN -> bf16 only ----------
__global__ __launch_bounds__(256) void ln2p_kernel(
    const unsigned short* __restrict__ p0, const unsigned short* __restrict__ p1,
    const float* __restrict__ bias, const float* __restrict__ resid,
    const float* __restrict__ gamma, const float* __restrict__ beta,
    unsigned short* __restrict__ outb) {
  const int row = blockIdx.x, tid = threadIdx.x;
  const size_t off = (size_t)row * 1024;
  u16x4_a a4 = *(const u16x4_a*)(p0 + off + tid * 4);
  u16x4_a b4 = *(const u16x4_a*)(p1 + off + tid * 4);
  float4 bb4 = ((const float4*)bias)[tid];
  float4 rr = ((const float4*)(resid + off))[tid];
  float4 v;
  v.x = b2f(a4[0]) + b2f(b4[0]) + bb4.x + rr.x;
  v.y = b2f(a4[1]) + b2f(b4[1]) + bb4.y + rr.y;
  v.z = b2f(a4[2]) + b2f(b4[2]) + bb4.z + rr.z;
  v.w = b2f(a4[3]) + b2f(b4[3]) + bb4.w + rr.w;

  float s = v.x + v.y + v.z + v.w;
  float ss = v.x * v.x + v.y * v.y + v.z * v.z + v.w * v.w;
#pragma unroll
  for (int o2 = 32; o2 > 0; o2 >>= 1) {
    s += __shfl_down(s, o2);
    ss += __shfl_down(ss, o2);
  }
  __shared__ float red[8];
  const int wid = tid >> 6;
  if ((tid & 63) == 0) { red[wid] = s; red[4 + wid] = ss; }
  __syncthreads();
  float S = red[0] + red[1] + red[2] + red[3];
  float SS = red[4] + red[5] + red[6] + red[7];
  const float mean = S * (1.f / 1024.f);
  const float var = SS * (1.f / 1024.f) - mean * mean;
  const float inv = 1.f / sqrtf(var + 1e-10f);
  float4 gg = ((const float4*)gamma)[tid];
  float4 be = ((const float4*)beta)[tid];
  float4 o;
  o.x = (v.x - mean) * inv * gg.x + be.x;
  o.y = (v.y - mean) * inv * gg.y + be.y;
  o.z = (v.z - mean) * inv * gg.z + be.z;
  o.w = (v.w - mean) * inv * gg.w + be.w;
  u16x4_a t = {f2b(o.x), f2b(o.y), f2b(o.z), f2b(o.w)};
  *(u16x4_a*)(outb + off + tid * 4) = t;
}

// ---------- fused 4x bf16-partial reduce + bias + bf16-residual + LN -> f32 ----------
__global__ __launch_bounds__(256) void ln4p_kernel(
    const unsigned short* __restrict__ p0, const unsigned short* __restrict__ p1,
    const unsigned short* __restrict__ p2, const unsigned short* __restrict__ p3,
    const float* __restrict__ bias, const unsigned short* __restrict__ residb,
    const float* __restrict__ gamma, const float* __restrict__ beta,
    float* __restrict__ outf) {
  const int row = blockIdx.x, tid = threadIdx.x;
  const size_t off = (size_t)row * 1024;
  u16x4_a a4 = *(const u16x4_a*)(p0 + off + tid * 4);
  u16x4_a b4 = *(const u16x4_a*)(p1 + off + tid * 4);
  u16x4_a c4 = *(const u16x4_a*)(p2 + off + tid * 4);
  u16x4_a d4 = *(const u16x4_a*)(p3 + off + tid * 4);
  u16x4_a r4 = *(const u16x4_a*)(residb + off + tid * 4);
  float4 bb4 = ((const float4*)bias)[tid];
  float4 v;
  v.x = (b2f(a4[0]) + b2f(b4[0])) + (b2f(c4[0]) + b2f(d4[0])) + bb4.x + b2f(r4[0]);
  v.y = (b2f(a4[1]) + b2f(b4[1])) + (b2f(c4[1]) + b2f(d4[1])) + bb4.y + b2f(r4[1]);
  v.z = (b2f(a4[2]) + b2f(b4[2])) + (b2f(c4[2]) + b2f(d4[2])) + bb4.z + b2f(r4[2]);
  v.w = (b2f(a4[3]) + b2f(b4[3])) + (b2f(c4[3]) + b2f(d4[3])) + bb4.w + b2f(r4[3]);

  float s = v.x + v.y + v.z + v.w;
  float ss = v.x * v.x + v.y * v.y + v.z * v.z + v.w * v.w;
#pragma unroll
  for (int o2 = 32; o2 > 0; o2 >>= 1) {
    s += __shfl_down(s, o2);
    ss += __shfl_down(ss, o2);
  }
  __shared__ float red[8];
  const int wid = tid >> 6;
  if ((tid & 63) == 0) { red[wid] = s; red[4 + wid] = ss; }
  __syncthreads();
  float S = red[0] + red[1] + red[2] + red[3];
  float SS = red[4] + red[5] + red[6] + red[7];
  const float mean = S * (1.f / 1024.f);
  const float var = SS * (1.f / 1024.f) - mean * mean;
  const float inv = 1.f / sqrtf(var + 1e-10f);
  float4 gg = ((const float4*)gamma)[tid];
  float4 be = ((const float4*)beta)[tid];
  float4 o;
  o.x = (v.x - mean) * inv * gg.x + be.x;
  o.y = (v.y - mean) * inv * gg.y + be.y;
  o.z = (v.z - mean) * inv * gg.z + be.z;
  o.w = (v.w - mean) * inv * gg.w + be.w;
  ((float4*)(outf + off))[tid] = o;
}

// ---------- launch ----------
extern "C" void kernel_launch(void* const* d_in, const int* in_sizes, int n_in,
                              void* d_out, int out_size, void* d_ws, size_t ws_size,
                              hipStream_t stream) {
  const float* x      = (const float*)d_in[0];
  const float* wq     = (const float*)d_in[1];
  const float* bq     = (const float*)d_in[2];
  const float* wk     = (const float*)d_in[3];
  const float* bk     = (const float*)d_in[4];
  const float* wv     = (const float*)d_in[5];
  const float* bv     = (const float*)d_in[6];
  const float* w_proj = (const float*)d_in[7];
  const float* b_proj = (const float*)d_in[8];
  const float* gamma1 = (const float*)d_in[9];
  const float* beta1  = (const float*)d_in[10];
  const float* w1     = (const float*)d_in[11];
  const float* b1     = (const float*)d_in[12];
  const float* w2     = (const float*)d_in[13];
  const float* b2     = (const float*)d_in[14];
  const float* gamma2 = (const float*)d_in[15];
  const float* beta2  = (const float*)d_in[16];

  char* p = (char*)d_ws;
  auto alloc = [&](size_t bytes) {
    char* r = p;
    p += (bytes + 255) & ~(size_t)255;
    return r;
  };
  unsigned short* xb      = (unsigned short*)alloc(4096ull * 1024 * 2);  // 8MB; dead after proj
  unsigned short* Wqkv_t  = (unsigned short*)alloc(3072ull * 1024 * 2);  // 6MB; dead after QKV
  unsigned short* Wproj_t = (unsigned short*)alloc(1024ull * 1024 * 2);  // 2MB; dead after proj
  unsigned short* W2t     = (unsigned short*)alloc(1024ull * 4096 * 2);  // 8MB; live thru FFN2
  float*          biasq   = (float*)alloc(3072 * 4);
  unsigned short* Qb      = (unsigned short*)alloc(4096ull * 1024 * 2);  // 8MB; dead after attn
  unsigned short* Kb      = (unsigned short*)alloc(4096ull * 1024 * 2);  // 8MB; dead after attn
  unsigned short* Vtb     = (unsigned short*)alloc(4096ull * 1024 * 2);  // 8MB; dead after attn
  unsigned short* W1t     = (unsigned short*)alloc(4096ull * 1024 * 2);  // 8MB; dead after FFN1
  unsigned short* out1b   = (unsigned short*)alloc(4096ull * 1024 * 2);  // live thru ln4p
  unsigned short* ffn_h   = (unsigned short*)alloc(4096ull * 4096 * 2);  // live thru FFN2
  unsigned short* concat  = xb;

  unsigned short* prA = Qb;
  unsigned short* prB = Kb;
  unsigned short* pp0 = xb;
  unsigned short* pp1 = Qb;
  unsigned short* pp2 = Kb;
  unsigned short* pp3 = Vtb;

  prepass_kernel<<<16396, 256, 0, stream>>>(x, wq, wk, wv, w_proj, w1, w2, bq, bk, bv,
                                            xb, Wqkv_t, Wproj_t, W1t, W2t, biasq);

  gemm256_kernel<0><<<192, 512, 0, stream>>>(xb, Wqkv_t, 4096, 3072, 1024, 12, 1, biasq,
                                             nullptr, Qb, Kb, Vtb, nullptr, nullptr,
                                             nullptr, nullptr);
  // attn: 2 q-groups/wave, 4-deep buffers -> 512 blocks
  attn_kernel<<<dim3(16, 32), 256, 0, stream>>>(Qb, Kb, Vtb, concat);
  gemm_bt_kernel<<<dim3(8, 32, 2), 256, 0, stream>>>(concat, Wproj_t, 4096, 1024, 512, 1024,
                                                     prA, prB);
  ln2p_kernel<<<4096, 256, 0, stream>>>(prA, prB, b_proj, x, gamma1, beta1, out1b);
  gemm256_kernel<2><<<256, 512, 0, stream>>>(out1b, W1t, 4096, 4096, 1024, 16, 1, b1,
                                             ffn_h, nullptr, nullptr, nullptr,
                                             nullptr, nullptr, nullptr, nullptr);
  gemm256_kernel<3><<<256, 512, 0, stream>>>(ffn_h, W2t, 4096, 1024, 4096, 4, 4, nullptr,
                                             nullptr, nullptr, nullptr, nullptr,
                                             pp0, pp1, pp2, pp3);
  ln4p_kernel<<<4096, 256, 0, stream>>>(pp0, pp1, pp2, pp3, b2, out1b, gamma2, beta2,
                                        (float*)d_out);
}

// Round 18
// 230.055 us; speedup vs baseline: 1.4584x; 1.0085x over previous
//
#include <hip/hip_runtime.h>
#include <stdint.h>

// ---------- types ----------
typedef float f32x4 __attribute__((ext_vector_type(4)));
typedef __bf16 bf16x8 __attribute__((ext_vector_type(8)));
typedef __bf16 bf16x8_a __attribute__((ext_vector_type(8), may_alias));
typedef __bf16 bf16x4_a __attribute__((ext_vector_type(4), may_alias));
typedef unsigned int u32x4_a __attribute__((ext_vector_type(4), may_alias));
typedef unsigned short u16x4_a __attribute__((ext_vector_type(4), may_alias));

#define DEV __device__ __forceinline__
#define MFMA_B16(a, b, c) __builtin_amdgcn_mfma_f32_16x16x32_bf16((a), (b), (c), 0, 0, 0)

#if __has_builtin(__builtin_amdgcn_exp2f)
#define EXP2(x) __builtin_amdgcn_exp2f(x)
#else
#define EXP2(x) exp2f(x)
#endif

DEV unsigned short f2b(float f) {  // f32 -> bf16 RNE
  unsigned int u = __float_as_uint(f);
  u = u + 0x7FFFu + ((u >> 16) & 1u);
  return (unsigned short)(u >> 16);
}
DEV float b2f(unsigned short u) { return __uint_as_float(((unsigned int)u) << 16); }

// async global->LDS, 16B per lane; LDS dest is wave-uniform base + lane*16
#define GLOAD_LDS16(gsrc, ldst)                                                  \
  __builtin_amdgcn_global_load_lds(                                              \
      (__attribute__((address_space(1))) void*)(uintptr_t)(const void*)(gsrc),   \
      (__attribute__((address_space(3))) void*)(ldst), 16, 0, 0)

// ---------- fused prepass: cvt x | transpose wq/wk/wv | transpose w_proj/w1/w2 | bias ----------
__global__ __launch_bounds__(256) void prepass_kernel(
    const float* __restrict__ x, const float* __restrict__ wq,
    const float* __restrict__ wk, const float* __restrict__ wv,
    const float* __restrict__ w_proj, const float* __restrict__ w1,
    const float* __restrict__ w2, const float* __restrict__ bq,
    const float* __restrict__ bk, const float* __restrict__ bv,
    unsigned short* __restrict__ xb, unsigned short* __restrict__ Wqkv_t,
    unsigned short* __restrict__ o_proj, unsigned short* __restrict__ o1,
    unsigned short* __restrict__ o2, float* __restrict__ biasq) {
  __shared__ float tile[32][33];
  int bid = blockIdx.x;
  if (bid < 4096) {  // cvt: x f32 -> bf16
    int i = bid * 256 + threadIdx.x;
    float4 v = ((const float4*)x)[i];
    u16x4_a t = {f2b(v.x), f2b(v.y), f2b(v.z), f2b(v.w)};
    ((u16x4_a*)xb)[i] = t;
    return;
  }
  bid -= 4096;
  if (bid < 3072) {  // tqkv
    const int bx = bid & 1, by = (bid >> 1) & 31, zz = bid >> 6;
    const int sel = zz >> 4, zh = zz & 15;
    const float scale = sel == 0 ? 0.18033688f : 1.f;  // q: 1/sqrt(HD)*log2(e)
    const float* ip = (sel == 0 ? wq : (sel == 1 ? wk : wv)) + (size_t)zh * 1024 * 64;
    unsigned short* op = Wqkv_t + (size_t)sel * 1024 * 1024 + (size_t)zh * 1024 * 64;
    const int tx = threadIdx.x & 31, ty = threadIdx.x >> 5;
    const int c0 = bx * 32, r0 = by * 32;
#pragma unroll
    for (int j = 0; j < 32; j += 8)
      tile[ty + j][tx] = ip[(size_t)(r0 + ty + j) * 64 + (c0 + tx)];
    __syncthreads();
#pragma unroll
    for (int j = 0; j < 32; j += 8)
      op[(size_t)(c0 + ty + j) * 1024 + (r0 + tx)] = f2b(tile[tx][ty + j] * scale);
    return;
  }
  bid -= 3072;
  if (bid < 9216) {  // tw
    const float* in;
    unsigned short* out;
    int rows, cols, bx, by;
    if (bid < 1024) {
      in = w_proj; out = o_proj; rows = 1024; cols = 1024; bx = bid & 31; by = bid >> 5;
    } else if (bid < 5120) {
      bid -= 1024; in = w1; out = o1; rows = 1024; cols = 4096; bx = bid & 127; by = bid >> 7;
    } else {
      bid -= 5120; in = w2; out = o2; rows = 4096; cols = 1024; bx = bid & 31; by = bid >> 5;
    }
    const int tx = threadIdx.x & 31, ty = threadIdx.x >> 5;
    const int c0 = bx * 32, r0 = by * 32;
#pragma unroll
    for (int j = 0; j < 32; j += 8)
      tile[ty + j][tx] = in[(size_t)(r0 + ty + j) * cols + (c0 + tx)];
    __syncthreads();
#pragma unroll
    for (int j = 0; j < 32; j += 8)
      out[(size_t)(c0 + ty + j) * rows + (r0 + tx)] = f2b(tile[tx][ty + j]);
    return;
  }
  bid -= 9216;  // bias
  int c = bid * 256 + threadIdx.x;
  int which = c >> 10, idx = c & 1023;
  float v = which == 0 ? bq[idx] : (which == 1 ? bk[idx] : bv[idx]);
  biasq[c] = which == 0 ? v * 0.18033688f : v;
}

// ---------- 256x256 8-phase GEMM (m201 template, plain HIP; R11 epilogues) ----------
// EP 0: QKV scatter + bias. EP 2: bf16 relu. EP 3: bf16 raw partial (split-K).
template <int EP>
__global__ __launch_bounds__(512, 2) void gemm256_kernel(
    const unsigned short* __restrict__ A, const unsigned short* __restrict__ Bt,
    int M, int N, int K, int nbx, int KS,
    const float* __restrict__ bias, unsigned short* __restrict__ outb,
    unsigned short* __restrict__ q_out, unsigned short* __restrict__ k_out,
    unsigned short* __restrict__ v_out,
    unsigned short* __restrict__ pp0, unsigned short* __restrict__ pp1,
    unsigned short* __restrict__ pp2, unsigned short* __restrict__ pp3) {
  __shared__ __align__(16) unsigned short sA[2][256 * 64];
  __shared__ __align__(16) unsigned short sB[2][256 * 64];

  const int tid = threadIdx.x;
  const int wid = tid >> 6, lane = tid & 63;
  const int g = lane >> 4, r15 = lane & 15;
  const int wm = wid >> 2, wn = wid & 3;

  const int nwg = gridDim.x, cpx = nwg >> 3, orig = blockIdx.x;
  const int wg = (orig & 7) * cpx + (orig >> 3);
  const int bx = wg % nbx;
  const int t1 = wg / nbx;
  const int kz = t1 % KS, by = t1 / KS;
  const int row0 = by * 256, col0 = bx * 256;

  const int tilesK = K >> 6;
  const int qT = tilesK / KS, rT = tilesK % KS;
  const int tile0 = kz * qT + (kz < rT ? kz : rT);
  const int NT = qT + (kz < rT ? 1 : 0);
  const int kbase = tile0 << 6;

  const unsigned short* gA0 = A + (size_t)row0 * K + kbase;
  const unsigned short* gB0 = Bt + (size_t)col0 * K + kbase;
  const int srow8 = lane >> 3;
  const int schunk = ((lane & 7) ^ srow8) * 8;

  f32x4 acc[8][4] = {};
  bf16x8 af[4][2], bfr[4][2];

  auto stA = [&](int buf, int k0, int i) {
    const int r = wid * 32 + i * 8;
    GLOAD_LDS16(gA0 + (size_t)(r + srow8) * K + k0 + schunk, &sA[buf][r * 64]);
  };
  auto stB = [&](int buf, int k0, int i) {
    const int r = wid * 32 + i * 8;
    GLOAD_LDS16(gB0 + (size_t)(r + srow8) * K + k0 + schunk, &sB[buf][r * 64]);
  };
  auto ldA = [&](const unsigned short* p, int m, int ks) -> bf16x8 {
    const int row = wm * 128 + m * 16 + r15;
    return *(const bf16x8_a*)&p[row * 64 + (((ks * 4 + g) ^ (r15 & 7)) * 8)];
  };
  auto ldB = [&](const unsigned short* p, int n, int ks) -> bf16x8 {
    const int row = wn * 64 + n * 16 + r15;
    return *(const bf16x8_a*)&p[row * 64 + (((ks * 4 + g) ^ (r15 & 7)) * 8)];
  };

#pragma unroll
  for (int i = 0; i < 4; ++i) { stA(0, 0, i); stB(0, 0, i); }
  asm volatile("s_waitcnt vmcnt(0)" ::: "memory");
  __builtin_amdgcn_s_barrier();

  for (int kt = 0; kt < NT; ++kt) {
    const int cb = kt & 1, nb = cb ^ 1;
    const bool pf = (kt + 1) < NT;
    const int k1 = (kt + 1) << 6;
    const unsigned short* pA = sA[cb];
    const unsigned short* pB = sB[cb];

#pragma unroll
    for (int m = 0; m < 4; ++m) { af[m][0] = ldA(pA, m, 0); af[m][1] = ldA(pA, m, 1); }
#pragma unroll
    for (int n = 0; n < 4; ++n) { bfr[n][0] = ldB(pB, n, 0); bfr[n][1] = ldB(pB, n, 1); }
    if (pf) { stA(nb, k1, 0); stA(nb, k1, 1); }
    __builtin_amdgcn_s_barrier();
    asm volatile("s_waitcnt lgkmcnt(0)" ::: "memory");
    __builtin_amdgcn_sched_barrier(0);
    __builtin_amdgcn_s_setprio(1);
#pragma unroll
    for (int m = 0; m < 4; ++m)
#pragma unroll
      for (int n = 0; n < 2; ++n) {
        acc[m][n] = MFMA_B16(af[m][0], bfr[n][0], acc[m][n]);
        acc[m][n] = MFMA_B16(af[m][1], bfr[n][1], acc[m][n]);
      }
    __builtin_amdgcn_s_setprio(0);
    __builtin_amdgcn_s_barrier();

    if (pf) { stA(nb, k1, 2); stA(nb, k1, 3); }
    __builtin_amdgcn_s_barrier();
    __builtin_amdgcn_s_setprio(1);
#pragma unroll
    for (int m = 0; m < 4; ++m)
#pragma unroll
      for (int n = 2; n < 4; ++n) {
        acc[m][n] = MFMA_B16(af[m][0], bfr[n][0], acc[m][n]);
        acc[m][n] = MFMA_B16(af[m][1], bfr[n][1], acc[m][n]);
      }
    __builtin_amdgcn_s_setprio(0);
    __builtin_amdgcn_s_barrier();

#pragma unroll
    for (int m = 0; m < 4; ++m) { af[m][0] = ldA(pA, m + 4, 0); af[m][1] = ldA(pA, m + 4, 1); }
    if (pf) { stB(nb, k1, 0); stB(nb, k1, 1); }
    __builtin_amdgcn_s_barrier();
    asm volatile("s_waitcnt lgkmcnt(0)" ::: "memory");
    __builtin_amdgcn_sched_barrier(0);
    __builtin_amdgcn_s_setprio(1);
#pragma unroll
    for (int m = 0; m < 4; ++m)
#pragma unroll
      for (int n = 0; n < 2; ++n) {
        acc[m + 4][n] = MFMA_B16(af[m][0], bfr[n][0], acc[m + 4][n]);
        acc[m + 4][n] = MFMA_B16(af[m][1], bfr[n][1], acc[m + 4][n]);
      }
    __builtin_amdgcn_s_setprio(0);
    __builtin_amdgcn_s_barrier();

    if (pf) { stB(nb, k1, 2); stB(nb, k1, 3); }
    __builtin_amdgcn_s_barrier();
    __builtin_amdgcn_s_setprio(1);
#pragma unroll
    for (int m = 0; m < 4; ++m)
#pragma unroll
      for (int n = 2; n < 4; ++n) {
        acc[m + 4][n] = MFMA_B16(af[m][0], bfr[n][0], acc[m + 4][n]);
        acc[m + 4][n] = MFMA_B16(af[m][1], bfr[n][1], acc[m + 4][n]);
      }
    __builtin_amdgcn_s_setprio(0);
    asm volatile("s_waitcnt vmcnt(0)" ::: "memory");
    __builtin_amdgcn_s_barrier();
  }

  unsigned short* pz = kz == 0 ? pp0 : (kz == 1 ? pp1 : (kz == 2 ? pp2 : pp3));
#pragma unroll
  for (int m = 0; m < 8; ++m) {
    const int rbase = row0 + wm * 128 + m * 16 + g * 4;
#pragma unroll
    for (int n = 0; n < 4; ++n) {
      const int col = col0 + wn * 64 + n * 16 + r15;
      const float bb = (EP == 3) ? 0.f : bias[col];
      if constexpr (EP == 0) {
        const int which = col >> 10, cc = col & 1023;
        const int hh = cc >> 6, e = cc & 63;
        const int b = rbase >> 11, s0v = rbase & 2047;
        if (which == 2) {
          bf16x4_a pk;
#pragma unroll
          for (int r = 0; r < 4; ++r) pk[r] = (__bf16)(acc[m][n][r] + bb);
          *(bf16x4_a*)(v_out + (((size_t)(b * 16 + hh) * 64) + e) * 2048 + s0v) = pk;
        } else {
          unsigned short* dst = which == 0 ? q_out : k_out;
#pragma unroll
          for (int r = 0; r < 4; ++r)
            dst[(((size_t)(b * 16 + hh) * 2048) + s0v + r) * 64 + e] =
                f2b(acc[m][n][r] + bb);
        }
      } else {
#pragma unroll
        for (int r = 0; r < 4; ++r) {
          const int row = rbase + r;
          float v = acc[m][n][r] + bb;
          if constexpr (EP == 3) {
            pz[(size_t)row * N + col] = f2b(v);
          } else {
            outb[(size_t)row * N + col] = f2b(v > 0.f ? v : 0.f);
          }
        }
      }
    }
  }
}

// ---------- 128x128 GEMM, BK=64 + XOR swizzle (gemm256 transplant), split-K z ----------
__global__ __launch_bounds__(256) void gemm_bt_kernel(
    const unsigned short* __restrict__ A, const unsigned short* __restrict__ Bt,
    int M, int N, int Kchunk, int Kstride,
    unsigned short* __restrict__ pp0, unsigned short* __restrict__ pp1) {
  __shared__ __align__(16) unsigned short sA[2][128 * 64];
  __shared__ __align__(16) unsigned short sB[2][128 * 64];
  const int tid = threadIdx.x;
  const int wid = tid >> 6, lane = tid & 63;
  const int g = lane >> 4, r15 = lane & 15;
  const int wr = wid >> 1, wc = wid & 1;
  const int row0 = blockIdx.y * 128, col0 = blockIdx.x * 128;
  const int kz = blockIdx.z;

  f32x4 acc[4][4] = {};

  const unsigned short* gA0 = A + (size_t)row0 * Kstride + (size_t)kz * Kchunk;
  const unsigned short* gB0 = Bt + (size_t)col0 * Kstride + (size_t)kz * Kchunk;
  const int srow8 = lane >> 3;
  const int schunk = ((lane & 7) ^ srow8) * 8;

  auto stage = [&](int buf, int k0) {
#pragma unroll
    for (int i = 0; i < 4; ++i) {
      const int r = wid * 32 + i * 8;
      GLOAD_LDS16(gA0 + (size_t)(r + srow8) * Kstride + k0 + schunk, &sA[buf][r * 64]);
      GLOAD_LDS16(gB0 + (size_t)(r + srow8) * Kstride + k0 + schunk, &sB[buf][r * 64]);
    }
  };
  auto ldA = [&](const unsigned short* p, int m, int ks) -> bf16x8 {
    const int row = wr * 64 + m * 16 + r15;
    return *(const bf16x8_a*)&p[row * 64 + (((ks * 4 + g) ^ (r15 & 7)) * 8)];
  };
  auto ldB = [&](const unsigned short* p, int n, int ks) -> bf16x8 {
    const int row = wc * 64 + n * 16 + r15;
    return *(const bf16x8_a*)&p[row * 64 + (((ks * 4 + g) ^ (r15 & 7)) * 8)];
  };

  stage(0, 0);
  const int NT = Kchunk >> 6;
  for (int t = 0; t < NT; ++t) {
    const int cb = t & 1;
    __syncthreads();
    if (t + 1 < NT) stage(cb ^ 1, (t + 1) * 64);
    bf16x8 af[4][2], bfr[4][2];
#pragma unroll
    for (int m = 0; m < 4; ++m) {
      af[m][0] = ldA(sA[cb], m, 0);
      af[m][1] = ldA(sA[cb], m, 1);
    }
#pragma unroll
    for (int n = 0; n < 4; ++n) {
      bfr[n][0] = ldB(sB[cb], n, 0);
      bfr[n][1] = ldB(sB[cb], n, 1);
    }
#pragma unroll
    for (int m = 0; m < 4; ++m)
#pragma unroll
      for (int n = 0; n < 4; ++n) {
        acc[m][n] = MFMA_B16(af[m][0], bfr[n][0], acc[m][n]);
        acc[m][n] = MFMA_B16(af[m][1], bfr[n][1], acc[m][n]);
      }
  }

  unsigned short* pz = kz == 0 ? pp0 : pp1;
#pragma unroll
  for (int m = 0; m < 4; ++m) {
    const int rbase = row0 + wr * 64 + m * 16 + g * 4;
#pragma unroll
    for (int n = 0; n < 4; ++n) {
      const int col = col0 + wc * 64 + n * 16 + r15;
#pragma unroll
      for (int r = 0; r < 4; ++r)
        pz[(size_t)(rbase + r) * N + col] = f2b(acc[m][n][r]);
    }
  }
}

// ---------- flash attention: 2 q-groups/wave, 4-deep K/V buffers (R17, frozen) ----------
__global__ __launch_bounds__(256) void attn_kernel(const unsigned short* __restrict__ Q,
                                                   const unsigned short* __restrict__ K,
                                                   const unsigned short* __restrict__ Vt,
                                                   unsigned short* __restrict__ out) {
  const int flat = blockIdx.y * gridDim.x + blockIdx.x;  // 0..511
  const int xcd = flat & 7, rest = flat >> 3;            // rest 0..63
  const int bh = xcd * 4 + (rest >> 4);
  const int q0 = (rest & 15) * 128;

  const int tid = threadIdx.x, wid = tid >> 6, lane = tid & 63;
  const int g = lane >> 4, r15 = lane & 15;
  const int h = r15 & 7;
  const int s0 = ((g ^ h) * 8);
  const int s1 = (((g + 4) ^ h) * 8);
  const int pswz = r15 & 14;

  __shared__ __align__(16) unsigned short sK[4][64 * 64];
  __shared__ __align__(16) unsigned short sV[4][64 * 64];
  __shared__ __align__(16) unsigned short sP[4][16 * 64];

  const size_t base = (size_t)bh * (2048 * 64);
  const unsigned short* Kb = K + base;
  const unsigned short* Vb = Vt + base;

  const int qrow0 = q0 + wid * 16 + r15;
  bf16x8 qf0[2], qf1[2];
  qf0[0] = *(const bf16x8_a*)(Q + base + (size_t)qrow0 * 64 + g * 8);
  qf0[1] = *(const bf16x8_a*)(Q + base + (size_t)qrow0 * 64 + 32 + g * 8);
  qf1[0] = *(const bf16x8_a*)(Q + base + (size_t)(qrow0 + 64) * 64 + g * 8);
  qf1[1] = *(const bf16x8_a*)(Q + base + (size_t)(qrow0 + 64) * 64 + 32 + g * 8);

  const int srow = lane >> 3;
  const int schunk = ((lane & 7) ^ srow) * 8;

  union {
    unsigned short u[8];
    bf16x8 v;
  } ou;
#pragma unroll
  for (int i = 0; i < 8; ++i) ou.u[i] = 0x3F80;
  const bf16x8 onesb = ou.v;

  f32x4 o0[4] = {}, o1[4] = {};
  float m0 = -1e30f, l0 = 0.f, m1 = -1e30f, l1 = 0.f;

  const int krd0 = r15 * 64 + s0;
  const int krd1 = r15 * 64 + s1;
  unsigned short* const pw = &sP[wid][r15 * 64];
  const int pwr0 = ((2 * g) ^ pswz) << 2;
  const int pwr1 = ((8 + 2 * g) ^ pswz) << 2;

  auto stage = [&](int bufi, int tile) {
    const int kt0s = tile * 64;
#pragma unroll
    for (int i = 0; i < 2; ++i) {
      const int inst = wid * 2 + i;
      const int row = 8 * inst + srow;
      GLOAD_LDS16(Kb + (size_t)(kt0s + row) * 64 + schunk, &sK[bufi][inst * 512]);
      GLOAD_LDS16(Vb + (size_t)row * 2048 + kt0s + schunk, &sV[bufi][inst * 512]);
    }
  };

  auto proc = [&](const unsigned short* kbuf, const unsigned short* vbuf,
                  const bf16x8 (&qf)[2], float& mrow, float& lrow, f32x4 (&o)[4]) {
    f32x4 sc[4] = {};
#pragma unroll
    for (int kt = 0; kt < 4; ++kt) {
      bf16x8 kf0 = *(const bf16x8_a*)&kbuf[kt * 1024 + krd0];
      bf16x8 kf1 = *(const bf16x8_a*)&kbuf[kt * 1024 + krd1];
      sc[kt] = MFMA_B16(kf0, qf[0], sc[kt]);
      sc[kt] = MFMA_B16(kf1, qf[1], sc[kt]);
    }

    float a0 = fmaxf(fmaxf(sc[0][0], sc[0][1]), sc[0][2]);
    float a1 = fmaxf(fmaxf(sc[0][3], sc[1][0]), sc[1][1]);
    float a2 = fmaxf(fmaxf(sc[1][2], sc[1][3]), sc[2][0]);
    float a3 = fmaxf(fmaxf(sc[2][1], sc[2][2]), sc[2][3]);
    float a4 = fmaxf(fmaxf(sc[3][0], sc[3][1]), sc[3][2]);
    float b0 = fmaxf(fmaxf(a0, a1), a2);
    float b1 = fmaxf(fmaxf(a3, a4), sc[3][3]);
    float pmax = fmaxf(b0, b1);
    pmax = fmaxf(pmax, __shfl_xor(pmax, 16));
    pmax = fmaxf(pmax, __shfl_xor(pmax, 32));

    const bool allkeep = __all(pmax - mrow <= 11.5441f);
    float fac;
    if (allkeep) {
      fac = 1.0f;
    } else {
      float nm = fmaxf(mrow, pmax);
      fac = EXP2(mrow - nm);
      mrow = nm;
#pragma unroll
      for (int dt = 0; dt < 4; ++dt)
#pragma unroll
        for (int r = 0; r < 4; ++r) o[dt][r] *= fac;
    }

#pragma unroll
    for (int kt = 0; kt < 4; ++kt) {
      bf16x4_a pb;
      pb[0] = (__bf16)EXP2(sc[kt][0] - mrow);
      pb[1] = (__bf16)EXP2(sc[kt][1] - mrow);
      pb[2] = (__bf16)EXP2(sc[kt][2] - mrow);
      pb[3] = (__bf16)EXP2(sc[kt][3] - mrow);
      *(bf16x4_a*)&pw[((4 * kt + g) ^ pswz) << 2] = pb;
    }

    bf16x8 pf0 = *(const bf16x8_a*)&pw[pwr0];
    bf16x8 pf1 = *(const bf16x8_a*)&pw[pwr1];

    f32x4 lacc = {};
    lacc = MFMA_B16(onesb, pf0, lacc);
    lacc = MFMA_B16(onesb, pf1, lacc);
    lrow = lrow * fac + lacc[0];

#pragma unroll
    for (int dt = 0; dt < 4; ++dt) {
      bf16x8 vf0 = *(const bf16x8_a*)&vbuf[dt * 1024 + krd0];
      bf16x8 vf1 = *(const bf16x8_a*)&vbuf[dt * 1024 + krd1];
      o[dt] = MFMA_B16(vf0, pf0, o[dt]);
      o[dt] = MFMA_B16(vf1, pf1, o[dt]);
    }
  };

  auto do_tile = [&](const unsigned short* kbuf, const unsigned short* vbuf) {
    proc(kbuf, vbuf, qf0, m0, l0, o0);
    proc(kbuf, vbuf, qf1, m1, l1, o1);
  };

  stage(0, 0);
  stage(1, 1);
#pragma unroll 1
  for (int t = 0; t < 32; t += 4) {
    __syncthreads();
    stage(2, t + 2);
    stage(3, t + 3);
    do_tile(&sK[0][0], &sV[0][0]);
    do_tile(&sK[1][0], &sV[1][0]);
    __syncthreads();
    if (t + 4 < 32) {
      stage(0, t + 4);
      stage(1, t + 5);
    }
    do_tile(&sK[2][0], &sV[2][0]);
    do_tile(&sK[3][0], &sV[3][0]);
  }

  const int b = bh >> 4, hh = bh & 15;
  const int s = q0 + wid * 16 + r15;
  const float inv0 = 1.f / l0, inv1 = 1.f / l1;
  unsigned short* orow0 = out + ((size_t)(b * 2048 + s)) * 1024 + hh * 64;
  unsigned short* orow1 = out + ((size_t)(b * 2048 + s + 64)) * 1024 + hh * 64;
#pragma unroll
  for (int dt = 0; dt < 4; ++dt) {
    bf16x4_a t0, t1;
    t0[0] = (__bf16)(o0[dt][0] * inv0);
    t0[1] = (__bf16)(o0[dt][1] * inv0);
    t0[2] = (__bf16)(o0[dt][2] * inv0);
    t0[3] = (__bf16)(o0[dt][3] * inv0);
    *(bf16x4_a*)(orow0 + dt * 16 + g * 4) = t0;
    t1[0] = (__bf16)(o1[dt][0] * inv1);
    t1[1] = (__bf16)(o1[dt][1] * inv1);
    t1[2] = (__bf16)(o1[dt][2] * inv1);
    t1[3] = (__bf16)(o1[dt][3] * inv1);
    *(bf16x4_a*)(orow1 + dt * 16 + g * 4) = t1;
  }
}

// ---------- fused 2x bf16-partial reduce + bias + bf16-residual + LN -> bf16 ----------
__global__ __launch_bounds__(256) void ln2p_kernel(
    const unsigned short* __restrict__ p0, const unsigned short* __restrict__ p1,
    const float* __restrict__ bias, const unsigned short* __restrict__ residb,
    const float* __restrict__ gamma, const float* __restrict__ beta,
    unsigned short* __restrict__ outb) {
  const int row = blockIdx.x, tid = threadIdx.x;
  const size_t off = (size_t)row * 1024;
  u16x4_a a4 = *(const u16x4_a*)(p0 + off + tid * 4);
  u16x4_a b4 = *(const u16x4_a*)(p1 + off + tid * 4);
  u16x4_a r4 = *(const u16x4_a*)(residb + off + tid * 4);
  float4 bb4 = ((const float4*)bias)[tid];
  float4 v;
  v.x = b2f(a4[0]) + b2f(b4[0]) + bb4.x + b2f(r4[0]);
  v.y = b2f(a4[1]) + b2f(b4[1]) + bb4.y + b2f(r4[1]);
  v.z = b2f(a4[2]) + b2f(b4[2]) + bb4.z + b2f(r4[2]);
  v.w = b2f(a4[3]) + b2f(b4[3]) + bb4.w + b2f(r4[3]);

  float s = v.x + v.y + v.z + v.w;
  float ss = v.x * v.x + v.y * v.y + v.z * v.z + v.w * v.w;
#pragma unroll
  for (int o2 = 32; o2 > 0; o2 >>= 1) {
    s += __shfl_down(s, o2);
    ss += __shfl_down(ss, o2);
  }
  __shared__ float red[8];
  const int wid = tid >> 6;
  if ((tid & 63) == 0) { red[wid] = s; red[4 + wid] = ss; }
  __syncthreads();
  float S = red[0] + red[1] + red[2] + red[3];
  float SS = red[4] + red[5] + red[6] + red[7];
  const float mean = S * (1.f / 1024.f);
  const float var = SS * (1.f / 1024.f) - mean * mean;
  const float inv = 1.f / sqrtf(var + 1e-10f);
  float4 gg = ((const float4*)gamma)[tid];
  float4 be = ((const float4*)beta)[tid];
  float4 o;
  o.x = (v.x - mean) * inv * gg.x + be.x;
  o.y = (v.y - mean) * inv * gg.y + be.y;
  o.z = (v.z - mean) * inv * gg.z + be.z;
  o.w = (v.w - mean) * inv * gg.w + be.w;
  u16x4_a t = {f2b(o.x), f2b(o.y), f2b(o.z), f2b(o.w)};
  *(u16x4_a*)(outb + off + tid * 4) = t;
}

// ---------- fused 4x bf16-partial reduce + bias + bf16-residual + LN -> f32 ----------
__global__ __launch_bounds__(256) void ln4p_kernel(
    const unsigned short* __restrict__ p0, const unsigned short* __restrict__ p1,
    const unsigned short* __restrict__ p2, const unsigned short* __restrict__ p3,
    const float* __restrict__ bias, const unsigned short* __restrict__ residb,
    const float* __restrict__ gamma, const float* __restrict__ beta,
    float* __restrict__ outf) {
  const int row = blockIdx.x, tid = threadIdx.x;
  const size_t off = (size_t)row * 1024;
  u16x4_a a4 = *(const u16x4_a*)(p0 + off + tid * 4);
  u16x4_a b4 = *(const u16x4_a*)(p1 + off + tid * 4);
  u16x4_a c4 = *(const u16x4_a*)(p2 + off + tid * 4);
  u16x4_a d4 = *(const u16x4_a*)(p3 + off + tid * 4);
  u16x4_a r4 = *(const u16x4_a*)(residb + off + tid * 4);
  float4 bb4 = ((const float4*)bias)[tid];
  float4 v;
  v.x = (b2f(a4[0]) + b2f(b4[0])) + (b2f(c4[0]) + b2f(d4[0])) + bb4.x + b2f(r4[0]);
  v.y = (b2f(a4[1]) + b2f(b4[1])) + (b2f(c4[1]) + b2f(d4[1])) + bb4.y + b2f(r4[1]);
  v.z = (b2f(a4[2]) + b2f(b4[2])) + (b2f(c4[2]) + b2f(d4[2])) + bb4.z + b2f(r4[2]);
  v.w = (b2f(a4[3]) + b2f(b4[3])) + (b2f(c4[3]) + b2f(d4[3])) + bb4.w + b2f(r4[3]);

  float s = v.x + v.y + v.z + v.w;
  float ss = v.x * v.x + v.y * v.y + v.z * v.z + v.w * v.w;
#pragma unroll
  for (int o2 = 32; o2 > 0; o2 >>= 1) {
    s += __shfl_down(s, o2);
    ss += __shfl_down(ss, o2);
  }
  __shared__ float red[8];
  const int wid = tid >> 6;
  if ((tid & 63) == 0) { red[wid] = s; red[4 + wid] = ss; }
  __syncthreads();
  float S = red[0] + red[1] + red[2] + red[3];
  float SS = red[4] + red[5] + red[6] + red[7];
  const float mean = S * (1.f / 1024.f);
  const float var = SS * (1.f / 1024.f) - mean * mean;
  const float inv = 1.f / sqrtf(var + 1e-10f);
  float4 gg = ((const float4*)gamma)[tid];
  float4 be = ((const float4*)beta)[tid];
  float4 o;
  o.x = (v.x - mean) * inv * gg.x + be.x;
  o.y = (v.y - mean) * inv * gg.y + be.y;
  o.z = (v.z - mean) * inv * gg.z + be.z;
  o.w = (v.w - mean) * inv * gg.w + be.w;
  ((float4*)(outf + off))[tid] = o;
}

// ---------- launch ----------
extern "C" void kernel_launch(void* const* d_in, const int* in_sizes, int n_in,
                              void* d_out, int out_size, void* d_ws, size_t ws_size,
                              hipStream_t stream) {
  const float* x      = (const float*)d_in[0];
  const float* wq     = (const float*)d_in[1];
  const float* bq     = (const float*)d_in[2];
  const float* wk     = (const float*)d_in[3];
  const float* bk     = (const float*)d_in[4];
  const float* wv     = (const float*)d_in[5];
  const float* bv     = (const float*)d_in[6];
  const float* w_proj = (const float*)d_in[7];
  const float* b_proj = (const float*)d_in[8];
  const float* gamma1 = (const float*)d_in[9];
  const float* beta1  = (const float*)d_in[10];
  const float* w1     = (const float*)d_in[11];
  const float* b1     = (const float*)d_in[12];
  const float* w2     = (const float*)d_in[13];
  const float* b2     = (const float*)d_in[14];
  const float* gamma2 = (const float*)d_in[15];
  const float* beta2  = (const float*)d_in[16];

  char* p = (char*)d_ws;
  auto alloc = [&](size_t bytes) {
    char* r = p;
    p += (bytes + 255) & ~(size_t)255;
    return r;
  };
  unsigned short* xb      = (unsigned short*)alloc(4096ull * 1024 * 2);  // 8MB; x bf16, live thru ln2p
  unsigned short* Wqkv_t  = (unsigned short*)alloc(3072ull * 1024 * 2);  // 6MB; dead after QKV
  unsigned short* Wproj_t = (unsigned short*)alloc(1024ull * 1024 * 2);  // 2MB; dead after proj
  unsigned short* W2t     = (unsigned short*)alloc(1024ull * 4096 * 2);  // 8MB; live thru FFN2
  float*          biasq   = (float*)alloc(3072 * 4);
  unsigned short* Qb      = (unsigned short*)alloc(4096ull * 1024 * 2);  // 8MB; dead after attn
  unsigned short* Kb      = (unsigned short*)alloc(4096ull * 1024 * 2);  // 8MB; dead after attn
  unsigned short* Vtb     = (unsigned short*)alloc(4096ull * 1024 * 2);  // 8MB; dead after attn
  unsigned short* W1t     = (unsigned short*)alloc(4096ull * 1024 * 2);  // 8MB; dead after FFN1
  unsigned short* out1b   = (unsigned short*)alloc(4096ull * 1024 * 2);  // attn-out, then ln1-out
  unsigned short* ffn_h   = (unsigned short*)alloc(4096ull * 4096 * 2);  // live thru FFN2

  // attn output -> out1b region (dead until ln2p overwrite; proj consumes first)
  unsigned short* aout = out1b;
  unsigned short* prA = Qb;
  unsigned short* prB = Kb;
  unsigned short* pp0 = xb;   // xb dead after ln2p
  unsigned short* pp1 = Qb;
  unsigned short* pp2 = Kb;
  unsigned short* pp3 = Vtb;

  prepass_kernel<<<16396, 256, 0, stream>>>(x, wq, wk, wv, w_proj, w1, w2, bq, bk, bv,
                                            xb, Wqkv_t, Wproj_t, W1t, W2t, biasq);

  gemm256_kernel<0><<<192, 512, 0, stream>>>(xb, Wqkv_t, 4096, 3072, 1024, 12, 1, biasq,
                                             nullptr, Qb, Kb, Vtb, nullptr, nullptr,
                                             nullptr, nullptr);
  attn_kernel<<<dim3(16, 32), 256, 0, stream>>>(Qb, Kb, Vtb, aout);
  gemm_bt_kernel<<<dim3(8, 32, 2), 256, 0, stream>>>(aout, Wproj_t, 4096, 1024, 512, 1024,
                                                     prA, prB);
  ln2p_kernel<<<4096, 256, 0, stream>>>(prA, prB, b_proj, xb, gamma1, beta1, out1b);
  gemm256_kernel<2><<<256, 512, 0, stream>>>(out1b, W1t, 4096, 4096, 1024, 16, 1, b1,
                                             ffn_h, nullptr, nullptr, nullptr,
                                             nullptr, nullptr, nullptr, nullptr);
  gemm256_kernel<3><<<256, 512, 0, stream>>>(ffn_h, W2t, 4096, 1024, 4096, 4, 4, nullptr,
                                             nullptr, nullptr, nullptr, nullptr,
                                             pp0, pp1, pp2, pp3);
  ln4p_kernel<<<4096, 256, 0, stream>>>(pp0, pp1, pp2, pp3, b2, out1b, gamma2, beta2,
                                        (float*)d_out);
}